// Round 1
// baseline (693.416 us; speedup 1.0000x reference)
//
#include <hip/hip_runtime.h>

#define ROI   268
#define FDIM  268
#define NB    64
#define NN    (NB*ROI)     // 17152
#define CC    32
#define DEG   32
#define KSEL  32
#define SLOPE 0.33f
#define EPSBN 1e-5f

__device__ __forceinline__ float lrelu(float h) { return h >= 0.f ? h : SLOPE * h; }

// ---------------- K1: per-node projections u1,v1,u2,v2,u3,v3,sq ----------------
// u = x @ (Wa - Wb) + bias ; v = x @ Wb    (EdgeConv first-layer factorization)
__global__ __launch_bounds__(256) void k_node_proj(
    const float* __restrict__ x,
    const float* __restrict__ W1a, const float* __restrict__ b1a,
    const float* __restrict__ W2a, const float* __restrict__ b2a,
    const float* __restrict__ W3,  const float* __restrict__ b3,
    float* __restrict__ u1, float* __restrict__ v1,
    float* __restrict__ u2, float* __restrict__ v2,
    float* __restrict__ u3, float* __restrict__ v3, float* __restrict__ sqv)
{
    __shared__ float Xs[16][272];
    const int tid = threadIdx.x;
    const int n0  = blockIdx.x * 16;
    for (int idx = tid; idx < 16 * FDIM; idx += 256) {
        int i = idx / FDIM, f = idx - i * FDIM;
        Xs[i][f] = x[(size_t)(n0 + i) * FDIM + f];
    }
    __syncthreads();
    const int c = tid & 31;
    const int h = (tid >> 5) & 1;   // node half
    const int m = tid >> 6;         // 0:u1 1:v1 2:u2 3:v2  (wave-uniform)
    const float* WA = (m < 2) ? W1a : W2a;
    const bool isU = (m & 1) == 0;
    float acc[8] = {0.f,0.f,0.f,0.f,0.f,0.f,0.f,0.f};
    for (int f = 0; f < FDIM; f += 4) {
        float w0, w1, w2, w3;
        {
            float wb0 = WA[(size_t)(FDIM + f + 0) * CC + c];
            float wb1 = WA[(size_t)(FDIM + f + 1) * CC + c];
            float wb2 = WA[(size_t)(FDIM + f + 2) * CC + c];
            float wb3 = WA[(size_t)(FDIM + f + 3) * CC + c];
            if (isU) {
                w0 = WA[(size_t)(f + 0) * CC + c] - wb0;
                w1 = WA[(size_t)(f + 1) * CC + c] - wb1;
                w2 = WA[(size_t)(f + 2) * CC + c] - wb2;
                w3 = WA[(size_t)(f + 3) * CC + c] - wb3;
            } else { w0 = wb0; w1 = wb1; w2 = wb2; w3 = wb3; }
        }
        #pragma unroll
        for (int i = 0; i < 8; ++i) {
            float4 xv = *(const float4*)&Xs[h * 8 + i][f];
            acc[i] += xv.x * w0 + xv.y * w1 + xv.z * w2 + xv.w * w3;
        }
    }
    float bias = 0.f;
    if (m == 0) bias = b1a[c];
    else if (m == 2) bias = b2a[c];
    float* outp = (m == 0) ? u1 : (m == 1) ? v1 : (m == 2) ? u2 : v2;
    #pragma unroll
    for (int i = 0; i < 8; ++i)
        outp[(size_t)(n0 + h * 8 + i) * CC + c] = acc[i] + bias;

    if (tid < 48) {  // 16 nodes x {u3, v3, sq}
        int i = tid / 3, sel = tid - 3 * (tid / 3);
        float a = 0.f;
        if (sel == 0) {
            for (int f = 0; f < FDIM; ++f) a += Xs[i][f] * (W3[f] - W3[FDIM + f]);
            u3[n0 + i] = a + b3[0];
        } else if (sel == 1) {
            for (int f = 0; f < FDIM; ++f) a += Xs[i][f] * W3[FDIM + f];
            v3[n0 + i] = a;
        } else {
            for (int f = 0; f < FDIM; ++f) a += Xs[i][f] * Xs[i][f];
            sqv[n0 + i] = a;
        }
    }
}

// ---------------- K2: per-graph gram + d2 + top-32 selection ----------------
#define TI2 16
#define TJ2 32
#define FP2 276   // pad to break stride-272 bank pattern on Xj reads

__device__ __forceinline__ void select_row(float (&vals)[9], int sl, int nglob, int b,
                                           int* __restrict__ knn)
{
    for (int it = 0; it < KSEL; ++it) {
        float bv = vals[0]; int bj = sl;
        #pragma unroll
        for (int q = 1; q < 9; ++q) {
            int jj = q * 32 + sl;
            if (vals[q] < bv) { bv = vals[q]; bj = jj; }   // ties -> smaller jj (q asc)
        }
        #pragma unroll
        for (int mm = 16; mm > 0; mm >>= 1) {
            float ov = __shfl_xor(bv, mm, 32);
            int   oj = __shfl_xor(bj, mm, 32);
            if (ov < bv || (ov == bv && oj < bj)) { bv = ov; bj = oj; }
        }
        if (sl == 0) knn[(size_t)nglob * KSEL + it] = b * ROI + bj;
        #pragma unroll
        for (int q = 0; q < 9; ++q)
            if (bj == q * 32 + sl) vals[q] = __builtin_inff();
    }
}

__global__ __launch_bounds__(256) void k_knn_sel(
    const float* __restrict__ x, const float* __restrict__ sqv, int* __restrict__ knn)
{
    __shared__ float Xi[TI2][272];
    __shared__ float Xj[TJ2][FP2];
    __shared__ float sqi[TI2];
    const int tid = threadIdx.x;
    const int b  = blockIdx.y;
    const int i0 = blockIdx.x * TI2;
    const int nrows = min(TI2, ROI - i0);
    for (int idx = tid; idx < TI2 * FDIM; idx += 256) {
        int r = idx / FDIM, f = idx - r * FDIM;
        Xi[r][f] = (r < nrows) ? x[(size_t)(b * ROI + i0 + r) * FDIM + f] : 0.f;
    }
    if (tid < TI2) sqi[tid] = (tid < nrows) ? sqv[b * ROI + i0 + tid] : 0.f;
    const int j  = tid & 31;
    const int rp = tid >> 5;     // 0..7 ; thread owns rows rp and rp+8
    float d2a[9], d2b[9];
    #pragma unroll
    for (int q = 0; q < 9; ++q) {
        const int j0 = q * TJ2;
        const int njc = min(TJ2, ROI - j0);
        __syncthreads();
        for (int idx = tid; idx < TJ2 * FDIM; idx += 256) {
            int r = idx / FDIM, f = idx - r * FDIM;
            Xj[r][f] = (r < njc) ? x[(size_t)(b * ROI + j0 + r) * FDIM + f] : 0.f;
        }
        __syncthreads();
        float acc0 = 0.f, acc1 = 0.f;
        for (int f = 0; f < FDIM; f += 4) {
            float4 xj  = *(const float4*)&Xj[j][f];
            float4 a0  = *(const float4*)&Xi[rp][f];
            float4 a1v = *(const float4*)&Xi[rp + 8][f];
            acc0 += a0.x * xj.x + a0.y * xj.y + a0.z * xj.z + a0.w * xj.w;
            acc1 += a1v.x * xj.x + a1v.y * xj.y + a1v.z * xj.z + a1v.w * xj.w;
        }
        if (j < njc) {
            float sqj = sqv[b * ROI + j0 + j];
            d2a[q] = sqi[rp]     + sqj - 2.f * acc0;
            d2b[q] = sqi[rp + 8] + sqj - 2.f * acc1;
        } else {
            d2a[q] = __builtin_inff();
            d2b[q] = __builtin_inff();
        }
    }
    if (rp < nrows)     select_row(d2a, j, b * ROI + i0 + rp,     b, knn);
    if (rp + 8 < nrows) select_row(d2b, j, b * ROI + i0 + rp + 8, b, knn);
}

// ---------------- K3/K4: edge MLP second layer + segment max ----------------
template<bool G3>
__global__ __launch_bounds__(256) void k_edge(
    const float* __restrict__ u, const float* __restrict__ v,
    const float* __restrict__ Wb, const float* __restrict__ bb,
    const int* __restrict__ nbr,
    const float* __restrict__ u3, const float* __restrict__ v3,
    float* __restrict__ aout, float* __restrict__ a3out)
{
    const int tid = threadIdx.x;
    const int c2 = tid & 31;
    const int n = blockIdx.x * 8 + (tid >> 5);
    float wcol[32];
    #pragma unroll
    for (int cc = 0; cc < 32; ++cc) wcol[cc] = Wb[cc * 32 + c2];
    const float bias = bb[c2];
    const float uc  = u[(size_t)n * 32 + c2];
    const float u3n = G3 ? u3[n] : 0.f;
    float amax  = -__builtin_inff();
    float a3max = -__builtin_inff();
    for (int e = 0; e < DEG; ++e) {
        int jn = nbr[(size_t)n * DEG + e];
        float hv = lrelu(uc + v[(size_t)jn * 32 + c2]);
        float macc = bias;
        #pragma unroll
        for (int cc = 0; cc < 32; ++cc)
            macc += __shfl(hv, cc, 32) * wcol[cc];
        amax = fmaxf(amax, macc);
        if (G3) a3max = fmaxf(a3max, u3n + v3[jn]);
    }
    aout[(size_t)n * 32 + c2] = amax;
    if (G3 && c2 == 0) a3out[n] = a3max;
}

// ---------------- K5: BN stats over N for a1(32) a2(32) a3(1) -> scale/shift ----
__global__ __launch_bounds__(256) void k_stats_nodes(
    const float* __restrict__ a1, const float* __restrict__ a2, const float* __restrict__ a3,
    const float* __restrict__ g1, const float* __restrict__ be1,
    const float* __restrict__ g2, const float* __restrict__ be2,
    const float* __restrict__ g3, const float* __restrict__ be3,
    float* __restrict__ st)
{
    const int ch = blockIdx.x;   // 0..64
    const int tid = threadIdx.x;
    const float* src; int stride; float gv, bev;
    if (ch < 32)      { src = a1 + ch;        stride = 32; gv = g1[ch];      bev = be1[ch]; }
    else if (ch < 64) { src = a2 + (ch - 32); stride = 32; gv = g2[ch - 32]; bev = be2[ch - 32]; }
    else              { src = a3;             stride = 1;  gv = g3[0];       bev = be3[0]; }
    float s = 0.f, ss = 0.f;
    for (int n = tid; n < NN; n += 256) {
        float v = src[(size_t)n * stride];
        s += v; ss += v * v;
    }
    __shared__ float S[256], SS[256];
    S[tid] = s; SS[tid] = ss; __syncthreads();
    for (int off = 128; off > 0; off >>= 1) {
        if (tid < off) { S[tid] += S[tid + off]; SS[tid] += SS[tid + off]; }
        __syncthreads();
    }
    if (tid == 0) {
        float mu  = S[0] * (1.f / NN);
        float var = SS[0] * (1.f / NN) - mu * mu;
        float sc  = gv * rsqrtf(var + EPSBN);
        st[ch * 2] = sc; st[ch * 2 + 1] = bev - mu * sc;
    }
}

// ---------------- K6: pooled readout -> z[B,332] = [p1(32) p2(32) x3(268)] ----
__global__ __launch_bounds__(256) void k_pool(
    const float* __restrict__ a1, const float* __restrict__ a2, const float* __restrict__ a3,
    const float* __restrict__ st, float* __restrict__ z)
{
    const int b = blockIdx.x, tid = threadIdx.x;
    const int c = tid & 63, grp = tid >> 6;
    const float* src = (c < 32) ? a1 : a2;
    const int ch = c & 31;
    const float sc = st[c * 2], sh = st[c * 2 + 1];
    float acc = 0.f;
    for (int i = grp; i < ROI; i += 4)
        acc += lrelu(src[(size_t)(b * ROI + i) * 32 + ch] * sc + sh);
    __shared__ float P[4][64];
    P[grp][c] = acc;
    __syncthreads();
    if (tid < 64) {
        float sum = P[0][tid] + P[1][tid] + P[2][tid] + P[3][tid];
        z[(size_t)b * 332 + tid] = sum * (1.f / ROI);
    }
    const float sc3 = st[128], sh3 = st[129];
    for (int i = tid; i < ROI; i += 256)
        z[(size_t)b * 332 + 64 + i] = lrelu(a3[b * ROI + i] * sc3 + sh3);
}

// ---------------- K7: h1 = z @ Wl1 + bl1 ----------------
__global__ __launch_bounds__(256) void k_fc1(
    const float* __restrict__ z, const float* __restrict__ Wl1, const float* __restrict__ bl1,
    float* __restrict__ h1)
{
    const int b = blockIdx.x, tid = threadIdx.x;
    __shared__ float zs[332];
    for (int i = tid; i < 332; i += 256) zs[i] = z[(size_t)b * 332 + i];
    __syncthreads();
    float acc = bl1[tid];
    for (int k = 0; k < 332; ++k) acc += zs[k] * Wl1[(size_t)k * 256 + tid];
    h1[(size_t)b * 256 + tid] = acc;
}

// ---------------- K8/K10: BN stats over B rows ----------------
__global__ void k_stats_rows(const float* __restrict__ h, int C,
                             const float* __restrict__ g, const float* __restrict__ be,
                             float* __restrict__ st)
{
    const int o = threadIdx.x;
    if (o >= C) return;
    float s = 0.f, ss = 0.f;
    for (int b2 = 0; b2 < NB; ++b2) {
        float v = h[(size_t)b2 * C + o];
        s += v; ss += v * v;
    }
    float mu  = s * (1.f / NB);
    float var = ss * (1.f / NB) - mu * mu;
    float sc  = g[o] * rsqrtf(var + EPSBN);
    st[o * 2] = sc; st[o * 2 + 1] = be[o] - mu * sc;
}

// ---------------- K9: h2 = leaky(bn(h1)) @ Wl2 + bl2 ----------------
__global__ __launch_bounds__(128) void k_fc2(
    const float* __restrict__ h1, const float* __restrict__ st,
    const float* __restrict__ Wl2, const float* __restrict__ bl2,
    float* __restrict__ h2)
{
    const int b = blockIdx.x, tid = threadIdx.x;
    __shared__ float hs[256];
    for (int i = tid; i < 256; i += 128)
        hs[i] = lrelu(h1[(size_t)b * 256 + i] * st[i * 2] + st[i * 2 + 1]);
    __syncthreads();
    float acc = bl2[tid];
    for (int k = 0; k < 256; ++k) acc += hs[k] * Wl2[(size_t)k * 128 + tid];
    h2[(size_t)b * 128 + tid] = acc;
}

// ---------------- K11: out = leaky(bn(h2)) @ Wl3 + bl3 ----------------
__global__ void k_fc3(
    const float* __restrict__ h2, const float* __restrict__ st,
    const float* __restrict__ Wl3, const float* __restrict__ bl3,
    float* __restrict__ out)
{
    const int b = threadIdx.x;
    if (b >= NB) return;
    float acc = bl3[0];
    for (int c = 0; c < 128; ++c)
        acc += lrelu(h2[(size_t)b * 128 + c] * st[c * 2] + st[c * 2 + 1]) * Wl3[c];
    out[b] = acc;
}

extern "C" void kernel_launch(void* const* d_in, const int* in_sizes, int n_in,
                              void* d_out, int out_size, void* d_ws, size_t ws_size,
                              hipStream_t stream)
{
    (void)in_sizes; (void)n_in; (void)out_size; (void)ws_size;
    const float* x   = (const float*)d_in[0];
    const int*   ei  = (const int*)d_in[1];   // [2,E] : first E = src (tgt = e/32 by construction)
    const float* W1a = (const float*)d_in[3];
    const float* b1a = (const float*)d_in[4];
    const float* W1b = (const float*)d_in[5];
    const float* b1b = (const float*)d_in[6];
    const float* g1  = (const float*)d_in[7];
    const float* be1 = (const float*)d_in[8];
    const float* W2a = (const float*)d_in[9];
    const float* b2a = (const float*)d_in[10];
    const float* W2b = (const float*)d_in[11];
    const float* b2b = (const float*)d_in[12];
    const float* g2  = (const float*)d_in[13];
    const float* be2 = (const float*)d_in[14];
    const float* W3  = (const float*)d_in[15];
    const float* b3  = (const float*)d_in[16];
    const float* g3  = (const float*)d_in[17];
    const float* be3 = (const float*)d_in[18];
    const float* Wl1 = (const float*)d_in[19];
    const float* bl1 = (const float*)d_in[20];
    const float* g4  = (const float*)d_in[21];
    const float* be4 = (const float*)d_in[22];
    const float* Wl2 = (const float*)d_in[23];
    const float* bl2 = (const float*)d_in[24];
    const float* g5  = (const float*)d_in[25];
    const float* be5 = (const float*)d_in[26];
    const float* Wl3 = (const float*)d_in[27];
    const float* bl3 = (const float*)d_in[28];

    float* ws  = (float*)d_ws;
    float* u1  = ws;
    float* v1  = u1 + (size_t)NN * 32;
    float* u2  = v1 + (size_t)NN * 32;
    float* v2  = u2 + (size_t)NN * 32;
    float* u3  = v2 + (size_t)NN * 32;
    float* v3  = u3 + NN;
    float* sqv = v3 + NN;
    float* a1  = sqv + NN;
    float* a2  = a1 + (size_t)NN * 32;
    float* a3  = a2 + (size_t)NN * 32;
    int*   knn = (int*)(a3 + NN);
    float* st  = (float*)(knn + (size_t)NN * 32);
    float* z   = st + 130;
    float* h1  = z + (size_t)NB * 332;
    float* h2  = h1 + (size_t)NB * 256;
    float* s4  = h2 + (size_t)NB * 128;
    float* s5  = s4 + 512;

    k_node_proj<<<NN / 16, 256, 0, stream>>>(x, W1a, b1a, W2a, b2a, W3, b3,
                                             u1, v1, u2, v2, u3, v3, sqv);
    k_knn_sel<<<dim3(17, NB), 256, 0, stream>>>(x, sqv, knn);
    k_edge<true><<<NN / 8, 256, 0, stream>>>(u1, v1, W1b, b1b, ei, u3, v3, a1, a3);
    k_edge<false><<<NN / 8, 256, 0, stream>>>(u2, v2, W2b, b2b, knn, nullptr, nullptr, a2, nullptr);
    k_stats_nodes<<<65, 256, 0, stream>>>(a1, a2, a3, g1, be1, g2, be2, g3, be3, st);
    k_pool<<<NB, 256, 0, stream>>>(a1, a2, a3, st, z);
    k_fc1<<<NB, 256, 0, stream>>>(z, Wl1, bl1, h1);
    k_stats_rows<<<1, 256, 0, stream>>>(h1, 256, g4, be4, s4);
    k_fc2<<<NB, 128, 0, stream>>>(h1, s4, Wl2, bl2, h2);
    k_stats_rows<<<1, 128, 0, stream>>>(h2, 128, g5, be5, s5);
    k_fc3<<<1, 64, 0, stream>>>(h2, s5, Wl3, bl3, (float*)d_out);
}

// Round 3
// 543.414 us; speedup vs baseline: 1.2760x; 1.2760x over previous
//
#include <hip/hip_runtime.h>

#define ROI   268
#define FDIM  268
#define NB    64
#define NN    (NB*ROI)     // 17152
#define CC    32
#define DEG   32
#define KSEL  32
#define SLOPE 0.33f
#define EPSBN 1e-5f

typedef __attribute__((ext_vector_type(8)))  short bf16x8;
typedef __attribute__((ext_vector_type(4)))  float f32x4;
typedef __attribute__((ext_vector_type(16))) float f32x16;

__device__ __forceinline__ float lrelu(float h) { return h >= 0.f ? h : SLOPE * h; }

__device__ __forceinline__ unsigned short bf16_rne(float f) {
    unsigned int u = __float_as_uint(f);
    unsigned int r = u + 0x7FFFu + ((u >> 16) & 1u);
    return (unsigned short)(r >> 16);
}
__device__ __forceinline__ float bf16_tof(unsigned short h) {
    return __uint_as_float(((unsigned int)h) << 16);
}

// ---------------- K1: per-node projections u1,v1,u2,v2,u3,v3,sq ----------------
__global__ __launch_bounds__(256) void k_node_proj(
    const float* __restrict__ x,
    const float* __restrict__ W1a, const float* __restrict__ b1a,
    const float* __restrict__ W2a, const float* __restrict__ b2a,
    const float* __restrict__ W3,  const float* __restrict__ b3,
    float* __restrict__ u1, float* __restrict__ v1,
    float* __restrict__ u2, float* __restrict__ v2,
    float* __restrict__ u3, float* __restrict__ v3, float* __restrict__ sqv)
{
    __shared__ float Xs[16][272];
    const int tid = threadIdx.x;
    const int n0  = blockIdx.x * 16;
    for (int idx = tid; idx < 16 * FDIM; idx += 256) {
        int i = idx / FDIM, f = idx - i * FDIM;
        Xs[i][f] = x[(size_t)(n0 + i) * FDIM + f];
    }
    __syncthreads();
    const int c = tid & 31;
    const int h = (tid >> 5) & 1;
    const int m = tid >> 6;
    const float* WA = (m < 2) ? W1a : W2a;
    const bool isU = (m & 1) == 0;
    float acc[8] = {0.f,0.f,0.f,0.f,0.f,0.f,0.f,0.f};
    for (int f = 0; f < FDIM; f += 4) {
        float w0, w1, w2, w3;
        {
            float wb0 = WA[(size_t)(FDIM + f + 0) * CC + c];
            float wb1 = WA[(size_t)(FDIM + f + 1) * CC + c];
            float wb2 = WA[(size_t)(FDIM + f + 2) * CC + c];
            float wb3 = WA[(size_t)(FDIM + f + 3) * CC + c];
            if (isU) {
                w0 = WA[(size_t)(f + 0) * CC + c] - wb0;
                w1 = WA[(size_t)(f + 1) * CC + c] - wb1;
                w2 = WA[(size_t)(f + 2) * CC + c] - wb2;
                w3 = WA[(size_t)(f + 3) * CC + c] - wb3;
            } else { w0 = wb0; w1 = wb1; w2 = wb2; w3 = wb3; }
        }
        #pragma unroll
        for (int i = 0; i < 8; ++i) {
            float4 xv = *(const float4*)&Xs[h * 8 + i][f];
            acc[i] += xv.x * w0 + xv.y * w1 + xv.z * w2 + xv.w * w3;
        }
    }
    float bias = 0.f;
    if (m == 0) bias = b1a[c];
    else if (m == 2) bias = b2a[c];
    float* outp = (m == 0) ? u1 : (m == 1) ? v1 : (m == 2) ? u2 : v2;
    #pragma unroll
    for (int i = 0; i < 8; ++i)
        outp[(size_t)(n0 + h * 8 + i) * CC + c] = acc[i] + bias;

    if (tid < 48) {
        int i = tid / 3, sel = tid - 3 * (tid / 3);
        float a = 0.f;
        if (sel == 0) {
            for (int f = 0; f < FDIM; ++f) a += Xs[i][f] * (W3[f] - W3[FDIM + f]);
            u3[n0 + i] = a + b3[0];
        } else if (sel == 1) {
            for (int f = 0; f < FDIM; ++f) a += Xs[i][f] * W3[FDIM + f];
            v3[n0 + i] = a;
        } else {
            for (int f = 0; f < FDIM; ++f) a += Xs[i][f] * Xs[i][f];
            sqv[n0 + i] = a;
        }
    }
}

// ---------------- K2: MFMA gram (split-bf16, 3 passes) + d2 + top-32 ----------------

__device__ __forceinline__ void select_row(float (&vals)[9], int sl, int nglob, int b,
                                           int* __restrict__ knn)
{
    for (int it = 0; it < KSEL; ++it) {
        float bv = vals[0]; int bj = sl;
        #pragma unroll
        for (int q = 1; q < 9; ++q) {
            int jj = q * 32 + sl;
            if (vals[q] < bv) { bv = vals[q]; bj = jj; }
        }
        #pragma unroll
        for (int mm = 16; mm > 0; mm >>= 1) {
            float ov = __shfl_xor(bv, mm, 32);
            int   oj = __shfl_xor(bj, mm, 32);
            if (ov < bv || (ov == bv && oj < bj)) { bv = ov; bj = oj; }
        }
        if (sl == 0) knn[(size_t)nglob * KSEL + it] = b * ROI + bj;
        #pragma unroll
        for (int q = 0; q < 9; ++q)
            if (bj == q * 32 + sl) vals[q] = __builtin_inff();
    }
}

__global__ __launch_bounds__(256) void k_knn_mfma(
    const float* __restrict__ x, const float* __restrict__ sqv, int* __restrict__ knn)
{
    __shared__ __align__(16) unsigned short Ah[2][9][64][8], Al[2][9][64][8];
    __shared__ __align__(16) unsigned short Bh[2][9][64][8], Bl[2][9][64][8];
    __shared__ float S[32][296];
    __shared__ float sqj[288];
    __shared__ float sqr[32];

    const int tid = threadIdx.x;
    const int b   = blockIdx.y;
    const int i0  = blockIdx.x * 32;
    const int nrows = min(32, ROI - i0);
    const size_t bN = (size_t)b * ROI;

    // ---- stage A (rows i0..i0+31) into split-bf16 frags ----
    for (int idx = tid; idx < 32 * 72; idx += 256) {
        const int r  = idx / 72;
        const int kc = idx - r * 72;
        const int k0 = kc * 4;
        float4 v = make_float4(0.f, 0.f, 0.f, 0.f);
        if (r < nrows && kc < 67)
            v = *(const float4*)&x[(bN + i0 + r) * FDIM + k0];
        const int ks = k0 >> 5;
        const int g  = (k0 & 31) >> 3;
        const int j0 = k0 & 7;
        const int ln = g * 16 + (r & 15);
        const int ra = r >> 4;
        unsigned short h0 = bf16_rne(v.x), h1 = bf16_rne(v.y), h2 = bf16_rne(v.z), h3 = bf16_rne(v.w);
        unsigned short l0 = bf16_rne(v.x - bf16_tof(h0)), l1 = bf16_rne(v.y - bf16_tof(h1));
        unsigned short l2 = bf16_rne(v.z - bf16_tof(h2)), l3 = bf16_rne(v.w - bf16_tof(h3));
        uint2 hp, lp;
        hp.x = (unsigned)h0 | ((unsigned)h1 << 16); hp.y = (unsigned)h2 | ((unsigned)h3 << 16);
        lp.x = (unsigned)l0 | ((unsigned)l1 << 16); lp.y = (unsigned)l2 | ((unsigned)l3 << 16);
        *(uint2*)&Ah[ra][ks][ln][j0] = hp;
        *(uint2*)&Al[ra][ks][ln][j0] = lp;
    }
    // FIX: blockDim=256 < 288 — must stride-loop, else sqj[256..287] is garbage
    for (int t = tid; t < 288; t += 256)
        sqj[t] = (t < ROI) ? sqv[bN + t] : __builtin_inff();
    if (tid < 32)  sqr[tid] = (tid < nrows) ? sqv[bN + i0 + tid] : 0.f;

    const int l  = tid & 63;
    const int w  = tid >> 6;
    const int ra = w >> 1;
    const int st = w & 1;

    for (int q = 0; q < 9; ++q) {
        // ---- stage B tile (cols q*32..q*32+31) ----
        for (int idx = tid; idx < 32 * 72; idx += 256) {
            const int cc = idx / 72;
            const int kc = idx - cc * 72;
            const int k0 = kc * 4;
            const int jcol = q * 32 + cc;
            float4 v = make_float4(0.f, 0.f, 0.f, 0.f);
            if (jcol < ROI && kc < 67)
                v = *(const float4*)&x[(bN + jcol) * FDIM + k0];
            const int ks = k0 >> 5;
            const int g  = (k0 & 31) >> 3;
            const int j0 = k0 & 7;
            const int ln = g * 16 + (cc & 15);
            const int sb = cc >> 4;
            unsigned short h0 = bf16_rne(v.x), h1 = bf16_rne(v.y), h2 = bf16_rne(v.z), h3 = bf16_rne(v.w);
            unsigned short l0 = bf16_rne(v.x - bf16_tof(h0)), l1 = bf16_rne(v.y - bf16_tof(h1));
            unsigned short l2 = bf16_rne(v.z - bf16_tof(h2)), l3 = bf16_rne(v.w - bf16_tof(h3));
            uint2 hp, lp;
            hp.x = (unsigned)h0 | ((unsigned)h1 << 16); hp.y = (unsigned)h2 | ((unsigned)h3 << 16);
            lp.x = (unsigned)l0 | ((unsigned)l1 << 16); lp.y = (unsigned)l2 | ((unsigned)l3 << 16);
            *(uint2*)&Bh[sb][ks][ln][j0] = hp;
            *(uint2*)&Bl[sb][ks][ln][j0] = lp;
        }
        __syncthreads();

        f32x4 acc = {0.f, 0.f, 0.f, 0.f};
        #pragma unroll
        for (int ks = 0; ks < 9; ++ks) {
            bf16x8 ah = *(const bf16x8*)&Ah[ra][ks][l][0];
            bf16x8 al = *(const bf16x8*)&Al[ra][ks][l][0];
            bf16x8 bh = *(const bf16x8*)&Bh[st][ks][l][0];
            bf16x8 bl = *(const bf16x8*)&Bl[st][ks][l][0];
            acc = __builtin_amdgcn_mfma_f32_16x16x32_bf16(ah, bh, acc, 0, 0, 0);
            acc = __builtin_amdgcn_mfma_f32_16x16x32_bf16(ah, bl, acc, 0, 0, 0);
            acc = __builtin_amdgcn_mfma_f32_16x16x32_bf16(al, bh, acc, 0, 0, 0);
        }
        const int col = q * 32 + st * 16 + (l & 15);
        const float sj = sqj[col];
        const int r0 = ra * 16 + (l >> 4) * 4;
        #pragma unroll
        for (int i = 0; i < 4; ++i)
            S[r0 + i][col] = sqr[r0 + i] + sj - 2.f * acc[i];
        __syncthreads();
    }

    const int g  = tid >> 5;
    const int sl = tid & 31;
    for (int rr = 0; rr < 4; ++rr) {
        const int row = g + rr * 8;
        if (row < nrows) {
            float vals[9];
            #pragma unroll
            for (int qq = 0; qq < 9; ++qq) vals[qq] = S[row][qq * 32 + sl];
            select_row(vals, sl, (int)(bN + i0 + row), b, knn);
        }
    }
}

// ---------------- K3/K4: edge MLP second layer via MFMA + segment max ----------------
template<bool G3>
__global__ __launch_bounds__(256) void k_edge_mfma(
    const float* __restrict__ u, const float* __restrict__ v,
    const float* __restrict__ Wb, const float* __restrict__ bb,
    const int* __restrict__ nbr,
    const float* __restrict__ u3, const float* __restrict__ v3,
    float* __restrict__ aout, float* __restrict__ a3out)
{
    const int tid  = threadIdx.x;
    const int l    = tid & 63;
    const int wv   = tid >> 6;
    const int half = l >> 5;
    const int e    = l & 31;

    bf16x8 bf0, bf1;
    #pragma unroll
    for (int j = 0; j < 8; ++j) {
        ((short*)&bf0)[j] = (short)bf16_rne(Wb[(half * 8 + j) * 32 + e]);
        ((short*)&bf1)[j] = (short)bf16_rne(Wb[(16 + half * 8 + j) * 32 + e]);
    }
    const float biasc = bb[e];

    for (int nn = 0; nn < 4; ++nn) {
        const int n  = blockIdx.x * 16 + wv * 4 + nn;
        const int jn = nbr[(size_t)n * DEG + e];

        float hv[16];
        #pragma unroll
        for (int s = 0; s < 2; ++s) {
            const int c0 = s * 16 + half * 8;
            float4 uv0 = *(const float4*)&u[(size_t)n  * 32 + c0];
            float4 uv1 = *(const float4*)&u[(size_t)n  * 32 + c0 + 4];
            float4 vv0 = *(const float4*)&v[(size_t)jn * 32 + c0];
            float4 vv1 = *(const float4*)&v[(size_t)jn * 32 + c0 + 4];
            hv[s*8+0] = lrelu(uv0.x + vv0.x);
            hv[s*8+1] = lrelu(uv0.y + vv0.y);
            hv[s*8+2] = lrelu(uv0.z + vv0.z);
            hv[s*8+3] = lrelu(uv0.w + vv0.w);
            hv[s*8+4] = lrelu(uv1.x + vv1.x);
            hv[s*8+5] = lrelu(uv1.y + vv1.y);
            hv[s*8+6] = lrelu(uv1.z + vv1.z);
            hv[s*8+7] = lrelu(uv1.w + vv1.w);
        }
        bf16x8 af0, af1;
        #pragma unroll
        for (int j = 0; j < 8; ++j) {
            ((short*)&af0)[j] = (short)bf16_rne(hv[j]);
            ((short*)&af1)[j] = (short)bf16_rne(hv[8 + j]);
        }
        f32x16 acc = {0.f,0.f,0.f,0.f,0.f,0.f,0.f,0.f,0.f,0.f,0.f,0.f,0.f,0.f,0.f,0.f};
        acc = __builtin_amdgcn_mfma_f32_32x32x16_bf16(af0, bf0, acc, 0, 0, 0);
        acc = __builtin_amdgcn_mfma_f32_32x32x16_bf16(af1, bf1, acc, 0, 0, 0);

        float mx = acc[0];
        #pragma unroll
        for (int r = 1; r < 16; ++r) mx = fmaxf(mx, acc[r]);
        mx = fmaxf(mx, __shfl_xor(mx, 32));
        if (l < 32) aout[(size_t)n * 32 + l] = mx + biasc;

        if (G3) {
            float a3v = u3[n] + v3[jn];
            #pragma unroll
            for (int mm = 16; mm > 0; mm >>= 1) a3v = fmaxf(a3v, __shfl_xor(a3v, mm));
            if (l == 0) a3out[n] = a3v;
        }
    }
}

// ---------------- K5: BN stats over N for a1(32) a2(32) a3(1) ----------------
__global__ __launch_bounds__(256) void k_stats_nodes(
    const float* __restrict__ a1, const float* __restrict__ a2, const float* __restrict__ a3,
    const float* __restrict__ g1, const float* __restrict__ be1,
    const float* __restrict__ g2, const float* __restrict__ be2,
    const float* __restrict__ g3, const float* __restrict__ be3,
    float* __restrict__ st)
{
    const int ch = blockIdx.x;
    const int tid = threadIdx.x;
    const float* src; int stride; float gv, bev;
    if (ch < 32)      { src = a1 + ch;        stride = 32; gv = g1[ch];      bev = be1[ch]; }
    else if (ch < 64) { src = a2 + (ch - 32); stride = 32; gv = g2[ch - 32]; bev = be2[ch - 32]; }
    else              { src = a3;             stride = 1;  gv = g3[0];       bev = be3[0]; }
    float s = 0.f, ss = 0.f;
    for (int n = tid; n < NN; n += 256) {
        float v = src[(size_t)n * stride];
        s += v; ss += v * v;
    }
    __shared__ float S[256], SS[256];
    S[tid] = s; SS[tid] = ss; __syncthreads();
    for (int off = 128; off > 0; off >>= 1) {
        if (tid < off) { S[tid] += S[tid + off]; SS[tid] += SS[tid + off]; }
        __syncthreads();
    }
    if (tid == 0) {
        float mu  = S[0] * (1.f / NN);
        float var = SS[0] * (1.f / NN) - mu * mu;
        float sc  = gv * rsqrtf(var + EPSBN);
        st[ch * 2] = sc; st[ch * 2 + 1] = bev - mu * sc;
    }
}

// ---------------- K6: pooled readout ----------------
__global__ __launch_bounds__(256) void k_pool(
    const float* __restrict__ a1, const float* __restrict__ a2, const float* __restrict__ a3,
    const float* __restrict__ st, float* __restrict__ z)
{
    const int b = blockIdx.x, tid = threadIdx.x;
    const int c = tid & 63, grp = tid >> 6;
    const float* src = (c < 32) ? a1 : a2;
    const int ch = c & 31;
    const float sc = st[c * 2], sh = st[c * 2 + 1];
    float acc = 0.f;
    for (int i = grp; i < ROI; i += 4)
        acc += lrelu(src[(size_t)(b * ROI + i) * 32 + ch] * sc + sh);
    __shared__ float P[4][64];
    P[grp][c] = acc;
    __syncthreads();
    if (tid < 64) {
        float sum = P[0][tid] + P[1][tid] + P[2][tid] + P[3][tid];
        z[(size_t)b * 332 + tid] = sum * (1.f / ROI);
    }
    const float sc3 = st[128], sh3 = st[129];
    for (int i = tid; i < ROI; i += 256)
        z[(size_t)b * 332 + 64 + i] = lrelu(a3[b * ROI + i] * sc3 + sh3);
}

// ---------------- K7: h1 = z @ Wl1 + bl1 ----------------
__global__ __launch_bounds__(256) void k_fc1(
    const float* __restrict__ z, const float* __restrict__ Wl1, const float* __restrict__ bl1,
    float* __restrict__ h1)
{
    const int b = blockIdx.x, tid = threadIdx.x;
    __shared__ float zs[332];
    for (int i = tid; i < 332; i += 256) zs[i] = z[(size_t)b * 332 + i];
    __syncthreads();
    float acc = bl1[tid];
    for (int k = 0; k < 332; ++k) acc += zs[k] * Wl1[(size_t)k * 256 + tid];
    h1[(size_t)b * 256 + tid] = acc;
}

// ---------------- K8/K10: BN stats over B rows ----------------
__global__ void k_stats_rows(const float* __restrict__ h, int C,
                             const float* __restrict__ g, const float* __restrict__ be,
                             float* __restrict__ st)
{
    const int o = threadIdx.x;
    if (o >= C) return;
    float s = 0.f, ss = 0.f;
    for (int b2 = 0; b2 < NB; ++b2) {
        float v = h[(size_t)b2 * C + o];
        s += v; ss += v * v;
    }
    float mu  = s * (1.f / NB);
    float var = ss * (1.f / NB) - mu * mu;
    float sc  = g[o] * rsqrtf(var + EPSBN);
    st[o * 2] = sc; st[o * 2 + 1] = be[o] - mu * sc;
}

// ---------------- K9: h2 = leaky(bn(h1)) @ Wl2 + bl2 ----------------
__global__ __launch_bounds__(128) void k_fc2(
    const float* __restrict__ h1, const float* __restrict__ st,
    const float* __restrict__ Wl2, const float* __restrict__ bl2,
    float* __restrict__ h2)
{
    const int b = blockIdx.x, tid = threadIdx.x;
    __shared__ float hs[256];
    for (int i = tid; i < 256; i += 128)
        hs[i] = lrelu(h1[(size_t)b * 256 + i] * st[i * 2] + st[i * 2 + 1]);
    __syncthreads();
    float acc = bl2[tid];
    for (int k = 0; k < 256; ++k) acc += hs[k] * Wl2[(size_t)k * 128 + tid];
    h2[(size_t)b * 128 + tid] = acc;
}

// ---------------- K11: out ----------------
__global__ void k_fc3(
    const float* __restrict__ h2, const float* __restrict__ st,
    const float* __restrict__ Wl3, const float* __restrict__ bl3,
    float* __restrict__ out)
{
    const int b = threadIdx.x;
    if (b >= NB) return;
    float acc = bl3[0];
    for (int c = 0; c < 128; ++c)
        acc += lrelu(h2[(size_t)b * 128 + c] * st[c * 2] + st[c * 2 + 1]) * Wl3[c];
    out[b] = acc;
}

extern "C" void kernel_launch(void* const* d_in, const int* in_sizes, int n_in,
                              void* d_out, int out_size, void* d_ws, size_t ws_size,
                              hipStream_t stream)
{
    (void)in_sizes; (void)n_in; (void)out_size; (void)ws_size;
    const float* x   = (const float*)d_in[0];
    const int*   ei  = (const int*)d_in[1];
    const float* W1a = (const float*)d_in[3];
    const float* b1a = (const float*)d_in[4];
    const float* W1b = (const float*)d_in[5];
    const float* b1b = (const float*)d_in[6];
    const float* g1  = (const float*)d_in[7];
    const float* be1 = (const float*)d_in[8];
    const float* W2a = (const float*)d_in[9];
    const float* b2a = (const float*)d_in[10];
    const float* W2b = (const float*)d_in[11];
    const float* b2b = (const float*)d_in[12];
    const float* g2  = (const float*)d_in[13];
    const float* be2 = (const float*)d_in[14];
    const float* W3  = (const float*)d_in[15];
    const float* b3  = (const float*)d_in[16];
    const float* g3  = (const float*)d_in[17];
    const float* be3 = (const float*)d_in[18];
    const float* Wl1 = (const float*)d_in[19];
    const float* bl1 = (const float*)d_in[20];
    const float* g4  = (const float*)d_in[21];
    const float* be4 = (const float*)d_in[22];
    const float* Wl2 = (const float*)d_in[23];
    const float* bl2 = (const float*)d_in[24];
    const float* g5  = (const float*)d_in[25];
    const float* be5 = (const float*)d_in[26];
    const float* Wl3 = (const float*)d_in[27];
    const float* bl3 = (const float*)d_in[28];

    float* ws  = (float*)d_ws;
    float* u1  = ws;
    float* v1  = u1 + (size_t)NN * 32;
    float* u2  = v1 + (size_t)NN * 32;
    float* v2  = u2 + (size_t)NN * 32;
    float* u3  = v2 + (size_t)NN * 32;
    float* v3  = u3 + NN;
    float* sqv = v3 + NN;
    float* a1  = sqv + NN;
    float* a2  = a1 + (size_t)NN * 32;
    float* a3  = a2 + (size_t)NN * 32;
    int*   knn = (int*)(a3 + NN);
    float* st  = (float*)(knn + (size_t)NN * 32);
    float* z   = st + 130;
    float* h1  = z + (size_t)NB * 332;
    float* h2  = h1 + (size_t)NB * 256;
    float* s4  = h2 + (size_t)NB * 128;
    float* s5  = s4 + 512;

    k_node_proj<<<NN / 16, 256, 0, stream>>>(x, W1a, b1a, W2a, b2a, W3, b3,
                                             u1, v1, u2, v2, u3, v3, sqv);
    k_knn_mfma<<<dim3(9, NB), 256, 0, stream>>>(x, sqv, knn);
    k_edge_mfma<true><<<NN / 16, 256, 0, stream>>>(u1, v1, W1b, b1b, ei, u3, v3, a1, a3);
    k_edge_mfma<false><<<NN / 16, 256, 0, stream>>>(u2, v2, W2b, b2b, knn, nullptr, nullptr, a2, nullptr);
    k_stats_nodes<<<65, 256, 0, stream>>>(a1, a2, a3, g1, be1, g2, be2, g3, be3, st);
    k_pool<<<NB, 256, 0, stream>>>(a1, a2, a3, st, z);
    k_fc1<<<NB, 256, 0, stream>>>(z, Wl1, bl1, h1);
    k_stats_rows<<<1, 256, 0, stream>>>(h1, 256, g4, be4, s4);
    k_fc2<<<NB, 128, 0, stream>>>(h1, s4, Wl2, bl2, h2);
    k_stats_rows<<<1, 128, 0, stream>>>(h2, 128, g5, be5, s5);
    k_fc3<<<1, 64, 0, stream>>>(h2, s5, Wl3, bl3, (float*)d_out);
}

// Round 4
// 308.651 us; speedup vs baseline: 2.2466x; 1.7606x over previous
//
#include <hip/hip_runtime.h>

#define ROI   268
#define FDIM  268
#define NB    64
#define NN    (NB*ROI)     // 17152
#define CC    32
#define DEG   32
#define KSEL  32
#define SLOPE 0.33f
#define EPSBN 1e-5f

typedef __attribute__((ext_vector_type(8)))  short bf16x8;
typedef __attribute__((ext_vector_type(4)))  float f32x4;
typedef __attribute__((ext_vector_type(16))) float f32x16;

__device__ __forceinline__ float lrelu(float h) { return h >= 0.f ? h : SLOPE * h; }

__device__ __forceinline__ unsigned short bf16_rne(float f) {
    unsigned int u = __float_as_uint(f);
    unsigned int r = u + 0x7FFFu + ((u >> 16) & 1u);
    return (unsigned short)(r >> 16);
}
__device__ __forceinline__ float bf16_tof(unsigned short h) {
    return __uint_as_float(((unsigned int)h) << 16);
}

// ---------------- K1: per-node projections u1,v1,u2,v2,u3,v3,sq ----------------
__global__ __launch_bounds__(256) void k_node_proj(
    const float* __restrict__ x,
    const float* __restrict__ W1a, const float* __restrict__ b1a,
    const float* __restrict__ W2a, const float* __restrict__ b2a,
    const float* __restrict__ W3,  const float* __restrict__ b3,
    float* __restrict__ u1, float* __restrict__ v1,
    float* __restrict__ u2, float* __restrict__ v2,
    float* __restrict__ u3, float* __restrict__ v3, float* __restrict__ sqv)
{
    __shared__ float Xs[16][272];
    const int tid = threadIdx.x;
    const int n0  = blockIdx.x * 16;
    for (int idx = tid; idx < 16 * FDIM; idx += 256) {
        int i = idx / FDIM, f = idx - i * FDIM;
        Xs[i][f] = x[(size_t)(n0 + i) * FDIM + f];
    }
    __syncthreads();
    const int c = tid & 31;
    const int h = (tid >> 5) & 1;
    const int m = tid >> 6;
    const float* WA = (m < 2) ? W1a : W2a;
    const bool isU = (m & 1) == 0;
    float acc[8] = {0.f,0.f,0.f,0.f,0.f,0.f,0.f,0.f};
    for (int f = 0; f < FDIM; f += 4) {
        float w0, w1, w2, w3;
        {
            float wb0 = WA[(size_t)(FDIM + f + 0) * CC + c];
            float wb1 = WA[(size_t)(FDIM + f + 1) * CC + c];
            float wb2 = WA[(size_t)(FDIM + f + 2) * CC + c];
            float wb3 = WA[(size_t)(FDIM + f + 3) * CC + c];
            if (isU) {
                w0 = WA[(size_t)(f + 0) * CC + c] - wb0;
                w1 = WA[(size_t)(f + 1) * CC + c] - wb1;
                w2 = WA[(size_t)(f + 2) * CC + c] - wb2;
                w3 = WA[(size_t)(f + 3) * CC + c] - wb3;
            } else { w0 = wb0; w1 = wb1; w2 = wb2; w3 = wb3; }
        }
        #pragma unroll
        for (int i = 0; i < 8; ++i) {
            float4 xv = *(const float4*)&Xs[h * 8 + i][f];
            acc[i] += xv.x * w0 + xv.y * w1 + xv.z * w2 + xv.w * w3;
        }
    }
    float bias = 0.f;
    if (m == 0) bias = b1a[c];
    else if (m == 2) bias = b2a[c];
    float* outp = (m == 0) ? u1 : (m == 1) ? v1 : (m == 2) ? u2 : v2;
    #pragma unroll
    for (int i = 0; i < 8; ++i)
        outp[(size_t)(n0 + h * 8 + i) * CC + c] = acc[i] + bias;

    if (tid < 48) {
        int i = tid / 3, sel = tid - 3 * (tid / 3);
        float a = 0.f;
        if (sel == 0) {
            for (int f = 0; f < FDIM; ++f) a += Xs[i][f] * (W3[f] - W3[FDIM + f]);
            u3[n0 + i] = a + b3[0];
        } else if (sel == 1) {
            for (int f = 0; f < FDIM; ++f) a += Xs[i][f] * W3[FDIM + f];
            v3[n0 + i] = a;
        } else {
            for (int f = 0; f < FDIM; ++f) a += Xs[i][f] * Xs[i][f];
            sqv[n0 + i] = a;
        }
    }
}

// ---------------- K1b: pack x into MFMA-fragment-ordered split-bf16 ----------------
// Layout: X{h,l}[ ((b*17 + ct)*9 + ks)*512 + l*8 + j ]  (shorts)
//   node = ct*16 + (l&15), k = ks*32 + (l>>4)*8 + j ; zero outside [0,ROI)x[0,FDIM)
__global__ __launch_bounds__(256) void k_pack(
    const float* __restrict__ x,
    unsigned short* __restrict__ Xh, unsigned short* __restrict__ Xl)
{
    const int gid = blockIdx.x * 256 + threadIdx.x;  // 64*17*9*64 total
    const int l   = gid & 63;
    const int f3  = gid >> 6;            // (b*17+ct)*9 + ks   (wave-uniform)
    const int ks  = f3 % 9;
    const int bc  = f3 / 9;
    const int ct  = bc % 17;
    const int b   = bc / 17;
    const int node = ct * 16 + (l & 15);
    const int k0   = ks * 32 + (l >> 4) * 8;
    float f[8];
    #pragma unroll
    for (int j = 0; j < 8; ++j) f[j] = 0.f;
    if (node < ROI) {
        const float* row = &x[((size_t)b * ROI + node) * FDIM];
        if (k0 + 3 < FDIM) { float4 v = *(const float4*)&row[k0];     f[0]=v.x; f[1]=v.y; f[2]=v.z; f[3]=v.w; }
        if (k0 + 7 < FDIM) { float4 v = *(const float4*)&row[k0 + 4]; f[4]=v.x; f[5]=v.y; f[6]=v.z; f[7]=v.w; }
    }
    unsigned short hh[8], ll[8];
    #pragma unroll
    for (int j = 0; j < 8; ++j) {
        hh[j] = bf16_rne(f[j]);
        ll[j] = bf16_rne(f[j] - bf16_tof(hh[j]));
    }
    uint4 hp, lp;
    hp.x = (unsigned)hh[0] | ((unsigned)hh[1] << 16); hp.y = (unsigned)hh[2] | ((unsigned)hh[3] << 16);
    hp.z = (unsigned)hh[4] | ((unsigned)hh[5] << 16); hp.w = (unsigned)hh[6] | ((unsigned)hh[7] << 16);
    lp.x = (unsigned)ll[0] | ((unsigned)ll[1] << 16); lp.y = (unsigned)ll[2] | ((unsigned)ll[3] << 16);
    lp.z = (unsigned)ll[4] | ((unsigned)ll[5] << 16); lp.w = (unsigned)ll[6] | ((unsigned)ll[7] << 16);
    const size_t base = (size_t)f3 * 512 + l * 8;
    *(uint4*)&Xh[base] = hp;
    *(uint4*)&Xl[base] = lp;
}

// ---------------- K2: KNN — A-frags in regs, B-frags from global, d2 in LDS ----------------
__device__ __forceinline__ void select_row(float (&vals)[9], int sl, int nglob, int b,
                                           int* __restrict__ knn)
{
    for (int it = 0; it < KSEL; ++it) {
        float bv = vals[0]; int bj = sl;
        #pragma unroll
        for (int q = 1; q < 9; ++q) {
            int jj = q * 32 + sl;
            if (vals[q] < bv) { bv = vals[q]; bj = jj; }
        }
        #pragma unroll
        for (int mm = 16; mm > 0; mm >>= 1) {
            float ov = __shfl_xor(bv, mm, 32);
            int   oj = __shfl_xor(bj, mm, 32);
            if (ov < bv || (ov == bv && oj < bj)) { bv = ov; bj = oj; }
        }
        if (sl == 0) knn[(size_t)nglob * KSEL + it] = b * ROI + bj;
        #pragma unroll
        for (int q = 0; q < 9; ++q)
            if (bj == q * 32 + sl) vals[q] = __builtin_inff();
    }
}

__global__ __launch_bounds__(256) void k_knn2(
    const unsigned short* __restrict__ Xh, const unsigned short* __restrict__ Xl,
    const float* __restrict__ sqv, int* __restrict__ knn)
{
    __shared__ float S[32][292];
    __shared__ float sqj[288];
    __shared__ float sqr[32];
    const int tid = threadIdx.x;
    const int b   = blockIdx.y;
    const int r0g = blockIdx.x * 32;
    const int nrows = min(32, ROI - r0g);
    const size_t bN = (size_t)b * ROI;

    for (int t = tid; t < 288; t += 256)
        sqj[t] = (t < ROI) ? sqv[bN + t] : __builtin_inff();
    if (tid < 32) sqr[tid] = (r0g + tid < ROI) ? sqv[bN + r0g + tid] : 0.f;
    for (int t = tid; t < 512; t += 256)
        S[t >> 4][272 + (t & 15)] = __builtin_inff();

    const int l  = tid & 63;
    const int w  = tid >> 6;
    const int ra = w & 1;
    const int rtile = min(blockIdx.x * 2 + ra, 16);

    bf16x8 Ah[9], Al[9];
    {
        const size_t abase = ((size_t)(b * 17 + rtile) * 9) * 512 + l * 8;
        #pragma unroll
        for (int ks = 0; ks < 9; ++ks) {
            Ah[ks] = *(const bf16x8*)&Xh[abase + ks * 512];
            Al[ks] = *(const bf16x8*)&Xl[abase + ks * 512];
        }
    }
    __syncthreads();

    for (int ct = (w >> 1); ct < 17; ct += 2) {
        const size_t bbase = ((size_t)(b * 17 + ct) * 9) * 512 + l * 8;
        f32x4 acc = {0.f, 0.f, 0.f, 0.f};
        #pragma unroll
        for (int ks = 0; ks < 9; ++ks) {
            bf16x8 bh = *(const bf16x8*)&Xh[bbase + ks * 512];
            bf16x8 bl = *(const bf16x8*)&Xl[bbase + ks * 512];
            acc = __builtin_amdgcn_mfma_f32_16x16x32_bf16(Ah[ks], bh, acc, 0, 0, 0);
            acc = __builtin_amdgcn_mfma_f32_16x16x32_bf16(Ah[ks], bl, acc, 0, 0, 0);
            acc = __builtin_amdgcn_mfma_f32_16x16x32_bf16(Al[ks], bh, acc, 0, 0, 0);
        }
        const int col = ct * 16 + (l & 15);
        const float sj = sqj[col];
        const int rr = ra * 16 + (l >> 4) * 4;
        #pragma unroll
        for (int i = 0; i < 4; ++i)
            S[rr + i][col] = sqr[rr + i] + sj - 2.f * acc[i];
    }
    __syncthreads();

    const int g = tid >> 5, sl = tid & 31;
    for (int rr2 = 0; rr2 < 4; ++rr2) {
        const int row = g + rr2 * 8;
        if (row < nrows) {
            float vals[9];
            #pragma unroll
            for (int q = 0; q < 9; ++q) vals[q] = S[row][q * 32 + sl];
            select_row(vals, sl, (int)(bN + r0g + row), b, knn);
        }
    }
}

// ---------------- K3/K4: edge MLP second layer via MFMA + segment max ----------------
template<bool G3>
__global__ __launch_bounds__(256) void k_edge_mfma(
    const float* __restrict__ u, const float* __restrict__ v,
    const float* __restrict__ Wb, const float* __restrict__ bb,
    const int* __restrict__ nbr,
    const float* __restrict__ u3, const float* __restrict__ v3,
    float* __restrict__ aout, float* __restrict__ a3out)
{
    const int tid  = threadIdx.x;
    const int l    = tid & 63;
    const int wv   = tid >> 6;
    const int half = l >> 5;
    const int e    = l & 31;

    bf16x8 bf0, bf1;
    #pragma unroll
    for (int j = 0; j < 8; ++j) {
        ((short*)&bf0)[j] = (short)bf16_rne(Wb[(half * 8 + j) * 32 + e]);
        ((short*)&bf1)[j] = (short)bf16_rne(Wb[(16 + half * 8 + j) * 32 + e]);
    }
    const float biasc = bb[e];

    for (int nn = 0; nn < 4; ++nn) {
        const int n  = blockIdx.x * 16 + wv * 4 + nn;
        const int jn = nbr[(size_t)n * DEG + e];

        float hv[16];
        #pragma unroll
        for (int s = 0; s < 2; ++s) {
            const int c0 = s * 16 + half * 8;
            float4 uv0 = *(const float4*)&u[(size_t)n  * 32 + c0];
            float4 uv1 = *(const float4*)&u[(size_t)n  * 32 + c0 + 4];
            float4 vv0 = *(const float4*)&v[(size_t)jn * 32 + c0];
            float4 vv1 = *(const float4*)&v[(size_t)jn * 32 + c0 + 4];
            hv[s*8+0] = lrelu(uv0.x + vv0.x);
            hv[s*8+1] = lrelu(uv0.y + vv0.y);
            hv[s*8+2] = lrelu(uv0.z + vv0.z);
            hv[s*8+3] = lrelu(uv0.w + vv0.w);
            hv[s*8+4] = lrelu(uv1.x + vv1.x);
            hv[s*8+5] = lrelu(uv1.y + vv1.y);
            hv[s*8+6] = lrelu(uv1.z + vv1.z);
            hv[s*8+7] = lrelu(uv1.w + vv1.w);
        }
        bf16x8 af0, af1;
        #pragma unroll
        for (int j = 0; j < 8; ++j) {
            ((short*)&af0)[j] = (short)bf16_rne(hv[j]);
            ((short*)&af1)[j] = (short)bf16_rne(hv[8 + j]);
        }
        f32x16 acc = {0.f,0.f,0.f,0.f,0.f,0.f,0.f,0.f,0.f,0.f,0.f,0.f,0.f,0.f,0.f,0.f};
        acc = __builtin_amdgcn_mfma_f32_32x32x16_bf16(af0, bf0, acc, 0, 0, 0);
        acc = __builtin_amdgcn_mfma_f32_32x32x16_bf16(af1, bf1, acc, 0, 0, 0);

        float mx = acc[0];
        #pragma unroll
        for (int r = 1; r < 16; ++r) mx = fmaxf(mx, acc[r]);
        mx = fmaxf(mx, __shfl_xor(mx, 32));
        if (l < 32) aout[(size_t)n * 32 + l] = mx + biasc;

        if (G3) {
            float a3v = u3[n] + v3[jn];
            #pragma unroll
            for (int mm = 16; mm > 0; mm >>= 1) a3v = fmaxf(a3v, __shfl_xor(a3v, mm));
            if (l == 0) a3out[n] = a3v;
        }
    }
}

// ---------------- K5a: coalesced per-chunk partial BN stats for a1,a2 ----------------
__global__ __launch_bounds__(256) void k_stats1(
    const float* __restrict__ a1, const float* __restrict__ a2,
    float* __restrict__ part)   // [64][128] : s1(32) q1(32) s2(32) q2(32)
{
    const int p = blockIdx.x;
    const int tid = threadIdx.x;
    const int ch = tid & 31, sub = tid >> 5;
    const size_t base = (size_t)p * ROI;
    float s1 = 0.f, q1 = 0.f, s2 = 0.f, q2 = 0.f;
    for (int n = sub; n < ROI; n += 8) {
        float v1 = a1[(base + n) * 32 + ch];
        float v2 = a2[(base + n) * 32 + ch];
        s1 += v1; q1 += v1 * v1; s2 += v2; q2 += v2 * v2;
    }
    __shared__ float L[4][256];
    L[0][tid] = s1; L[1][tid] = q1; L[2][tid] = s2; L[3][tid] = q2;
    __syncthreads();
    if (tid < 128) {
        const int a = tid >> 5, c = tid & 31;
        float s = 0.f;
        #pragma unroll
        for (int k = 0; k < 8; ++k) s += L[a][c + 32 * k];
        part[p * 128 + a * 32 + c] = s;
    }
}

// ---------------- K5b: finalize BN scale/shift (a1,a2 from partials; a3 full scan) ----
__global__ __launch_bounds__(256) void k_stats2(
    const float* __restrict__ part, const float* __restrict__ a3,
    const float* __restrict__ g1, const float* __restrict__ be1,
    const float* __restrict__ g2, const float* __restrict__ be2,
    const float* __restrict__ g3, const float* __restrict__ be3,
    float* __restrict__ st)
{
    const int tid = threadIdx.x;
    float s = 0.f, q = 0.f;
    for (int n = tid; n < NN; n += 256) { float v = a3[n]; s += v; q += v * v; }
    __shared__ float S3[256], Q3[256];
    S3[tid] = s; Q3[tid] = q; __syncthreads();
    for (int off = 128; off > 0; off >>= 1) {
        if (tid < off) { S3[tid] += S3[tid + off]; Q3[tid] += Q3[tid + off]; }
        __syncthreads();
    }
    if (tid < 64) {
        const int a = (tid >> 5) * 2, c = tid & 31;
        float ss = 0.f, qq = 0.f;
        for (int p = 0; p < 64; ++p) {
            ss += part[p * 128 + a * 32 + c];
            qq += part[p * 128 + (a + 1) * 32 + c];
        }
        float gv = (tid < 32) ? g1[c] : g2[c];
        float bv = (tid < 32) ? be1[c] : be2[c];
        float mu  = ss * (1.f / NN);
        float var = qq * (1.f / NN) - mu * mu;
        float sc  = gv * rsqrtf(var + EPSBN);
        st[tid * 2] = sc; st[tid * 2 + 1] = bv - mu * sc;
    }
    if (tid == 64) {
        float mu  = S3[0] * (1.f / NN);
        float var = Q3[0] * (1.f / NN) - mu * mu;
        float sc  = g3[0] * rsqrtf(var + EPSBN);
        st[128] = sc; st[129] = be3[0] - mu * sc;
    }
}

// ---------------- K6: pooled readout ----------------
__global__ __launch_bounds__(256) void k_pool(
    const float* __restrict__ a1, const float* __restrict__ a2, const float* __restrict__ a3,
    const float* __restrict__ st, float* __restrict__ z)
{
    const int b = blockIdx.x, tid = threadIdx.x;
    const int c = tid & 63, grp = tid >> 6;
    const float* src = (c < 32) ? a1 : a2;
    const int ch = c & 31;
    const float sc = st[c * 2], sh = st[c * 2 + 1];
    float acc = 0.f;
    for (int i = grp; i < ROI; i += 4)
        acc += lrelu(src[(size_t)(b * ROI + i) * 32 + ch] * sc + sh);
    __shared__ float P[4][64];
    P[grp][c] = acc;
    __syncthreads();
    if (tid < 64) {
        float sum = P[0][tid] + P[1][tid] + P[2][tid] + P[3][tid];
        z[(size_t)b * 332 + tid] = sum * (1.f / ROI);
    }
    const float sc3 = st[128], sh3 = st[129];
    for (int i = tid; i < ROI; i += 256)
        z[(size_t)b * 332 + 64 + i] = lrelu(a3[b * ROI + i] * sc3 + sh3);
}

// ---------------- K7: h1 = z @ Wl1 + bl1 ----------------
__global__ __launch_bounds__(256) void k_fc1(
    const float* __restrict__ z, const float* __restrict__ Wl1, const float* __restrict__ bl1,
    float* __restrict__ h1)
{
    const int b = blockIdx.x, tid = threadIdx.x;
    __shared__ float zs[332];
    for (int i = tid; i < 332; i += 256) zs[i] = z[(size_t)b * 332 + i];
    __syncthreads();
    float acc = bl1[tid];
    for (int k = 0; k < 332; ++k) acc += zs[k] * Wl1[(size_t)k * 256 + tid];
    h1[(size_t)b * 256 + tid] = acc;
}

// ---------------- K8/K10: BN stats over B rows ----------------
__global__ void k_stats_rows(const float* __restrict__ h, int C,
                             const float* __restrict__ g, const float* __restrict__ be,
                             float* __restrict__ st)
{
    const int o = threadIdx.x;
    if (o >= C) return;
    float s = 0.f, ss = 0.f;
    for (int b2 = 0; b2 < NB; ++b2) {
        float v = h[(size_t)b2 * C + o];
        s += v; ss += v * v;
    }
    float mu  = s * (1.f / NB);
    float var = ss * (1.f / NB) - mu * mu;
    float sc  = g[o] * rsqrtf(var + EPSBN);
    st[o * 2] = sc; st[o * 2 + 1] = be[o] - mu * sc;
}

// ---------------- K9: h2 = leaky(bn(h1)) @ Wl2 + bl2 ----------------
__global__ __launch_bounds__(128) void k_fc2(
    const float* __restrict__ h1, const float* __restrict__ st,
    const float* __restrict__ Wl2, const float* __restrict__ bl2,
    float* __restrict__ h2)
{
    const int b = blockIdx.x, tid = threadIdx.x;
    __shared__ float hs[256];
    for (int i = tid; i < 256; i += 128)
        hs[i] = lrelu(h1[(size_t)b * 256 + i] * st[i * 2] + st[i * 2 + 1]);
    __syncthreads();
    float acc = bl2[tid];
    for (int k = 0; k < 256; ++k) acc += hs[k] * Wl2[(size_t)k * 128 + tid];
    h2[(size_t)b * 128 + tid] = acc;
}

// ---------------- K11: out ----------------
__global__ void k_fc3(
    const float* __restrict__ h2, const float* __restrict__ st,
    const float* __restrict__ Wl3, const float* __restrict__ bl3,
    float* __restrict__ out)
{
    const int b = threadIdx.x;
    if (b >= NB) return;
    float acc = bl3[0];
    for (int c = 0; c < 128; ++c)
        acc += lrelu(h2[(size_t)b * 128 + c] * st[c * 2] + st[c * 2 + 1]) * Wl3[c];
    out[b] = acc;
}

extern "C" void kernel_launch(void* const* d_in, const int* in_sizes, int n_in,
                              void* d_out, int out_size, void* d_ws, size_t ws_size,
                              hipStream_t stream)
{
    (void)in_sizes; (void)n_in; (void)out_size; (void)ws_size;
    const float* x   = (const float*)d_in[0];
    const int*   ei  = (const int*)d_in[1];
    const float* W1a = (const float*)d_in[3];
    const float* b1a = (const float*)d_in[4];
    const float* W1b = (const float*)d_in[5];
    const float* b1b = (const float*)d_in[6];
    const float* g1  = (const float*)d_in[7];
    const float* be1 = (const float*)d_in[8];
    const float* W2a = (const float*)d_in[9];
    const float* b2a = (const float*)d_in[10];
    const float* W2b = (const float*)d_in[11];
    const float* b2b = (const float*)d_in[12];
    const float* g2  = (const float*)d_in[13];
    const float* be2 = (const float*)d_in[14];
    const float* W3  = (const float*)d_in[15];
    const float* b3  = (const float*)d_in[16];
    const float* g3  = (const float*)d_in[17];
    const float* be3 = (const float*)d_in[18];
    const float* Wl1 = (const float*)d_in[19];
    const float* bl1 = (const float*)d_in[20];
    const float* g4  = (const float*)d_in[21];
    const float* be4 = (const float*)d_in[22];
    const float* Wl2 = (const float*)d_in[23];
    const float* bl2 = (const float*)d_in[24];
    const float* g5  = (const float*)d_in[25];
    const float* be5 = (const float*)d_in[26];
    const float* Wl3 = (const float*)d_in[27];
    const float* bl3 = (const float*)d_in[28];

    float* ws  = (float*)d_ws;
    float* u1  = ws;
    float* v1  = u1 + (size_t)NN * 32;
    float* u2  = v1 + (size_t)NN * 32;
    float* v2  = u2 + (size_t)NN * 32;
    float* u3  = v2 + (size_t)NN * 32;
    float* v3  = u3 + NN;
    float* sqv = v3 + NN;
    float* a1  = sqv + NN;
    float* a2  = a1 + (size_t)NN * 32;
    float* a3  = a2 + (size_t)NN * 32;
    int*   knn = (int*)(a3 + NN);
    float* st  = (float*)(knn + (size_t)NN * 32);
    float* z   = st + 130;
    float* h1  = z + (size_t)NB * 332;
    float* h2  = h1 + (size_t)NB * 256;
    float* s4  = h2 + (size_t)NB * 128;
    float* s5  = s4 + 512;
    float* part = s5 + 512;                         // [64][128]
    unsigned short* Xh = (unsigned short*)(((uintptr_t)(part + 64 * 128) + 255) & ~(uintptr_t)255);
    unsigned short* Xl = Xh + (size_t)64 * 17 * 9 * 512;   // 5,013,504 shorts each

    k_pack<<<(64 * 17 * 9 * 64) / 256, 256, 0, stream>>>(x, Xh, Xl);
    k_node_proj<<<NN / 16, 256, 0, stream>>>(x, W1a, b1a, W2a, b2a, W3, b3,
                                             u1, v1, u2, v2, u3, v3, sqv);
    k_knn2<<<dim3(9, NB), 256, 0, stream>>>(Xh, Xl, sqv, knn);
    k_edge_mfma<true><<<NN / 16, 256, 0, stream>>>(u1, v1, W1b, b1b, ei, u3, v3, a1, a3);
    k_edge_mfma<false><<<NN / 16, 256, 0, stream>>>(u2, v2, W2b, b2b, knn, nullptr, nullptr, a2, nullptr);
    k_stats1<<<64, 256, 0, stream>>>(a1, a2, part);
    k_stats2<<<1, 256, 0, stream>>>(part, a3, g1, be1, g2, be2, g3, be3, st);
    k_pool<<<NB, 256, 0, stream>>>(a1, a2, a3, st, z);
    k_fc1<<<NB, 256, 0, stream>>>(z, Wl1, bl1, h1);
    k_stats_rows<<<1, 256, 0, stream>>>(h1, 256, g4, be4, s4);
    k_fc2<<<NB, 128, 0, stream>>>(h1, s4, Wl2, bl2, h2);
    k_stats_rows<<<1, 128, 0, stream>>>(h2, 128, g5, be5, s5);
    k_fc3<<<1, 64, 0, stream>>>(h2, s5, Wl3, bl3, (float*)d_out);
}

// Round 5
// 270.623 us; speedup vs baseline: 2.5623x; 1.1405x over previous
//
#include <hip/hip_runtime.h>

#define ROI   268
#define FDIM  268
#define NB    64
#define NN    (NB*ROI)     // 17152
#define CC    32
#define DEG   32
#define KSEL  32
#define SLOPE 0.33f
#define EPSBN 1e-5f

typedef __attribute__((ext_vector_type(8)))  short bf16x8;
typedef __attribute__((ext_vector_type(4)))  float f32x4;
typedef __attribute__((ext_vector_type(16))) float f32x16;

__device__ __forceinline__ float lrelu(float h) { return h >= 0.f ? h : SLOPE * h; }

__device__ __forceinline__ unsigned short bf16_rne(float f) {
    unsigned int u = __float_as_uint(f);
    unsigned int r = u + 0x7FFFu + ((u >> 16) & 1u);
    return (unsigned short)(r >> 16);
}
__device__ __forceinline__ float bf16_tof(unsigned short h) {
    return __uint_as_float(((unsigned int)h) << 16);
}

// ---------------- K1: per-node projections u1,v1,u2,v2,u3,v3,sq ----------------
__global__ __launch_bounds__(256) void k_node_proj(
    const float* __restrict__ x,
    const float* __restrict__ W1a, const float* __restrict__ b1a,
    const float* __restrict__ W2a, const float* __restrict__ b2a,
    const float* __restrict__ W3,  const float* __restrict__ b3,
    float* __restrict__ u1, float* __restrict__ v1,
    float* __restrict__ u2, float* __restrict__ v2,
    float* __restrict__ u3, float* __restrict__ v3, float* __restrict__ sqv)
{
    __shared__ float Xs[16][272];
    const int tid = threadIdx.x;
    const int n0  = blockIdx.x * 16;
    for (int idx = tid; idx < 16 * FDIM; idx += 256) {
        int i = idx / FDIM, f = idx - i * FDIM;
        Xs[i][f] = x[(size_t)(n0 + i) * FDIM + f];
    }
    __syncthreads();
    const int c = tid & 31;
    const int h = (tid >> 5) & 1;
    const int m = tid >> 6;
    const float* WA = (m < 2) ? W1a : W2a;
    const bool isU = (m & 1) == 0;
    float acc[8] = {0.f,0.f,0.f,0.f,0.f,0.f,0.f,0.f};
    for (int f = 0; f < FDIM; f += 4) {
        float w0, w1, w2, w3;
        {
            float wb0 = WA[(size_t)(FDIM + f + 0) * CC + c];
            float wb1 = WA[(size_t)(FDIM + f + 1) * CC + c];
            float wb2 = WA[(size_t)(FDIM + f + 2) * CC + c];
            float wb3 = WA[(size_t)(FDIM + f + 3) * CC + c];
            if (isU) {
                w0 = WA[(size_t)(f + 0) * CC + c] - wb0;
                w1 = WA[(size_t)(f + 1) * CC + c] - wb1;
                w2 = WA[(size_t)(f + 2) * CC + c] - wb2;
                w3 = WA[(size_t)(f + 3) * CC + c] - wb3;
            } else { w0 = wb0; w1 = wb1; w2 = wb2; w3 = wb3; }
        }
        #pragma unroll
        for (int i = 0; i < 8; ++i) {
            float4 xv = *(const float4*)&Xs[h * 8 + i][f];
            acc[i] += xv.x * w0 + xv.y * w1 + xv.z * w2 + xv.w * w3;
        }
    }
    float bias = 0.f;
    if (m == 0) bias = b1a[c];
    else if (m == 2) bias = b2a[c];
    float* outp = (m == 0) ? u1 : (m == 1) ? v1 : (m == 2) ? u2 : v2;
    #pragma unroll
    for (int i = 0; i < 8; ++i)
        outp[(size_t)(n0 + h * 8 + i) * CC + c] = acc[i] + bias;

    if (tid < 48) {
        int i = tid / 3, sel = tid - 3 * (tid / 3);
        float a = 0.f;
        if (sel == 0) {
            for (int f = 0; f < FDIM; ++f) a += Xs[i][f] * (W3[f] - W3[FDIM + f]);
            u3[n0 + i] = a + b3[0];
        } else if (sel == 1) {
            for (int f = 0; f < FDIM; ++f) a += Xs[i][f] * W3[FDIM + f];
            v3[n0 + i] = a;
        } else {
            for (int f = 0; f < FDIM; ++f) a += Xs[i][f] * Xs[i][f];
            sqv[n0 + i] = a;
        }
    }
}

// ---------------- K1b: pack x into MFMA-fragment-ordered split-bf16 ----------------
__global__ __launch_bounds__(256) void k_pack(
    const float* __restrict__ x,
    unsigned short* __restrict__ Xh, unsigned short* __restrict__ Xl)
{
    const int gid = blockIdx.x * 256 + threadIdx.x;
    const int l   = gid & 63;
    const int f3  = gid >> 6;
    const int ks  = f3 % 9;
    const int bc  = f3 / 9;
    const int ct  = bc % 17;
    const int b   = bc / 17;
    const int node = ct * 16 + (l & 15);
    const int k0   = ks * 32 + (l >> 4) * 8;
    float f[8];
    #pragma unroll
    for (int j = 0; j < 8; ++j) f[j] = 0.f;
    if (node < ROI) {
        const float* row = &x[((size_t)b * ROI + node) * FDIM];
        if (k0 + 3 < FDIM) { float4 v = *(const float4*)&row[k0];     f[0]=v.x; f[1]=v.y; f[2]=v.z; f[3]=v.w; }
        if (k0 + 7 < FDIM) { float4 v = *(const float4*)&row[k0 + 4]; f[4]=v.x; f[5]=v.y; f[6]=v.z; f[7]=v.w; }
    }
    unsigned short hh[8], ll[8];
    #pragma unroll
    for (int j = 0; j < 8; ++j) {
        hh[j] = bf16_rne(f[j]);
        ll[j] = bf16_rne(f[j] - bf16_tof(hh[j]));
    }
    uint4 hp, lp;
    hp.x = (unsigned)hh[0] | ((unsigned)hh[1] << 16); hp.y = (unsigned)hh[2] | ((unsigned)hh[3] << 16);
    hp.z = (unsigned)hh[4] | ((unsigned)hh[5] << 16); hp.w = (unsigned)hh[6] | ((unsigned)hh[7] << 16);
    lp.x = (unsigned)ll[0] | ((unsigned)ll[1] << 16); lp.y = (unsigned)ll[2] | ((unsigned)ll[3] << 16);
    lp.z = (unsigned)ll[4] | ((unsigned)ll[5] << 16); lp.w = (unsigned)ll[6] | ((unsigned)ll[7] << 16);
    const size_t base = (size_t)f3 * 512 + l * 8;
    *(uint4*)&Xh[base] = hp;
    *(uint4*)&Xl[base] = lp;
}

// ---------------- K2a: d2 matrix via MFMA (A-frags in regs, B from global) ----------
// d2 layout: [64][288 rows][288 cols] fp32; rows >= ROI / cols >= ROI: cols padded inf
__global__ __launch_bounds__(256) void k_dist(
    const unsigned short* __restrict__ Xh, const unsigned short* __restrict__ Xl,
    const float* __restrict__ sqv, float* __restrict__ d2)
{
    __shared__ float sqj[288];
    __shared__ float sqr[32];
    const int tid = threadIdx.x;
    const int b   = blockIdx.y;
    const int r0g = blockIdx.x * 32;
    const size_t bN = (size_t)b * ROI;

    for (int t = tid; t < 288; t += 256)
        sqj[t] = (t < ROI) ? sqv[bN + t] : __builtin_inff();
    if (tid < 32) sqr[tid] = (r0g + tid < ROI) ? sqv[bN + r0g + tid] : 0.f;

    const int l  = tid & 63;
    const int w  = tid >> 6;
    const int ra = w & 1;
    const int rtile = min(blockIdx.x * 2 + ra, 16);

    bf16x8 Ah[9], Al[9];
    {
        const size_t abase = ((size_t)(b * 17 + rtile) * 9) * 512 + l * 8;
        #pragma unroll
        for (int ks = 0; ks < 9; ++ks) {
            Ah[ks] = *(const bf16x8*)&Xh[abase + ks * 512];
            Al[ks] = *(const bf16x8*)&Xl[abase + ks * 512];
        }
    }
    __syncthreads();

    float* drow = &d2[(size_t)b * 288 * 288];
    for (int ct = (w >> 1); ct < 17; ct += 2) {
        const size_t bbase = ((size_t)(b * 17 + ct) * 9) * 512 + l * 8;
        f32x4 acc = {0.f, 0.f, 0.f, 0.f};
        #pragma unroll
        for (int ks = 0; ks < 9; ++ks) {
            bf16x8 bh = *(const bf16x8*)&Xh[bbase + ks * 512];
            bf16x8 bl = *(const bf16x8*)&Xl[bbase + ks * 512];
            acc = __builtin_amdgcn_mfma_f32_16x16x32_bf16(Ah[ks], bh, acc, 0, 0, 0);
            acc = __builtin_amdgcn_mfma_f32_16x16x32_bf16(Ah[ks], bl, acc, 0, 0, 0);
            acc = __builtin_amdgcn_mfma_f32_16x16x32_bf16(Al[ks], bh, acc, 0, 0, 0);
        }
        const int col = ct * 16 + (l & 15);
        const float sj = sqj[col];
        const int rr = ra * 16 + (l >> 4) * 4;
        #pragma unroll
        for (int i = 0; i < 4; ++i)
            drow[(size_t)(r0g + rr + i) * 288 + col] = sqr[rr + i] + sj - 2.f * acc[i];
    }
    // pad cols 272..287 of the 16 "ct=17" positions? not needed: col<=271 always written,
    // cols 272..287 handled below
    for (int t = tid; t < 32 * 16; t += 256) {
        const int r = t >> 4, cc = 272 + (t & 15);
        drow[(size_t)(r0g + r) * 288 + cc] = __builtin_inff();
    }
}

// ---------------- K2b: top-32 selection, one 32-lane group per row ----------------
__global__ __launch_bounds__(256) void k_sel(
    const float* __restrict__ d2, int* __restrict__ knn)
{
    const int grp = blockIdx.x * 8 + (threadIdx.x >> 5);  // 0..17151
    const int sl  = threadIdx.x & 31;
    const int b   = grp / ROI;
    const int row = grp - b * ROI;
    const float* src = &d2[((size_t)b * 288 + row) * 288];

    float vals[9];
    #pragma unroll
    for (int q = 0; q < 9; ++q) vals[q] = src[q * 32 + sl];

    int* out = &knn[(size_t)grp * KSEL];
    const int cbase = b * ROI;
    for (int it = 0; it < KSEL; ++it) {
        float bv = vals[0]; int bj = sl;
        #pragma unroll
        for (int q = 1; q < 9; ++q) {
            int jj = q * 32 + sl;
            if (vals[q] < bv) { bv = vals[q]; bj = jj; }
        }
        #pragma unroll
        for (int mm = 16; mm > 0; mm >>= 1) {
            float ov = __shfl_xor(bv, mm, 32);
            int   oj = __shfl_xor(bj, mm, 32);
            if (ov < bv || (ov == bv && oj < bj)) { bv = ov; bj = oj; }
        }
        if (sl == 0) out[it] = cbase + bj;
        #pragma unroll
        for (int q = 0; q < 9; ++q)
            if (bj == q * 32 + sl) vals[q] = __builtin_inff();
    }
}

// ---------------- K3/K4: edge MLP second layer via MFMA + segment max ----------------
template<bool G3>
__global__ __launch_bounds__(256) void k_edge_mfma(
    const float* __restrict__ u, const float* __restrict__ v,
    const float* __restrict__ Wb, const float* __restrict__ bb,
    const int* __restrict__ nbr,
    const float* __restrict__ u3, const float* __restrict__ v3,
    float* __restrict__ aout, float* __restrict__ a3out)
{
    const int tid  = threadIdx.x;
    const int l    = tid & 63;
    const int wv   = tid >> 6;
    const int half = l >> 5;
    const int e    = l & 31;

    bf16x8 bf0, bf1;
    #pragma unroll
    for (int j = 0; j < 8; ++j) {
        ((short*)&bf0)[j] = (short)bf16_rne(Wb[(half * 8 + j) * 32 + e]);
        ((short*)&bf1)[j] = (short)bf16_rne(Wb[(16 + half * 8 + j) * 32 + e]);
    }
    const float biasc = bb[e];

    for (int nn = 0; nn < 4; ++nn) {
        const int n  = blockIdx.x * 16 + wv * 4 + nn;
        const int jn = nbr[(size_t)n * DEG + e];

        float hv[16];
        #pragma unroll
        for (int s = 0; s < 2; ++s) {
            const int c0 = s * 16 + half * 8;
            float4 uv0 = *(const float4*)&u[(size_t)n  * 32 + c0];
            float4 uv1 = *(const float4*)&u[(size_t)n  * 32 + c0 + 4];
            float4 vv0 = *(const float4*)&v[(size_t)jn * 32 + c0];
            float4 vv1 = *(const float4*)&v[(size_t)jn * 32 + c0 + 4];
            hv[s*8+0] = lrelu(uv0.x + vv0.x);
            hv[s*8+1] = lrelu(uv0.y + vv0.y);
            hv[s*8+2] = lrelu(uv0.z + vv0.z);
            hv[s*8+3] = lrelu(uv0.w + vv0.w);
            hv[s*8+4] = lrelu(uv1.x + vv1.x);
            hv[s*8+5] = lrelu(uv1.y + vv1.y);
            hv[s*8+6] = lrelu(uv1.z + vv1.z);
            hv[s*8+7] = lrelu(uv1.w + vv1.w);
        }
        bf16x8 af0, af1;
        #pragma unroll
        for (int j = 0; j < 8; ++j) {
            ((short*)&af0)[j] = (short)bf16_rne(hv[j]);
            ((short*)&af1)[j] = (short)bf16_rne(hv[8 + j]);
        }
        f32x16 acc = {0.f,0.f,0.f,0.f,0.f,0.f,0.f,0.f,0.f,0.f,0.f,0.f,0.f,0.f,0.f,0.f};
        acc = __builtin_amdgcn_mfma_f32_32x32x16_bf16(af0, bf0, acc, 0, 0, 0);
        acc = __builtin_amdgcn_mfma_f32_32x32x16_bf16(af1, bf1, acc, 0, 0, 0);

        float mx = acc[0];
        #pragma unroll
        for (int r = 1; r < 16; ++r) mx = fmaxf(mx, acc[r]);
        mx = fmaxf(mx, __shfl_xor(mx, 32));
        if (l < 32) aout[(size_t)n * 32 + l] = mx + biasc;

        if (G3) {
            float a3v = u3[n] + v3[jn];
            #pragma unroll
            for (int mm = 16; mm > 0; mm >>= 1) a3v = fmaxf(a3v, __shfl_xor(a3v, mm));
            if (l == 0) a3out[n] = a3v;
        }
    }
}

// ---------------- K5a: coalesced per-chunk partial BN stats for a1,a2 ----------------
__global__ __launch_bounds__(256) void k_stats1(
    const float* __restrict__ a1, const float* __restrict__ a2,
    float* __restrict__ part)
{
    const int p = blockIdx.x;
    const int tid = threadIdx.x;
    const int ch = tid & 31, sub = tid >> 5;
    const size_t base = (size_t)p * ROI;
    float s1 = 0.f, q1 = 0.f, s2 = 0.f, q2 = 0.f;
    for (int n = sub; n < ROI; n += 8) {
        float v1 = a1[(base + n) * 32 + ch];
        float v2 = a2[(base + n) * 32 + ch];
        s1 += v1; q1 += v1 * v1; s2 += v2; q2 += v2 * v2;
    }
    __shared__ float L[4][256];
    L[0][tid] = s1; L[1][tid] = q1; L[2][tid] = s2; L[3][tid] = q2;
    __syncthreads();
    if (tid < 128) {
        const int a = tid >> 5, c = tid & 31;
        float s = 0.f;
        #pragma unroll
        for (int k = 0; k < 8; ++k) s += L[a][c + 32 * k];
        part[p * 128 + a * 32 + c] = s;
    }
}

// ---------------- K5b: finalize BN scale/shift ----------------
__global__ __launch_bounds__(256) void k_stats2(
    const float* __restrict__ part, const float* __restrict__ a3,
    const float* __restrict__ g1, const float* __restrict__ be1,
    const float* __restrict__ g2, const float* __restrict__ be2,
    const float* __restrict__ g3, const float* __restrict__ be3,
    float* __restrict__ st)
{
    const int tid = threadIdx.x;
    float s = 0.f, q = 0.f;
    for (int n = tid; n < NN; n += 256) { float v = a3[n]; s += v; q += v * v; }
    __shared__ float S3[256], Q3[256];
    S3[tid] = s; Q3[tid] = q; __syncthreads();
    for (int off = 128; off > 0; off >>= 1) {
        if (tid < off) { S3[tid] += S3[tid + off]; Q3[tid] += Q3[tid + off]; }
        __syncthreads();
    }
    if (tid < 64) {
        const int a = (tid >> 5) * 2, c = tid & 31;
        float ss = 0.f, qq = 0.f;
        for (int p = 0; p < 64; ++p) {
            ss += part[p * 128 + a * 32 + c];
            qq += part[p * 128 + (a + 1) * 32 + c];
        }
        float gv = (tid < 32) ? g1[c] : g2[c];
        float bv = (tid < 32) ? be1[c] : be2[c];
        float mu  = ss * (1.f / NN);
        float var = qq * (1.f / NN) - mu * mu;
        float sc  = gv * rsqrtf(var + EPSBN);
        st[tid * 2] = sc; st[tid * 2 + 1] = bv - mu * sc;
    }
    if (tid == 64) {
        float mu  = S3[0] * (1.f / NN);
        float var = Q3[0] * (1.f / NN) - mu * mu;
        float sc  = g3[0] * rsqrtf(var + EPSBN);
        st[128] = sc; st[129] = be3[0] - mu * sc;
    }
}

// ---------------- K6: pooled readout ----------------
__global__ __launch_bounds__(256) void k_pool(
    const float* __restrict__ a1, const float* __restrict__ a2, const float* __restrict__ a3,
    const float* __restrict__ st, float* __restrict__ z)
{
    const int b = blockIdx.x, tid = threadIdx.x;
    const int c = tid & 63, grp = tid >> 6;
    const float* src = (c < 32) ? a1 : a2;
    const int ch = c & 31;
    const float sc = st[c * 2], sh = st[c * 2 + 1];
    float acc = 0.f;
    for (int i = grp; i < ROI; i += 4)
        acc += lrelu(src[(size_t)(b * ROI + i) * 32 + ch] * sc + sh);
    __shared__ float P[4][64];
    P[grp][c] = acc;
    __syncthreads();
    if (tid < 64) {
        float sum = P[0][tid] + P[1][tid] + P[2][tid] + P[3][tid];
        z[(size_t)b * 332 + tid] = sum * (1.f / ROI);
    }
    const float sc3 = st[128], sh3 = st[129];
    for (int i = tid; i < ROI; i += 256)
        z[(size_t)b * 332 + 64 + i] = lrelu(a3[b * ROI + i] * sc3 + sh3);
}

// ---------------- K7: h1 = z @ Wl1 + bl1 ----------------
__global__ __launch_bounds__(256) void k_fc1(
    const float* __restrict__ z, const float* __restrict__ Wl1, const float* __restrict__ bl1,
    float* __restrict__ h1)
{
    const int b = blockIdx.x, tid = threadIdx.x;
    __shared__ float zs[332];
    for (int i = tid; i < 332; i += 256) zs[i] = z[(size_t)b * 332 + i];
    __syncthreads();
    float acc = bl1[tid];
    for (int k = 0; k < 332; ++k) acc += zs[k] * Wl1[(size_t)k * 256 + tid];
    h1[(size_t)b * 256 + tid] = acc;
}

// ---------------- K8/K10: BN stats over B rows ----------------
__global__ void k_stats_rows(const float* __restrict__ h, int C,
                             const float* __restrict__ g, const float* __restrict__ be,
                             float* __restrict__ st)
{
    const int o = threadIdx.x;
    if (o >= C) return;
    float s = 0.f, ss = 0.f;
    for (int b2 = 0; b2 < NB; ++b2) {
        float v = h[(size_t)b2 * C + o];
        s += v; ss += v * v;
    }
    float mu  = s * (1.f / NB);
    float var = ss * (1.f / NB) - mu * mu;
    float sc  = g[o] * rsqrtf(var + EPSBN);
    st[o * 2] = sc; st[o * 2 + 1] = be[o] - mu * sc;
}

// ---------------- K9: h2 = leaky(bn(h1)) @ Wl2 + bl2 ----------------
__global__ __launch_bounds__(128) void k_fc2(
    const float* __restrict__ h1, const float* __restrict__ st,
    const float* __restrict__ Wl2, const float* __restrict__ bl2,
    float* __restrict__ h2)
{
    const int b = blockIdx.x, tid = threadIdx.x;
    __shared__ float hs[256];
    for (int i = tid; i < 256; i += 128)
        hs[i] = lrelu(h1[(size_t)b * 256 + i] * st[i * 2] + st[i * 2 + 1]);
    __syncthreads();
    float acc = bl2[tid];
    for (int k = 0; k < 256; ++k) acc += hs[k] * Wl2[(size_t)k * 128 + tid];
    h2[(size_t)b * 128 + tid] = acc;
}

// ---------------- K11: out ----------------
__global__ void k_fc3(
    const float* __restrict__ h2, const float* __restrict__ st,
    const float* __restrict__ Wl3, const float* __restrict__ bl3,
    float* __restrict__ out)
{
    const int b = threadIdx.x;
    if (b >= NB) return;
    float acc = bl3[0];
    for (int c = 0; c < 128; ++c)
        acc += lrelu(h2[(size_t)b * 128 + c] * st[c * 2] + st[c * 2 + 1]) * Wl3[c];
    out[b] = acc;
}

extern "C" void kernel_launch(void* const* d_in, const int* in_sizes, int n_in,
                              void* d_out, int out_size, void* d_ws, size_t ws_size,
                              hipStream_t stream)
{
    (void)in_sizes; (void)n_in; (void)out_size; (void)ws_size;
    const float* x   = (const float*)d_in[0];
    const int*   ei  = (const int*)d_in[1];
    const float* W1a = (const float*)d_in[3];
    const float* b1a = (const float*)d_in[4];
    const float* W1b = (const float*)d_in[5];
    const float* b1b = (const float*)d_in[6];
    const float* g1  = (const float*)d_in[7];
    const float* be1 = (const float*)d_in[8];
    const float* W2a = (const float*)d_in[9];
    const float* b2a = (const float*)d_in[10];
    const float* W2b = (const float*)d_in[11];
    const float* b2b = (const float*)d_in[12];
    const float* g2  = (const float*)d_in[13];
    const float* be2 = (const float*)d_in[14];
    const float* W3  = (const float*)d_in[15];
    const float* b3  = (const float*)d_in[16];
    const float* g3  = (const float*)d_in[17];
    const float* be3 = (const float*)d_in[18];
    const float* Wl1 = (const float*)d_in[19];
    const float* bl1 = (const float*)d_in[20];
    const float* g4  = (const float*)d_in[21];
    const float* be4 = (const float*)d_in[22];
    const float* Wl2 = (const float*)d_in[23];
    const float* bl2 = (const float*)d_in[24];
    const float* g5  = (const float*)d_in[25];
    const float* be5 = (const float*)d_in[26];
    const float* Wl3 = (const float*)d_in[27];
    const float* bl3 = (const float*)d_in[28];

    float* ws  = (float*)d_ws;
    float* u1  = ws;
    float* v1  = u1 + (size_t)NN * 32;
    float* u2  = v1 + (size_t)NN * 32;
    float* v2  = u2 + (size_t)NN * 32;
    float* u3  = v2 + (size_t)NN * 32;
    float* v3  = u3 + NN;
    float* sqv = v3 + NN;
    float* a1  = sqv + NN;
    float* a2  = a1 + (size_t)NN * 32;
    float* a3  = a2 + (size_t)NN * 32;
    int*   knn = (int*)(a3 + NN);
    float* st  = (float*)(knn + (size_t)NN * 32);
    float* z   = st + 130;
    float* h1  = z + (size_t)NB * 332;
    float* h2  = h1 + (size_t)NB * 256;
    float* s4  = h2 + (size_t)NB * 128;
    float* s5  = s4 + 512;
    float* part = s5 + 512;                         // [64][128]
    unsigned short* Xh = (unsigned short*)(((uintptr_t)(part + 64 * 128) + 255) & ~(uintptr_t)255);
    unsigned short* Xl = Xh + (size_t)64 * 17 * 9 * 512;   // 5,013,504 shorts each
    float* d2 = (float*)(((uintptr_t)(Xl + (size_t)64 * 17 * 9 * 512) + 255) & ~(uintptr_t)255);
                                                    // [64][288][288] fp32 = 21.2 MB

    k_pack<<<(64 * 17 * 9 * 64) / 256, 256, 0, stream>>>(x, Xh, Xl);
    k_node_proj<<<NN / 16, 256, 0, stream>>>(x, W1a, b1a, W2a, b2a, W3, b3,
                                             u1, v1, u2, v2, u3, v3, sqv);
    k_dist<<<dim3(9, NB), 256, 0, stream>>>(Xh, Xl, sqv, d2);
    k_sel<<<NN / 8, 256, 0, stream>>>(d2, knn);
    k_edge_mfma<true><<<NN / 16, 256, 0, stream>>>(u1, v1, W1b, b1b, ei, u3, v3, a1, a3);
    k_edge_mfma<false><<<NN / 16, 256, 0, stream>>>(u2, v2, W2b, b2b, knn, nullptr, nullptr, a2, nullptr);
    k_stats1<<<64, 256, 0, stream>>>(a1, a2, part);
    k_stats2<<<1, 256, 0, stream>>>(part, a3, g1, be1, g2, be2, g3, be3, st);
    k_pool<<<NB, 256, 0, stream>>>(a1, a2, a3, st, z);
    k_fc1<<<NB, 256, 0, stream>>>(z, Wl1, bl1, h1);
    k_stats_rows<<<1, 256, 0, stream>>>(h1, 256, g4, be4, s4);
    k_fc2<<<NB, 128, 0, stream>>>(h1, s4, Wl2, bl2, h2);
    k_stats_rows<<<1, 128, 0, stream>>>(h2, 128, g5, be5, s5);
    k_fc3<<<1, 64, 0, stream>>>(h2, s5, Wl3, bl3, (float*)d_out);
}

// Round 6
// 230.842 us; speedup vs baseline: 3.0039x; 1.1723x over previous
//
#include <hip/hip_runtime.h>

#define ROI   268
#define FDIM  268
#define NB    64
#define NN    (NB*ROI)     // 17152
#define CC    32
#define DEG   32
#define KSEL  32
#define SLOPE 0.33f
#define EPSBN 1e-5f

typedef __attribute__((ext_vector_type(8)))  short bf16x8;
typedef __attribute__((ext_vector_type(4)))  float f32x4;
typedef __attribute__((ext_vector_type(16))) float f32x16;

__device__ __forceinline__ float lrelu(float h) { return h >= 0.f ? h : SLOPE * h; }

__device__ __forceinline__ unsigned short bf16_rne(float f) {
    unsigned int u = __float_as_uint(f);
    unsigned int r = u + 0x7FFFu + ((u >> 16) & 1u);
    return (unsigned short)(r >> 16);
}
__device__ __forceinline__ float bf16_tof(unsigned short h) {
    return __uint_as_float(((unsigned int)h) << 16);
}

// ---------------- K1a: pack x into MFMA-fragment-ordered split-bf16 ----------------
// X{h,l}[ (tile*9 + ks)*512 + l*8 + j ], tile = b*17+ct: node = ct*16+(l&15), k = ks*32+(l>>4)*8+j
__global__ __launch_bounds__(256) void k_pack(
    const float* __restrict__ x,
    unsigned short* __restrict__ Xh, unsigned short* __restrict__ Xl)
{
    const int gid = blockIdx.x * 256 + threadIdx.x;
    const int l   = gid & 63;
    const int f3  = gid >> 6;
    const int ks  = f3 % 9;
    const int bc  = f3 / 9;
    const int ct  = bc % 17;
    const int b   = bc / 17;
    const int node = ct * 16 + (l & 15);
    const int k0   = ks * 32 + (l >> 4) * 8;
    float f[8];
    #pragma unroll
    for (int j = 0; j < 8; ++j) f[j] = 0.f;
    if (node < ROI) {
        const float* row = &x[((size_t)b * ROI + node) * FDIM];
        if (k0 + 3 < FDIM) { float4 v = *(const float4*)&row[k0];     f[0]=v.x; f[1]=v.y; f[2]=v.z; f[3]=v.w; }
        if (k0 + 7 < FDIM) { float4 v = *(const float4*)&row[k0 + 4]; f[4]=v.x; f[5]=v.y; f[6]=v.z; f[7]=v.w; }
    }
    unsigned short hh[8], ll[8];
    #pragma unroll
    for (int j = 0; j < 8; ++j) {
        hh[j] = bf16_rne(f[j]);
        ll[j] = bf16_rne(f[j] - bf16_tof(hh[j]));
    }
    uint4 hp, lp;
    hp.x = (unsigned)hh[0] | ((unsigned)hh[1] << 16); hp.y = (unsigned)hh[2] | ((unsigned)hh[3] << 16);
    hp.z = (unsigned)hh[4] | ((unsigned)hh[5] << 16); hp.w = (unsigned)hh[6] | ((unsigned)hh[7] << 16);
    lp.x = (unsigned)ll[0] | ((unsigned)ll[1] << 16); lp.y = (unsigned)ll[2] | ((unsigned)ll[3] << 16);
    lp.z = (unsigned)ll[4] | ((unsigned)ll[5] << 16); lp.w = (unsigned)ll[6] | ((unsigned)ll[7] << 16);
    const size_t base = (size_t)f3 * 512 + l * 8;
    *(uint4*)&Xh[base] = hp;
    *(uint4*)&Xl[base] = lp;
}

// ---------------- K1b: pack projection weights into split-bf16 B-fragments --------
// Wf{h,l}[ ((m*2+ct)*9 + ks)*512 + l*8 + j ] : B[k][c], k=ks*32+(l>>4)*8+j, c=ct*16+(l&15)
// m: 0 = W1a_u (Wa-Wb), 1 = W1a_v (Wb), 2 = W2a_u, 3 = W2a_v
__global__ __launch_bounds__(256) void k_packw(
    const float* __restrict__ W1a, const float* __restrict__ W2a,
    unsigned short* __restrict__ Wfh, unsigned short* __restrict__ Wfl)
{
    const int gid = blockIdx.x * 256 + threadIdx.x;   // 4608 total
    if (gid >= 4608) return;
    const int l  = gid & 63;
    const int f3 = gid >> 6;        // 0..71 : mc*9 + ks
    const int ks = f3 % 9;
    const int mc = f3 / 9;          // m*2+ct
    const int ct = mc & 1;
    const int m  = mc >> 1;
    const int k0 = ks * 32 + (l >> 4) * 8;
    const int c  = ct * 16 + (l & 15);
    const float* W = (m < 2) ? W1a : W2a;
    const bool isU = (m & 1) == 0;
    unsigned short hh[8], ll[8];
    #pragma unroll
    for (int j = 0; j < 8; ++j) {
        const int kk = k0 + j;
        float val = 0.f;
        if (kk < FDIM) {
            float wb = W[(size_t)(FDIM + kk) * CC + c];
            val = isU ? (W[(size_t)kk * CC + c] - wb) : wb;
        }
        hh[j] = bf16_rne(val);
        ll[j] = bf16_rne(val - bf16_tof(hh[j]));
    }
    uint4 hp, lp;
    hp.x = (unsigned)hh[0] | ((unsigned)hh[1] << 16); hp.y = (unsigned)hh[2] | ((unsigned)hh[3] << 16);
    hp.z = (unsigned)hh[4] | ((unsigned)hh[5] << 16); hp.w = (unsigned)hh[6] | ((unsigned)hh[7] << 16);
    lp.x = (unsigned)ll[0] | ((unsigned)ll[1] << 16); lp.y = (unsigned)ll[2] | ((unsigned)ll[3] << 16);
    lp.z = (unsigned)ll[4] | ((unsigned)ll[5] << 16); lp.w = (unsigned)ll[6] | ((unsigned)ll[7] << 16);
    const size_t base = (size_t)f3 * 512 + l * 8;
    *(uint4*)&Wfh[base] = hp;
    *(uint4*)&Wfl[base] = lp;
}

// ---------------- K1c: scalar projections u3, v3 and squared norms ----------------
__global__ __launch_bounds__(256) void k_scalars(
    const float* __restrict__ x, const float* __restrict__ W3, const float* __restrict__ b3,
    float* __restrict__ u3, float* __restrict__ v3, float* __restrict__ sqv)
{
    const int l = threadIdx.x & 63;
    const int n = blockIdx.x * 4 + (threadIdx.x >> 6);
    const float* row = &x[(size_t)n * FDIM];
    float su = 0.f, sv = 0.f, sq = 0.f;
    #pragma unroll
    for (int t = 0; t < 4; ++t) {
        const int f = l + 64 * t;
        float xv = row[f];
        float wv = W3[FDIM + f];
        float wu = W3[f] - wv;
        su += xv * wu; sv += xv * wv; sq += xv * xv;
    }
    if (l < 12) {
        const int f = 256 + l;
        float xv = row[f];
        float wv = W3[FDIM + f];
        float wu = W3[f] - wv;
        su += xv * wu; sv += xv * wv; sq += xv * xv;
    }
    #pragma unroll
    for (int mm = 32; mm > 0; mm >>= 1) {
        su += __shfl_xor(su, mm);
        sv += __shfl_xor(sv, mm);
        sq += __shfl_xor(sq, mm);
    }
    if (l == 0) {
        u3[n] = su + b3[0];
        v3[n] = sv;
        sqv[n] = sq;
    }
}

// ---------------- K1d: node projections u1,v1,u2,v2 via MFMA (split-bf16) ---------
__global__ __launch_bounds__(256) void k_proj_mfma(
    const unsigned short* __restrict__ Xh, const unsigned short* __restrict__ Xl,
    const unsigned short* __restrict__ Wfh, const unsigned short* __restrict__ Wfl,
    const float* __restrict__ b1a, const float* __restrict__ b2a,
    float* __restrict__ u1, float* __restrict__ v1,
    float* __restrict__ u2, float* __restrict__ v2)
{
    const int tid = threadIdx.x;
    const int l   = tid & 63;
    const int m   = tid >> 6;         // wave = matrix 0..3
    const int tile = blockIdx.x;      // 0..1087 = b*17+ctn
    const int b    = tile / 17;
    const int ctn  = tile % 17;

    bf16x8 Ah[9], Al[9];
    {
        const size_t abase = (size_t)tile * 9 * 512 + l * 8;
        #pragma unroll
        for (int ks = 0; ks < 9; ++ks) {
            Ah[ks] = *(const bf16x8*)&Xh[abase + ks * 512];
            Al[ks] = *(const bf16x8*)&Xl[abase + ks * 512];
        }
    }
    float* outp = (m == 0) ? u1 : (m == 1) ? v1 : (m == 2) ? u2 : v2;

    #pragma unroll
    for (int ct = 0; ct < 2; ++ct) {
        const size_t wbase = ((size_t)((m * 2 + ct) * 9)) * 512 + l * 8;
        f32x4 acc = {0.f, 0.f, 0.f, 0.f};
        #pragma unroll
        for (int ks = 0; ks < 9; ++ks) {
            bf16x8 bh = *(const bf16x8*)&Wfh[wbase + ks * 512];
            bf16x8 bl = *(const bf16x8*)&Wfl[wbase + ks * 512];
            acc = __builtin_amdgcn_mfma_f32_16x16x32_bf16(Ah[ks], bh, acc, 0, 0, 0);
            acc = __builtin_amdgcn_mfma_f32_16x16x32_bf16(Ah[ks], bl, acc, 0, 0, 0);
            acc = __builtin_amdgcn_mfma_f32_16x16x32_bf16(Al[ks], bh, acc, 0, 0, 0);
        }
        const int ch = ct * 16 + (l & 15);
        float bias = 0.f;
        if (m == 0) bias = b1a[ch];
        else if (m == 2) bias = b2a[ch];
        const int r0 = (l >> 4) * 4;
        #pragma unroll
        for (int i = 0; i < 4; ++i) {
            const int node = ctn * 16 + r0 + i;
            if (node < ROI)
                outp[((size_t)b * ROI + node) * 32 + ch] = acc[i] + bias;
        }
    }
}

// ---------------- K2a: d2 matrix via MFMA (A-frags in regs, B from global) ----------
__global__ __launch_bounds__(256) void k_dist(
    const unsigned short* __restrict__ Xh, const unsigned short* __restrict__ Xl,
    const float* __restrict__ sqv, float* __restrict__ d2)
{
    __shared__ float sqj[288];
    __shared__ float sqr[32];
    const int tid = threadIdx.x;
    const int b   = blockIdx.y;
    const int r0g = blockIdx.x * 32;
    const size_t bN = (size_t)b * ROI;

    for (int t = tid; t < 288; t += 256)
        sqj[t] = (t < ROI) ? sqv[bN + t] : __builtin_inff();
    if (tid < 32) sqr[tid] = (r0g + tid < ROI) ? sqv[bN + r0g + tid] : 0.f;

    const int l  = tid & 63;
    const int w  = tid >> 6;
    const int ra = w & 1;
    const int rtile = min(blockIdx.x * 2 + ra, 16);

    bf16x8 Ah[9], Al[9];
    {
        const size_t abase = ((size_t)(b * 17 + rtile) * 9) * 512 + l * 8;
        #pragma unroll
        for (int ks = 0; ks < 9; ++ks) {
            Ah[ks] = *(const bf16x8*)&Xh[abase + ks * 512];
            Al[ks] = *(const bf16x8*)&Xl[abase + ks * 512];
        }
    }
    __syncthreads();

    float* drow = &d2[(size_t)b * 288 * 288];
    for (int ct = (w >> 1); ct < 17; ct += 2) {
        const size_t bbase = ((size_t)(b * 17 + ct) * 9) * 512 + l * 8;
        f32x4 acc = {0.f, 0.f, 0.f, 0.f};
        #pragma unroll
        for (int ks = 0; ks < 9; ++ks) {
            bf16x8 bh = *(const bf16x8*)&Xh[bbase + ks * 512];
            bf16x8 bl = *(const bf16x8*)&Xl[bbase + ks * 512];
            acc = __builtin_amdgcn_mfma_f32_16x16x32_bf16(Ah[ks], bh, acc, 0, 0, 0);
            acc = __builtin_amdgcn_mfma_f32_16x16x32_bf16(Ah[ks], bl, acc, 0, 0, 0);
            acc = __builtin_amdgcn_mfma_f32_16x16x32_bf16(Al[ks], bh, acc, 0, 0, 0);
        }
        const int col = ct * 16 + (l & 15);
        const float sj = sqj[col];
        const int rr = ra * 16 + (l >> 4) * 4;
        #pragma unroll
        for (int i = 0; i < 4; ++i)
            drow[(size_t)(r0g + rr + i) * 288 + col] = sqr[rr + i] + sj - 2.f * acc[i];
    }
    for (int t = tid; t < 32 * 16; t += 256) {
        const int r = t >> 4, cc = 272 + (t & 15);
        drow[(size_t)(r0g + r) * 288 + cc] = __builtin_inff();
    }
}

// ---------------- K2b: top-32 selection, one 32-lane group per row ----------------
__global__ __launch_bounds__(256) void k_sel(
    const float* __restrict__ d2, int* __restrict__ knn)
{
    const int grp = blockIdx.x * 8 + (threadIdx.x >> 5);
    const int sl  = threadIdx.x & 31;
    const int b   = grp / ROI;
    const int row = grp - b * ROI;
    const float* src = &d2[((size_t)b * 288 + row) * 288];

    float vals[9];
    #pragma unroll
    for (int q = 0; q < 9; ++q) vals[q] = src[q * 32 + sl];

    int* out = &knn[(size_t)grp * KSEL];
    const int cbase = b * ROI;
    for (int it = 0; it < KSEL; ++it) {
        float bv = vals[0]; int bj = sl;
        #pragma unroll
        for (int q = 1; q < 9; ++q) {
            int jj = q * 32 + sl;
            if (vals[q] < bv) { bv = vals[q]; bj = jj; }
        }
        #pragma unroll
        for (int mm = 16; mm > 0; mm >>= 1) {
            float ov = __shfl_xor(bv, mm, 32);
            int   oj = __shfl_xor(bj, mm, 32);
            if (ov < bv || (ov == bv && oj < bj)) { bv = ov; bj = oj; }
        }
        if (sl == 0) out[it] = cbase + bj;
        #pragma unroll
        for (int q = 0; q < 9; ++q)
            if (bj == q * 32 + sl) vals[q] = __builtin_inff();
    }
}

// ---------------- K3/K4: edge MLP second layer via MFMA + segment max ----------------
template<bool G3>
__global__ __launch_bounds__(256) void k_edge_mfma(
    const float* __restrict__ u, const float* __restrict__ v,
    const float* __restrict__ Wb, const float* __restrict__ bb,
    const int* __restrict__ nbr,
    const float* __restrict__ u3, const float* __restrict__ v3,
    float* __restrict__ aout, float* __restrict__ a3out)
{
    const int tid  = threadIdx.x;
    const int l    = tid & 63;
    const int wv   = tid >> 6;
    const int half = l >> 5;
    const int e    = l & 31;

    bf16x8 bf0, bf1;
    #pragma unroll
    for (int j = 0; j < 8; ++j) {
        ((short*)&bf0)[j] = (short)bf16_rne(Wb[(half * 8 + j) * 32 + e]);
        ((short*)&bf1)[j] = (short)bf16_rne(Wb[(16 + half * 8 + j) * 32 + e]);
    }
    const float biasc = bb[e];

    for (int nn = 0; nn < 4; ++nn) {
        const int n  = blockIdx.x * 16 + wv * 4 + nn;
        const int jn = nbr[(size_t)n * DEG + e];

        float hv[16];
        #pragma unroll
        for (int s = 0; s < 2; ++s) {
            const int c0 = s * 16 + half * 8;
            float4 uv0 = *(const float4*)&u[(size_t)n  * 32 + c0];
            float4 uv1 = *(const float4*)&u[(size_t)n  * 32 + c0 + 4];
            float4 vv0 = *(const float4*)&v[(size_t)jn * 32 + c0];
            float4 vv1 = *(const float4*)&v[(size_t)jn * 32 + c0 + 4];
            hv[s*8+0] = lrelu(uv0.x + vv0.x);
            hv[s*8+1] = lrelu(uv0.y + vv0.y);
            hv[s*8+2] = lrelu(uv0.z + vv0.z);
            hv[s*8+3] = lrelu(uv0.w + vv0.w);
            hv[s*8+4] = lrelu(uv1.x + vv1.x);
            hv[s*8+5] = lrelu(uv1.y + vv1.y);
            hv[s*8+6] = lrelu(uv1.z + vv1.z);
            hv[s*8+7] = lrelu(uv1.w + vv1.w);
        }
        bf16x8 af0, af1;
        #pragma unroll
        for (int j = 0; j < 8; ++j) {
            ((short*)&af0)[j] = (short)bf16_rne(hv[j]);
            ((short*)&af1)[j] = (short)bf16_rne(hv[8 + j]);
        }
        f32x16 acc = {0.f,0.f,0.f,0.f,0.f,0.f,0.f,0.f,0.f,0.f,0.f,0.f,0.f,0.f,0.f,0.f};
        acc = __builtin_amdgcn_mfma_f32_32x32x16_bf16(af0, bf0, acc, 0, 0, 0);
        acc = __builtin_amdgcn_mfma_f32_32x32x16_bf16(af1, bf1, acc, 0, 0, 0);

        float mx = acc[0];
        #pragma unroll
        for (int r = 1; r < 16; ++r) mx = fmaxf(mx, acc[r]);
        mx = fmaxf(mx, __shfl_xor(mx, 32));
        if (l < 32) aout[(size_t)n * 32 + l] = mx + biasc;

        if (G3) {
            float a3v = u3[n] + v3[jn];
            #pragma unroll
            for (int mm = 16; mm > 0; mm >>= 1) a3v = fmaxf(a3v, __shfl_xor(a3v, mm));
            if (l == 0) a3out[n] = a3v;
        }
    }
}

// ---------------- K5a: coalesced per-chunk partial BN stats for a1,a2 ----------------
__global__ __launch_bounds__(256) void k_stats1(
    const float* __restrict__ a1, const float* __restrict__ a2,
    float* __restrict__ part)
{
    const int p = blockIdx.x;
    const int tid = threadIdx.x;
    const int ch = tid & 31, sub = tid >> 5;
    const size_t base = (size_t)p * ROI;
    float s1 = 0.f, q1 = 0.f, s2 = 0.f, q2 = 0.f;
    for (int n = sub; n < ROI; n += 8) {
        float v1 = a1[(base + n) * 32 + ch];
        float v2 = a2[(base + n) * 32 + ch];
        s1 += v1; q1 += v1 * v1; s2 += v2; q2 += v2 * v2;
    }
    __shared__ float L[4][256];
    L[0][tid] = s1; L[1][tid] = q1; L[2][tid] = s2; L[3][tid] = q2;
    __syncthreads();
    if (tid < 128) {
        const int a = tid >> 5, c = tid & 31;
        float s = 0.f;
        #pragma unroll
        for (int k = 0; k < 8; ++k) s += L[a][c + 32 * k];
        part[p * 128 + a * 32 + c] = s;
    }
}

// ---------------- K5b: finalize BN scale/shift ----------------
__global__ __launch_bounds__(256) void k_stats2(
    const float* __restrict__ part, const float* __restrict__ a3,
    const float* __restrict__ g1, const float* __restrict__ be1,
    const float* __restrict__ g2, const float* __restrict__ be2,
    const float* __restrict__ g3, const float* __restrict__ be3,
    float* __restrict__ st)
{
    const int tid = threadIdx.x;
    float s = 0.f, q = 0.f;
    for (int n = tid; n < NN; n += 256) { float v = a3[n]; s += v; q += v * v; }
    __shared__ float S3[256], Q3[256];
    S3[tid] = s; Q3[tid] = q; __syncthreads();
    for (int off = 128; off > 0; off >>= 1) {
        if (tid < off) { S3[tid] += S3[tid + off]; Q3[tid] += Q3[tid + off]; }
        __syncthreads();
    }
    if (tid < 64) {
        const int a = (tid >> 5) * 2, c = tid & 31;
        float ss = 0.f, qq = 0.f;
        for (int p = 0; p < 64; ++p) {
            ss += part[p * 128 + a * 32 + c];
            qq += part[p * 128 + (a + 1) * 32 + c];
        }
        float gv = (tid < 32) ? g1[c] : g2[c];
        float bv = (tid < 32) ? be1[c] : be2[c];
        float mu  = ss * (1.f / NN);
        float var = qq * (1.f / NN) - mu * mu;
        float sc  = gv * rsqrtf(var + EPSBN);
        st[tid * 2] = sc; st[tid * 2 + 1] = bv - mu * sc;
    }
    if (tid == 64) {
        float mu  = S3[0] * (1.f / NN);
        float var = Q3[0] * (1.f / NN) - mu * mu;
        float sc  = g3[0] * rsqrtf(var + EPSBN);
        st[128] = sc; st[129] = be3[0] - mu * sc;
    }
}

// ---------------- K6: pooled readout ----------------
__global__ __launch_bounds__(256) void k_pool(
    const float* __restrict__ a1, const float* __restrict__ a2, const float* __restrict__ a3,
    const float* __restrict__ st, float* __restrict__ z)
{
    const int b = blockIdx.x, tid = threadIdx.x;
    const int c = tid & 63, grp = tid >> 6;
    const float* src = (c < 32) ? a1 : a2;
    const int ch = c & 31;
    const float sc = st[c * 2], sh = st[c * 2 + 1];
    float acc = 0.f;
    for (int i = grp; i < ROI; i += 4)
        acc += lrelu(src[(size_t)(b * ROI + i) * 32 + ch] * sc + sh);
    __shared__ float P[4][64];
    P[grp][c] = acc;
    __syncthreads();
    if (tid < 64) {
        float sum = P[0][tid] + P[1][tid] + P[2][tid] + P[3][tid];
        z[(size_t)b * 332 + tid] = sum * (1.f / ROI);
    }
    const float sc3 = st[128], sh3 = st[129];
    for (int i = tid; i < ROI; i += 256)
        z[(size_t)b * 332 + 64 + i] = lrelu(a3[b * ROI + i] * sc3 + sh3);
}

// ---------------- K7: h1 = z @ Wl1 + bl1 ----------------
__global__ __launch_bounds__(256) void k_fc1(
    const float* __restrict__ z, const float* __restrict__ Wl1, const float* __restrict__ bl1,
    float* __restrict__ h1)
{
    const int b = blockIdx.x, tid = threadIdx.x;
    __shared__ float zs[332];
    for (int i = tid; i < 332; i += 256) zs[i] = z[(size_t)b * 332 + i];
    __syncthreads();
    float acc = bl1[tid];
    for (int k = 0; k < 332; ++k) acc += zs[k] * Wl1[(size_t)k * 256 + tid];
    h1[(size_t)b * 256 + tid] = acc;
}

// ---------------- K8/K10: BN stats over B rows ----------------
__global__ void k_stats_rows(const float* __restrict__ h, int C,
                             const float* __restrict__ g, const float* __restrict__ be,
                             float* __restrict__ st)
{
    const int o = threadIdx.x;
    if (o >= C) return;
    float s = 0.f, ss = 0.f;
    for (int b2 = 0; b2 < NB; ++b2) {
        float v = h[(size_t)b2 * C + o];
        s += v; ss += v * v;
    }
    float mu  = s * (1.f / NB);
    float var = ss * (1.f / NB) - mu * mu;
    float sc  = g[o] * rsqrtf(var + EPSBN);
    st[o * 2] = sc; st[o * 2 + 1] = be[o] - mu * sc;
}

// ---------------- K9: h2 = leaky(bn(h1)) @ Wl2 + bl2 ----------------
__global__ __launch_bounds__(128) void k_fc2(
    const float* __restrict__ h1, const float* __restrict__ st,
    const float* __restrict__ Wl2, const float* __restrict__ bl2,
    float* __restrict__ h2)
{
    const int b = blockIdx.x, tid = threadIdx.x;
    __shared__ float hs[256];
    for (int i = tid; i < 256; i += 128)
        hs[i] = lrelu(h1[(size_t)b * 256 + i] * st[i * 2] + st[i * 2 + 1]);
    __syncthreads();
    float acc = bl2[tid];
    for (int k = 0; k < 256; ++k) acc += hs[k] * Wl2[(size_t)k * 128 + tid];
    h2[(size_t)b * 128 + tid] = acc;
}

// ---------------- K11: out ----------------
__global__ void k_fc3(
    const float* __restrict__ h2, const float* __restrict__ st,
    const float* __restrict__ Wl3, const float* __restrict__ bl3,
    float* __restrict__ out)
{
    const int b = threadIdx.x;
    if (b >= NB) return;
    float acc = bl3[0];
    for (int c = 0; c < 128; ++c)
        acc += lrelu(h2[(size_t)b * 128 + c] * st[c * 2] + st[c * 2 + 1]) * Wl3[c];
    out[b] = acc;
}

extern "C" void kernel_launch(void* const* d_in, const int* in_sizes, int n_in,
                              void* d_out, int out_size, void* d_ws, size_t ws_size,
                              hipStream_t stream)
{
    (void)in_sizes; (void)n_in; (void)out_size; (void)ws_size;
    const float* x   = (const float*)d_in[0];
    const int*   ei  = (const int*)d_in[1];
    const float* W1a = (const float*)d_in[3];
    const float* b1a = (const float*)d_in[4];
    const float* W1b = (const float*)d_in[5];
    const float* b1b = (const float*)d_in[6];
    const float* g1  = (const float*)d_in[7];
    const float* be1 = (const float*)d_in[8];
    const float* W2a = (const float*)d_in[9];
    const float* b2a = (const float*)d_in[10];
    const float* W2b = (const float*)d_in[11];
    const float* b2b = (const float*)d_in[12];
    const float* g2  = (const float*)d_in[13];
    const float* be2 = (const float*)d_in[14];
    const float* W3  = (const float*)d_in[15];
    const float* b3  = (const float*)d_in[16];
    const float* g3  = (const float*)d_in[17];
    const float* be3 = (const float*)d_in[18];
    const float* Wl1 = (const float*)d_in[19];
    const float* bl1 = (const float*)d_in[20];
    const float* g4  = (const float*)d_in[21];
    const float* be4 = (const float*)d_in[22];
    const float* Wl2 = (const float*)d_in[23];
    const float* bl2 = (const float*)d_in[24];
    const float* g5  = (const float*)d_in[25];
    const float* be5 = (const float*)d_in[26];
    const float* Wl3 = (const float*)d_in[27];
    const float* bl3 = (const float*)d_in[28];

    float* ws  = (float*)d_ws;
    float* u1  = ws;
    float* v1  = u1 + (size_t)NN * 32;
    float* u2  = v1 + (size_t)NN * 32;
    float* v2  = u2 + (size_t)NN * 32;
    float* u3  = v2 + (size_t)NN * 32;
    float* v3  = u3 + NN;
    float* sqv = v3 + NN;
    float* a1  = sqv + NN;
    float* a2  = a1 + (size_t)NN * 32;
    float* a3  = a2 + (size_t)NN * 32;
    int*   knn = (int*)(a3 + NN);
    float* st  = (float*)(knn + (size_t)NN * 32);
    float* z   = st + 130;
    float* h1  = z + (size_t)NB * 332;
    float* h2  = h1 + (size_t)NB * 256;
    float* s4  = h2 + (size_t)NB * 128;
    float* s5  = s4 + 512;
    float* part = s5 + 512;                         // [64][128]
    unsigned short* Xh = (unsigned short*)(((uintptr_t)(part + 64 * 128) + 255) & ~(uintptr_t)255);
    unsigned short* Xl = Xh + (size_t)64 * 17 * 9 * 512;
    float* d2 = (float*)(((uintptr_t)(Xl + (size_t)64 * 17 * 9 * 512) + 255) & ~(uintptr_t)255);
    unsigned short* Wfh = (unsigned short*)(d2 + (size_t)64 * 288 * 288);
    unsigned short* Wfl = Wfh + (size_t)8 * 9 * 512;

    k_pack<<<(64 * 17 * 9 * 64) / 256, 256, 0, stream>>>(x, Xh, Xl);
    k_packw<<<18, 256, 0, stream>>>(W1a, W2a, Wfh, Wfl);
    k_scalars<<<NN / 4, 256, 0, stream>>>(x, W3, b3, u3, v3, sqv);
    k_proj_mfma<<<1088, 256, 0, stream>>>(Xh, Xl, Wfh, Wfl, b1a, b2a, u1, v1, u2, v2);
    k_dist<<<dim3(9, NB), 256, 0, stream>>>(Xh, Xl, sqv, d2);
    k_sel<<<NN / 8, 256, 0, stream>>>(d2, knn);
    k_edge_mfma<true><<<NN / 16, 256, 0, stream>>>(u1, v1, W1b, b1b, ei, u3, v3, a1, a3);
    k_edge_mfma<false><<<NN / 16, 256, 0, stream>>>(u2, v2, W2b, b2b, knn, nullptr, nullptr, a2, nullptr);
    k_stats1<<<64, 256, 0, stream>>>(a1, a2, part);
    k_stats2<<<1, 256, 0, stream>>>(part, a3, g1, be1, g2, be2, g3, be3, st);
    k_pool<<<NB, 256, 0, stream>>>(a1, a2, a3, st, z);
    k_fc1<<<NB, 256, 0, stream>>>(z, Wl1, bl1, h1);
    k_stats_rows<<<1, 256, 0, stream>>>(h1, 256, g4, be4, s4);
    k_fc2<<<NB, 128, 0, stream>>>(h1, s4, Wl2, bl2, h2);
    k_stats_rows<<<1, 128, 0, stream>>>(h2, 128, g5, be5, s5);
    k_fc3<<<1, 64, 0, stream>>>(h2, s5, Wl3, bl3, (float*)d_out);
}

// Round 7
// 203.280 us; speedup vs baseline: 3.4111x; 1.1356x over previous
//
#include <hip/hip_runtime.h>
#include <hip/hip_bf16.h>

#define ROI   268
#define FDIM  268
#define NB    64
#define NN    (NB*ROI)     // 17152
#define CC    32
#define DEG   32
#define KSEL  32
#define SLOPE 0.33f
#define EPSBN 1e-5f

typedef __attribute__((ext_vector_type(8)))  short bf16x8;
typedef __attribute__((ext_vector_type(4)))  float f32x4;
typedef __attribute__((ext_vector_type(16))) float f32x16;

__device__ __forceinline__ float lrelu(float h) { return h >= 0.f ? h : SLOPE * h; }

__device__ __forceinline__ unsigned short f2bf(float f) {
    union { __hip_bfloat16 h; unsigned short s; } u;
    u.h = __float2bfloat16(f);   // RNE, lowers to HW cvt
    return u.s;
}
__device__ __forceinline__ float bf2f(unsigned short h) {
    return __uint_as_float(((unsigned int)h) << 16);
}

// ---------------- K1a: pack x into MFMA-fragment-ordered split-bf16 ----------------
// X{h,l}[ (tile*9 + ks)*512 + l*8 + j ], tile = b*17+ct: node = ct*16+(l&15), k = ks*32+(l>>4)*8+j
__global__ __launch_bounds__(256) void k_pack(
    const float* __restrict__ x,
    unsigned short* __restrict__ Xh, unsigned short* __restrict__ Xl)
{
    const int gid = blockIdx.x * 256 + threadIdx.x;
    const int l   = gid & 63;
    const int f3  = gid >> 6;
    const int ks  = f3 % 9;
    const int bc  = f3 / 9;
    const int ct  = bc % 17;
    const int b   = bc / 17;
    const int node = ct * 16 + (l & 15);
    const int k0   = ks * 32 + (l >> 4) * 8;
    float f[8];
    #pragma unroll
    for (int j = 0; j < 8; ++j) f[j] = 0.f;
    if (node < ROI) {
        const float* row = &x[((size_t)b * ROI + node) * FDIM];
        if (k0 + 3 < FDIM) { float4 v = *(const float4*)&row[k0];     f[0]=v.x; f[1]=v.y; f[2]=v.z; f[3]=v.w; }
        if (k0 + 7 < FDIM) { float4 v = *(const float4*)&row[k0 + 4]; f[4]=v.x; f[5]=v.y; f[6]=v.z; f[7]=v.w; }
    }
    unsigned short hh[8], ll[8];
    #pragma unroll
    for (int j = 0; j < 8; ++j) {
        hh[j] = f2bf(f[j]);
        ll[j] = f2bf(f[j] - bf2f(hh[j]));
    }
    uint4 hp, lp;
    hp.x = (unsigned)hh[0] | ((unsigned)hh[1] << 16); hp.y = (unsigned)hh[2] | ((unsigned)hh[3] << 16);
    hp.z = (unsigned)hh[4] | ((unsigned)hh[5] << 16); hp.w = (unsigned)hh[6] | ((unsigned)hh[7] << 16);
    lp.x = (unsigned)ll[0] | ((unsigned)ll[1] << 16); lp.y = (unsigned)ll[2] | ((unsigned)ll[3] << 16);
    lp.z = (unsigned)ll[4] | ((unsigned)ll[5] << 16); lp.w = (unsigned)ll[6] | ((unsigned)ll[7] << 16);
    const size_t base = (size_t)f3 * 512 + l * 8;
    *(uint4*)&Xh[base] = hp;
    *(uint4*)&Xl[base] = lp;
}

// ---------------- K1b: pack projection weights into split-bf16 B-fragments --------
__global__ __launch_bounds__(256) void k_packw(
    const float* __restrict__ W1a, const float* __restrict__ W2a,
    unsigned short* __restrict__ Wfh, unsigned short* __restrict__ Wfl)
{
    const int gid = blockIdx.x * 256 + threadIdx.x;   // 4608 total
    if (gid >= 4608) return;
    const int l  = gid & 63;
    const int f3 = gid >> 6;        // 0..71 : mc*9 + ks
    const int ks = f3 % 9;
    const int mc = f3 / 9;          // m*2+ct
    const int ct = mc & 1;
    const int m  = mc >> 1;
    const int k0 = ks * 32 + (l >> 4) * 8;
    const int c  = ct * 16 + (l & 15);
    const float* W = (m < 2) ? W1a : W2a;
    const bool isU = (m & 1) == 0;
    unsigned short hh[8], ll[8];
    #pragma unroll
    for (int j = 0; j < 8; ++j) {
        const int kk = k0 + j;
        float val = 0.f;
        if (kk < FDIM) {
            float wb = W[(size_t)(FDIM + kk) * CC + c];
            val = isU ? (W[(size_t)kk * CC + c] - wb) : wb;
        }
        hh[j] = f2bf(val);
        ll[j] = f2bf(val - bf2f(hh[j]));
    }
    uint4 hp, lp;
    hp.x = (unsigned)hh[0] | ((unsigned)hh[1] << 16); hp.y = (unsigned)hh[2] | ((unsigned)hh[3] << 16);
    hp.z = (unsigned)hh[4] | ((unsigned)hh[5] << 16); hp.w = (unsigned)hh[6] | ((unsigned)hh[7] << 16);
    lp.x = (unsigned)ll[0] | ((unsigned)ll[1] << 16); lp.y = (unsigned)ll[2] | ((unsigned)ll[3] << 16);
    lp.z = (unsigned)ll[4] | ((unsigned)ll[5] << 16); lp.w = (unsigned)ll[6] | ((unsigned)ll[7] << 16);
    const size_t base = (size_t)f3 * 512 + l * 8;
    *(uint4*)&Wfh[base] = hp;
    *(uint4*)&Wfl[base] = lp;
}

// ---------------- K1c: scalar projections u3, v3 and squared norms ----------------
__global__ __launch_bounds__(256) void k_scalars(
    const float* __restrict__ x, const float* __restrict__ W3, const float* __restrict__ b3,
    float* __restrict__ u3, float* __restrict__ v3, float* __restrict__ sqv)
{
    const int l = threadIdx.x & 63;
    const int n = blockIdx.x * 4 + (threadIdx.x >> 6);
    const float* row = &x[(size_t)n * FDIM];
    float su = 0.f, sv = 0.f, sq = 0.f;
    #pragma unroll
    for (int t = 0; t < 4; ++t) {
        const int f = l + 64 * t;
        float xv = row[f];
        float wv = W3[FDIM + f];
        float wu = W3[f] - wv;
        su += xv * wu; sv += xv * wv; sq += xv * xv;
    }
    if (l < 12) {
        const int f = 256 + l;
        float xv = row[f];
        float wv = W3[FDIM + f];
        float wu = W3[f] - wv;
        su += xv * wu; sv += xv * wv; sq += xv * xv;
    }
    #pragma unroll
    for (int mm = 32; mm > 0; mm >>= 1) {
        su += __shfl_xor(su, mm);
        sv += __shfl_xor(sv, mm);
        sq += __shfl_xor(sq, mm);
    }
    if (l == 0) {
        u3[n] = su + b3[0];
        v3[n] = sv;
        sqv[n] = sq;
    }
}

// ---------------- K1d: node projections u1,v1,u2,v2 via MFMA (split-bf16) ---------
__global__ __launch_bounds__(256) void k_proj_mfma(
    const unsigned short* __restrict__ Xh, const unsigned short* __restrict__ Xl,
    const unsigned short* __restrict__ Wfh, const unsigned short* __restrict__ Wfl,
    const float* __restrict__ b1a, const float* __restrict__ b2a,
    float* __restrict__ u1, float* __restrict__ v1,
    float* __restrict__ u2, float* __restrict__ v2)
{
    const int tid = threadIdx.x;
    const int l   = tid & 63;
    const int m   = tid >> 6;         // wave = matrix 0..3
    const int tile = blockIdx.x;      // 0..1087 = b*17+ctn
    const int b    = tile / 17;
    const int ctn  = tile % 17;

    bf16x8 Ah[9], Al[9];
    {
        const size_t abase = (size_t)tile * 9 * 512 + l * 8;
        #pragma unroll
        for (int ks = 0; ks < 9; ++ks) {
            Ah[ks] = *(const bf16x8*)&Xh[abase + ks * 512];
            Al[ks] = *(const bf16x8*)&Xl[abase + ks * 512];
        }
    }
    float* outp = (m == 0) ? u1 : (m == 1) ? v1 : (m == 2) ? u2 : v2;

    #pragma unroll
    for (int ct = 0; ct < 2; ++ct) {
        const size_t wbase = ((size_t)((m * 2 + ct) * 9)) * 512 + l * 8;
        f32x4 acc = {0.f, 0.f, 0.f, 0.f};
        #pragma unroll
        for (int ks = 0; ks < 9; ++ks) {
            bf16x8 bh = *(const bf16x8*)&Wfh[wbase + ks * 512];
            bf16x8 bl = *(const bf16x8*)&Wfl[wbase + ks * 512];
            acc = __builtin_amdgcn_mfma_f32_16x16x32_bf16(Ah[ks], bh, acc, 0, 0, 0);
            acc = __builtin_amdgcn_mfma_f32_16x16x32_bf16(Ah[ks], bl, acc, 0, 0, 0);
            acc = __builtin_amdgcn_mfma_f32_16x16x32_bf16(Al[ks], bh, acc, 0, 0, 0);
        }
        const int ch = ct * 16 + (l & 15);
        float bias = 0.f;
        if (m == 0) bias = b1a[ch];
        else if (m == 2) bias = b2a[ch];
        const int r0 = (l >> 4) * 4;
        #pragma unroll
        for (int i = 0; i < 4; ++i) {
            const int node = ctn * 16 + r0 + i;
            if (node < ROI)
                outp[((size_t)b * ROI + node) * 32 + ch] = acc[i] + bias;
        }
    }
}

// ---------------- K2a: d2 matrix via MFMA (A-frags in regs, B from global) ----------
__global__ __launch_bounds__(256) void k_dist(
    const unsigned short* __restrict__ Xh, const unsigned short* __restrict__ Xl,
    const float* __restrict__ sqv, float* __restrict__ d2)
{
    __shared__ float sqj[288];
    __shared__ float sqr[32];
    const int tid = threadIdx.x;
    const int b   = blockIdx.y;
    const int r0g = blockIdx.x * 32;
    const size_t bN = (size_t)b * ROI;

    for (int t = tid; t < 288; t += 256)
        sqj[t] = (t < ROI) ? sqv[bN + t] : __builtin_inff();
    if (tid < 32) sqr[tid] = (r0g + tid < ROI) ? sqv[bN + r0g + tid] : 0.f;

    const int l  = tid & 63;
    const int w  = tid >> 6;
    const int ra = w & 1;
    const int rtile = min(blockIdx.x * 2 + ra, 16);

    bf16x8 Ah[9], Al[9];
    {
        const size_t abase = ((size_t)(b * 17 + rtile) * 9) * 512 + l * 8;
        #pragma unroll
        for (int ks = 0; ks < 9; ++ks) {
            Ah[ks] = *(const bf16x8*)&Xh[abase + ks * 512];
            Al[ks] = *(const bf16x8*)&Xl[abase + ks * 512];
        }
    }
    __syncthreads();

    float* drow = &d2[(size_t)b * 288 * 288];
    for (int ct = (w >> 1); ct < 17; ct += 2) {
        const size_t bbase = ((size_t)(b * 17 + ct) * 9) * 512 + l * 8;
        f32x4 acc = {0.f, 0.f, 0.f, 0.f};
        #pragma unroll
        for (int ks = 0; ks < 9; ++ks) {
            bf16x8 bh = *(const bf16x8*)&Xh[bbase + ks * 512];
            bf16x8 bl = *(const bf16x8*)&Xl[bbase + ks * 512];
            acc = __builtin_amdgcn_mfma_f32_16x16x32_bf16(Ah[ks], bh, acc, 0, 0, 0);
            acc = __builtin_amdgcn_mfma_f32_16x16x32_bf16(Ah[ks], bl, acc, 0, 0, 0);
            acc = __builtin_amdgcn_mfma_f32_16x16x32_bf16(Al[ks], bh, acc, 0, 0, 0);
        }
        const int col = ct * 16 + (l & 15);
        const float sj = sqj[col];
        const int rr = ra * 16 + (l >> 4) * 4;
        #pragma unroll
        for (int i = 0; i < 4; ++i)
            drow[(size_t)(r0g + rr + i) * 288 + col] = sqr[rr + i] + sj - 2.f * acc[i];
    }
    for (int t = tid; t < 32 * 16; t += 256) {
        const int r = t >> 4, cc = 272 + (t & 15);
        drow[(size_t)(r0g + r) * 288 + cc] = __builtin_inff();
    }
}

// ---------------- K2b: top-32 via packed-key tournament ----------------
// key = (monotonic_u32(d2) & ~0x1FF) | col  — unique keys, idx-tiebreak built in.
__global__ __launch_bounds__(256) void k_sel(
    const float* __restrict__ d2, int* __restrict__ knn)
{
    const int grp = blockIdx.x * 8 + (threadIdx.x >> 5);
    const int sl  = threadIdx.x & 31;
    const int b   = grp / ROI;
    const int row = grp - b * ROI;
    const float* src = &d2[((size_t)b * 288 + row) * 288];

    unsigned k[9];
    #pragma unroll
    for (int q = 0; q < 9; ++q) {
        const int idx = q * 32 + sl;
        unsigned bits = __float_as_uint(src[idx]);
        unsigned msk  = (unsigned)(((int)bits) >> 31) | 0x80000000u;
        k[q] = ((bits ^ msk) & ~0x1FFu) | (unsigned)idx;
    }
    // insertion sorting network (constant indices, data-independent)
    #pragma unroll
    for (int i = 1; i < 9; ++i) {
        #pragma unroll
        for (int j = i; j > 0; --j) {
            unsigned lo = k[j-1] < k[j] ? k[j-1] : k[j];
            unsigned hi = k[j-1] < k[j] ? k[j]   : k[j-1];
            k[j-1] = lo; k[j] = hi;
        }
    }
    unsigned keep = 0;
    #pragma unroll
    for (int it = 0; it < KSEL; ++it) {
        unsigned m = k[0];
        #pragma unroll
        for (int mm = 16; mm > 0; mm >>= 1) {
            unsigned o = (unsigned)__shfl_xor((int)m, mm, 32);
            m = o < m ? o : m;
        }
        if (sl == it) keep = m;
        const bool win = (k[0] == m);
        #pragma unroll
        for (int q = 0; q < 8; ++q) k[q] = win ? k[q+1] : k[q];
        k[8] = win ? 0xFFFFFFFFu : k[8];
    }
    knn[(size_t)grp * KSEL + sl] = b * ROI + (int)(keep & 0x1FFu);
}

// ---------------- K3/K4: edge MLP second layer via MFMA + segment max ----------------
template<bool G3>
__global__ __launch_bounds__(256) void k_edge_mfma(
    const float* __restrict__ u, const float* __restrict__ v,
    const float* __restrict__ Wb, const float* __restrict__ bb,
    const int* __restrict__ nbr,
    const float* __restrict__ u3, const float* __restrict__ v3,
    float* __restrict__ aout, float* __restrict__ a3out)
{
    const int tid  = threadIdx.x;
    const int l    = tid & 63;
    const int wv   = tid >> 6;
    const int half = l >> 5;
    const int e    = l & 31;

    union { bf16x8 v8; unsigned u4[4]; } B0, B1;
    #pragma unroll
    for (int j = 0; j < 4; ++j) {
        B0.u4[j] = (unsigned)f2bf(Wb[(half * 8 + 2*j    ) * 32 + e])
                 | ((unsigned)f2bf(Wb[(half * 8 + 2*j + 1) * 32 + e]) << 16);
        B1.u4[j] = (unsigned)f2bf(Wb[(16 + half * 8 + 2*j    ) * 32 + e])
                 | ((unsigned)f2bf(Wb[(16 + half * 8 + 2*j + 1) * 32 + e]) << 16);
    }
    const float biasc = bb[e];

    for (int nn = 0; nn < 4; ++nn) {
        const int n  = blockIdx.x * 16 + wv * 4 + nn;
        const int jn = nbr[(size_t)n * DEG + e];

        float hv[16];
        #pragma unroll
        for (int s = 0; s < 2; ++s) {
            const int c0 = s * 16 + half * 8;
            float4 uv0 = *(const float4*)&u[(size_t)n  * 32 + c0];
            float4 uv1 = *(const float4*)&u[(size_t)n  * 32 + c0 + 4];
            float4 vv0 = *(const float4*)&v[(size_t)jn * 32 + c0];
            float4 vv1 = *(const float4*)&v[(size_t)jn * 32 + c0 + 4];
            hv[s*8+0] = lrelu(uv0.x + vv0.x);
            hv[s*8+1] = lrelu(uv0.y + vv0.y);
            hv[s*8+2] = lrelu(uv0.z + vv0.z);
            hv[s*8+3] = lrelu(uv0.w + vv0.w);
            hv[s*8+4] = lrelu(uv1.x + vv1.x);
            hv[s*8+5] = lrelu(uv1.y + vv1.y);
            hv[s*8+6] = lrelu(uv1.z + vv1.z);
            hv[s*8+7] = lrelu(uv1.w + vv1.w);
        }
        union { bf16x8 v8; unsigned u4[4]; } A0, A1;
        #pragma unroll
        for (int j = 0; j < 4; ++j) {
            A0.u4[j] = (unsigned)f2bf(hv[2*j])     | ((unsigned)f2bf(hv[2*j + 1]) << 16);
            A1.u4[j] = (unsigned)f2bf(hv[8 + 2*j]) | ((unsigned)f2bf(hv[8 + 2*j + 1]) << 16);
        }
        f32x16 acc = {0.f,0.f,0.f,0.f,0.f,0.f,0.f,0.f,0.f,0.f,0.f,0.f,0.f,0.f,0.f,0.f};
        acc = __builtin_amdgcn_mfma_f32_32x32x16_bf16(A0.v8, B0.v8, acc, 0, 0, 0);
        acc = __builtin_amdgcn_mfma_f32_32x32x16_bf16(A1.v8, B1.v8, acc, 0, 0, 0);

        float mx = acc[0];
        #pragma unroll
        for (int r = 1; r < 16; ++r) mx = fmaxf(mx, acc[r]);
        mx = fmaxf(mx, __shfl_xor(mx, 32));
        if (l < 32) aout[(size_t)n * 32 + l] = mx + biasc;

        if (G3) {
            float a3v = u3[n] + v3[jn];
            #pragma unroll
            for (int mm = 16; mm > 0; mm >>= 1) a3v = fmaxf(a3v, __shfl_xor(a3v, mm));
            if (l == 0) a3out[n] = a3v;
        }
    }
}

// ---------------- K5a: coalesced per-chunk partial BN stats for a1,a2 ----------------
__global__ __launch_bounds__(256) void k_stats1(
    const float* __restrict__ a1, const float* __restrict__ a2,
    float* __restrict__ part)
{
    const int p = blockIdx.x;
    const int tid = threadIdx.x;
    const int ch = tid & 31, sub = tid >> 5;
    const size_t base = (size_t)p * ROI;
    float s1 = 0.f, q1 = 0.f, s2 = 0.f, q2 = 0.f;
    for (int n = sub; n < ROI; n += 8) {
        float v1 = a1[(base + n) * 32 + ch];
        float v2 = a2[(base + n) * 32 + ch];
        s1 += v1; q1 += v1 * v1; s2 += v2; q2 += v2 * v2;
    }
    __shared__ float L[4][256];
    L[0][tid] = s1; L[1][tid] = q1; L[2][tid] = s2; L[3][tid] = q2;
    __syncthreads();
    if (tid < 128) {
        const int a = tid >> 5, c = tid & 31;
        float s = 0.f;
        #pragma unroll
        for (int k = 0; k < 8; ++k) s += L[a][c + 32 * k];
        part[p * 128 + a * 32 + c] = s;
    }
}

// ---------------- K5b: finalize BN scale/shift ----------------
__global__ __launch_bounds__(256) void k_stats2(
    const float* __restrict__ part, const float* __restrict__ a3,
    const float* __restrict__ g1, const float* __restrict__ be1,
    const float* __restrict__ g2, const float* __restrict__ be2,
    const float* __restrict__ g3, const float* __restrict__ be3,
    float* __restrict__ st)
{
    const int tid = threadIdx.x;
    float s = 0.f, q = 0.f;
    for (int n = tid; n < NN; n += 256) { float v = a3[n]; s += v; q += v * v; }
    __shared__ float S3[256], Q3[256];
    S3[tid] = s; Q3[tid] = q; __syncthreads();
    for (int off = 128; off > 0; off >>= 1) {
        if (tid < off) { S3[tid] += S3[tid + off]; Q3[tid] += Q3[tid + off]; }
        __syncthreads();
    }
    if (tid < 64) {
        const int a = (tid >> 5) * 2, c = tid & 31;
        float ss = 0.f, qq = 0.f;
        for (int p = 0; p < 64; ++p) {
            ss += part[p * 128 + a * 32 + c];
            qq += part[p * 128 + (a + 1) * 32 + c];
        }
        float gv = (tid < 32) ? g1[c] : g2[c];
        float bv = (tid < 32) ? be1[c] : be2[c];
        float mu  = ss * (1.f / NN);
        float var = qq * (1.f / NN) - mu * mu;
        float sc  = gv * rsqrtf(var + EPSBN);
        st[tid * 2] = sc; st[tid * 2 + 1] = bv - mu * sc;
    }
    if (tid == 64) {
        float mu  = S3[0] * (1.f / NN);
        float var = Q3[0] * (1.f / NN) - mu * mu;
        float sc  = g3[0] * rsqrtf(var + EPSBN);
        st[128] = sc; st[129] = be3[0] - mu * sc;
    }
}

// ---------------- K6: pooled readout fused with fc1 ----------------
__global__ __launch_bounds__(256) void k_pool_fc1(
    const float* __restrict__ a1, const float* __restrict__ a2, const float* __restrict__ a3,
    const float* __restrict__ st, const float* __restrict__ Wl1, const float* __restrict__ bl1,
    float* __restrict__ h1)
{
    const int b = blockIdx.x, tid = threadIdx.x;
    __shared__ float zs[332];
    __shared__ float P[4][64];
    const int c = tid & 63, grp = tid >> 6;
    const float* src = (c < 32) ? a1 : a2;
    const int ch = c & 31;
    const float sc = st[c * 2], sh = st[c * 2 + 1];
    float acc = 0.f;
    for (int i = grp; i < ROI; i += 4)
        acc += lrelu(src[(size_t)(b * ROI + i) * 32 + ch] * sc + sh);
    P[grp][c] = acc;
    const float sc3 = st[128], sh3 = st[129];
    for (int i = tid; i < ROI; i += 256)
        zs[64 + i] = lrelu(a3[b * ROI + i] * sc3 + sh3);
    __syncthreads();
    if (tid < 64)
        zs[tid] = (P[0][tid] + P[1][tid] + P[2][tid] + P[3][tid]) * (1.f / ROI);
    __syncthreads();
    float a = bl1[tid];
    for (int k = 0; k < 332; ++k) a += zs[k] * Wl1[(size_t)k * 256 + tid];
    h1[(size_t)b * 256 + tid] = a;
}

// ---------------- K8/K10: BN stats over B rows ----------------
__global__ void k_stats_rows(const float* __restrict__ h, int C,
                             const float* __restrict__ g, const float* __restrict__ be,
                             float* __restrict__ st)
{
    const int o = threadIdx.x;
    if (o >= C) return;
    float s = 0.f, ss = 0.f;
    for (int b2 = 0; b2 < NB; ++b2) {
        float v = h[(size_t)b2 * C + o];
        s += v; ss += v * v;
    }
    float mu  = s * (1.f / NB);
    float var = ss * (1.f / NB) - mu * mu;
    float sc  = g[o] * rsqrtf(var + EPSBN);
    st[o * 2] = sc; st[o * 2 + 1] = be[o] - mu * sc;
}

// ---------------- K9: h2 = leaky(bn(h1)) @ Wl2 + bl2 ----------------
__global__ __launch_bounds__(128) void k_fc2(
    const float* __restrict__ h1, const float* __restrict__ st,
    const float* __restrict__ Wl2, const float* __restrict__ bl2,
    float* __restrict__ h2)
{
    const int b = blockIdx.x, tid = threadIdx.x;
    __shared__ float hs[256];
    for (int i = tid; i < 256; i += 128)
        hs[i] = lrelu(h1[(size_t)b * 256 + i] * st[i * 2] + st[i * 2 + 1]);
    __syncthreads();
    float acc = bl2[tid];
    for (int k = 0; k < 256; ++k) acc += hs[k] * Wl2[(size_t)k * 128 + tid];
    h2[(size_t)b * 128 + tid] = acc;
}

// ---------------- K11: out ----------------
__global__ void k_fc3(
    const float* __restrict__ h2, const float* __restrict__ st,
    const float* __restrict__ Wl3, const float* __restrict__ bl3,
    float* __restrict__ out)
{
    const int b = threadIdx.x;
    if (b >= NB) return;
    float acc = bl3[0];
    for (int c = 0; c < 128; ++c)
        acc += lrelu(h2[(size_t)b * 128 + c] * st[c * 2] + st[c * 2 + 1]) * Wl3[c];
    out[b] = acc;
}

extern "C" void kernel_launch(void* const* d_in, const int* in_sizes, int n_in,
                              void* d_out, int out_size, void* d_ws, size_t ws_size,
                              hipStream_t stream)
{
    (void)in_sizes; (void)n_in; (void)out_size; (void)ws_size;
    const float* x   = (const float*)d_in[0];
    const int*   ei  = (const int*)d_in[1];
    const float* W1a = (const float*)d_in[3];
    const float* b1a = (const float*)d_in[4];
    const float* W1b = (const float*)d_in[5];
    const float* b1b = (const float*)d_in[6];
    const float* g1  = (const float*)d_in[7];
    const float* be1 = (const float*)d_in[8];
    const float* W2a = (const float*)d_in[9];
    const float* b2a = (const float*)d_in[10];
    const float* W2b = (const float*)d_in[11];
    const float* b2b = (const float*)d_in[12];
    const float* g2  = (const float*)d_in[13];
    const float* be2 = (const float*)d_in[14];
    const float* W3  = (const float*)d_in[15];
    const float* b3  = (const float*)d_in[16];
    const float* g3  = (const float*)d_in[17];
    const float* be3 = (const float*)d_in[18];
    const float* Wl1 = (const float*)d_in[19];
    const float* bl1 = (const float*)d_in[20];
    const float* g4  = (const float*)d_in[21];
    const float* be4 = (const float*)d_in[22];
    const float* Wl2 = (const float*)d_in[23];
    const float* bl2 = (const float*)d_in[24];
    const float* g5  = (const float*)d_in[25];
    const float* be5 = (const float*)d_in[26];
    const float* Wl3 = (const float*)d_in[27];
    const float* bl3 = (const float*)d_in[28];

    float* ws  = (float*)d_ws;
    float* u1  = ws;
    float* v1  = u1 + (size_t)NN * 32;
    float* u2  = v1 + (size_t)NN * 32;
    float* v2  = u2 + (size_t)NN * 32;
    float* u3  = v2 + (size_t)NN * 32;
    float* v3  = u3 + NN;
    float* sqv = v3 + NN;
    float* a1  = sqv + NN;
    float* a2  = a1 + (size_t)NN * 32;
    float* a3  = a2 + (size_t)NN * 32;
    int*   knn = (int*)(a3 + NN);
    float* st  = (float*)(knn + (size_t)NN * 32);
    float* z   = st + 130;
    float* h1  = z + (size_t)NB * 332;
    float* h2  = h1 + (size_t)NB * 256;
    float* s4  = h2 + (size_t)NB * 128;
    float* s5  = s4 + 512;
    float* part = s5 + 512;                         // [64][128]
    unsigned short* Xh = (unsigned short*)(((uintptr_t)(part + 64 * 128) + 255) & ~(uintptr_t)255);
    unsigned short* Xl = Xh + (size_t)64 * 17 * 9 * 512;
    float* d2 = (float*)(((uintptr_t)(Xl + (size_t)64 * 17 * 9 * 512) + 255) & ~(uintptr_t)255);
    unsigned short* Wfh = (unsigned short*)(d2 + (size_t)64 * 288 * 288);
    unsigned short* Wfl = Wfh + (size_t)8 * 9 * 512;

    k_pack<<<(64 * 17 * 9 * 64) / 256, 256, 0, stream>>>(x, Xh, Xl);
    k_packw<<<18, 256, 0, stream>>>(W1a, W2a, Wfh, Wfl);
    k_scalars<<<NN / 4, 256, 0, stream>>>(x, W3, b3, u3, v3, sqv);
    k_proj_mfma<<<1088, 256, 0, stream>>>(Xh, Xl, Wfh, Wfl, b1a, b2a, u1, v1, u2, v2);
    k_dist<<<dim3(9, NB), 256, 0, stream>>>(Xh, Xl, sqv, d2);
    k_sel<<<NN / 8, 256, 0, stream>>>(d2, knn);
    k_edge_mfma<true><<<NN / 16, 256, 0, stream>>>(u1, v1, W1b, b1b, ei, u3, v3, a1, a3);
    k_edge_mfma<false><<<NN / 16, 256, 0, stream>>>(u2, v2, W2b, b2b, knn, nullptr, nullptr, a2, nullptr);
    k_stats1<<<64, 256, 0, stream>>>(a1, a2, part);
    k_stats2<<<1, 256, 0, stream>>>(part, a3, g1, be1, g2, be2, g3, be3, st);
    k_pool_fc1<<<NB, 256, 0, stream>>>(a1, a2, a3, st, Wl1, bl1, h1);
    k_stats_rows<<<1, 256, 0, stream>>>(h1, 256, g4, be4, s4);
    k_fc2<<<NB, 128, 0, stream>>>(h1, s4, Wl2, bl2, h2);
    k_stats_rows<<<1, 128, 0, stream>>>(h2, 128, g5, be5, s5);
    k_fc3<<<1, 64, 0, stream>>>(h2, s5, Wl3, bl3, (float*)d_out);
}

// Round 8
// 178.596 us; speedup vs baseline: 3.8826x; 1.1382x over previous
//
#include <hip/hip_runtime.h>
#include <hip/hip_bf16.h>

#define ROI   268
#define FDIM  268
#define NB    64
#define NN    (NB*ROI)     // 17152
#define CC    32
#define DEG   32
#define KSEL  32
#define SLOPE 0.33f
#define EPSBN 1e-5f

typedef __attribute__((ext_vector_type(8)))  short bf16x8;
typedef __attribute__((ext_vector_type(4)))  float f32x4;
typedef __attribute__((ext_vector_type(16))) float f32x16;

__device__ __forceinline__ float lrelu(float h) { return h >= 0.f ? h : SLOPE * h; }

__device__ __forceinline__ unsigned short f2bf(float f) {
    union { __hip_bfloat16 h; unsigned short s; } u;
    u.h = __float2bfloat16(f);   // RNE, lowers to HW cvt
    return u.s;
}
__device__ __forceinline__ float bf2f(unsigned short h) {
    return __uint_as_float(((unsigned int)h) << 16);
}

// ---------------- K1a: pack x into MFMA-fragment-ordered split-bf16 ----------------
__global__ __launch_bounds__(256) void k_pack(
    const float* __restrict__ x,
    unsigned short* __restrict__ Xh, unsigned short* __restrict__ Xl)
{
    const int gid = blockIdx.x * 256 + threadIdx.x;
    const int l   = gid & 63;
    const int f3  = gid >> 6;
    const int ks  = f3 % 9;
    const int bc  = f3 / 9;
    const int ct  = bc % 17;
    const int b   = bc / 17;
    const int node = ct * 16 + (l & 15);
    const int k0   = ks * 32 + (l >> 4) * 8;
    float f[8];
    #pragma unroll
    for (int j = 0; j < 8; ++j) f[j] = 0.f;
    if (node < ROI) {
        const float* row = &x[((size_t)b * ROI + node) * FDIM];
        if (k0 + 3 < FDIM) { float4 v = *(const float4*)&row[k0];     f[0]=v.x; f[1]=v.y; f[2]=v.z; f[3]=v.w; }
        if (k0 + 7 < FDIM) { float4 v = *(const float4*)&row[k0 + 4]; f[4]=v.x; f[5]=v.y; f[6]=v.z; f[7]=v.w; }
    }
    unsigned short hh[8], ll[8];
    #pragma unroll
    for (int j = 0; j < 8; ++j) {
        hh[j] = f2bf(f[j]);
        ll[j] = f2bf(f[j] - bf2f(hh[j]));
    }
    uint4 hp, lp;
    hp.x = (unsigned)hh[0] | ((unsigned)hh[1] << 16); hp.y = (unsigned)hh[2] | ((unsigned)hh[3] << 16);
    hp.z = (unsigned)hh[4] | ((unsigned)hh[5] << 16); hp.w = (unsigned)hh[6] | ((unsigned)hh[7] << 16);
    lp.x = (unsigned)ll[0] | ((unsigned)ll[1] << 16); lp.y = (unsigned)ll[2] | ((unsigned)ll[3] << 16);
    lp.z = (unsigned)ll[4] | ((unsigned)ll[5] << 16); lp.w = (unsigned)ll[6] | ((unsigned)ll[7] << 16);
    const size_t base = (size_t)f3 * 512 + l * 8;
    *(uint4*)&Xh[base] = hp;
    *(uint4*)&Xl[base] = lp;
}

// ---------------- K1b: pack projection weights into split-bf16 B-fragments --------
__global__ __launch_bounds__(256) void k_packw(
    const float* __restrict__ W1a, const float* __restrict__ W2a,
    unsigned short* __restrict__ Wfh, unsigned short* __restrict__ Wfl)
{
    const int gid = blockIdx.x * 256 + threadIdx.x;   // 4608 total
    if (gid >= 4608) return;
    const int l  = gid & 63;
    const int f3 = gid >> 6;        // 0..71 : mc*9 + ks
    const int ks = f3 % 9;
    const int mc = f3 / 9;          // m*2+ct
    const int ct = mc & 1;
    const int m  = mc >> 1;
    const int k0 = ks * 32 + (l >> 4) * 8;
    const int c  = ct * 16 + (l & 15);
    const float* W = (m < 2) ? W1a : W2a;
    const bool isU = (m & 1) == 0;
    unsigned short hh[8], ll[8];
    #pragma unroll
    for (int j = 0; j < 8; ++j) {
        const int kk = k0 + j;
        float val = 0.f;
        if (kk < FDIM) {
            float wb = W[(size_t)(FDIM + kk) * CC + c];
            val = isU ? (W[(size_t)kk * CC + c] - wb) : wb;
        }
        hh[j] = f2bf(val);
        ll[j] = f2bf(val - bf2f(hh[j]));
    }
    uint4 hp, lp;
    hp.x = (unsigned)hh[0] | ((unsigned)hh[1] << 16); hp.y = (unsigned)hh[2] | ((unsigned)hh[3] << 16);
    hp.z = (unsigned)hh[4] | ((unsigned)hh[5] << 16); hp.w = (unsigned)hh[6] | ((unsigned)hh[7] << 16);
    lp.x = (unsigned)ll[0] | ((unsigned)ll[1] << 16); lp.y = (unsigned)ll[2] | ((unsigned)ll[3] << 16);
    lp.z = (unsigned)ll[4] | ((unsigned)ll[5] << 16); lp.w = (unsigned)ll[6] | ((unsigned)ll[7] << 16);
    const size_t base = (size_t)f3 * 512 + l * 8;
    *(uint4*)&Wfh[base] = hp;
    *(uint4*)&Wfl[base] = lp;
}

// ---------------- K1c: scalar projections u3, v3 and squared norms ----------------
__global__ __launch_bounds__(256) void k_scalars(
    const float* __restrict__ x, const float* __restrict__ W3, const float* __restrict__ b3,
    float* __restrict__ u3, float* __restrict__ v3, float* __restrict__ sqv)
{
    const int l = threadIdx.x & 63;
    const int n = blockIdx.x * 4 + (threadIdx.x >> 6);
    const float* row = &x[(size_t)n * FDIM];
    float su = 0.f, sv = 0.f, sq = 0.f;
    #pragma unroll
    for (int t = 0; t < 4; ++t) {
        const int f = l + 64 * t;
        float xv = row[f];
        float wv = W3[FDIM + f];
        float wu = W3[f] - wv;
        su += xv * wu; sv += xv * wv; sq += xv * xv;
    }
    if (l < 12) {
        const int f = 256 + l;
        float xv = row[f];
        float wv = W3[FDIM + f];
        float wu = W3[f] - wv;
        su += xv * wu; sv += xv * wv; sq += xv * xv;
    }
    #pragma unroll
    for (int mm = 32; mm > 0; mm >>= 1) {
        su += __shfl_xor(su, mm);
        sv += __shfl_xor(sv, mm);
        sq += __shfl_xor(sq, mm);
    }
    if (l == 0) {
        u3[n] = su + b3[0];
        v3[n] = sv;
        sqv[n] = sq;
    }
}

// ---------------- K1d: node projections u1,v1,u2,v2 via MFMA (split-bf16) ---------
__global__ __launch_bounds__(256) void k_proj_mfma(
    const unsigned short* __restrict__ Xh, const unsigned short* __restrict__ Xl,
    const unsigned short* __restrict__ Wfh, const unsigned short* __restrict__ Wfl,
    const float* __restrict__ b1a, const float* __restrict__ b2a,
    float* __restrict__ u1, float* __restrict__ v1,
    float* __restrict__ u2, float* __restrict__ v2)
{
    const int tid = threadIdx.x;
    const int l   = tid & 63;
    const int m   = tid >> 6;         // wave = matrix 0..3
    const int tile = blockIdx.x;      // 0..1087 = b*17+ctn
    const int b    = tile / 17;
    const int ctn  = tile % 17;

    bf16x8 Ah[9], Al[9];
    {
        const size_t abase = (size_t)tile * 9 * 512 + l * 8;
        #pragma unroll
        for (int ks = 0; ks < 9; ++ks) {
            Ah[ks] = *(const bf16x8*)&Xh[abase + ks * 512];
            Al[ks] = *(const bf16x8*)&Xl[abase + ks * 512];
        }
    }
    float* outp = (m == 0) ? u1 : (m == 1) ? v1 : (m == 2) ? u2 : v2;

    #pragma unroll
    for (int ct = 0; ct < 2; ++ct) {
        const size_t wbase = ((size_t)((m * 2 + ct) * 9)) * 512 + l * 8;
        f32x4 acc = {0.f, 0.f, 0.f, 0.f};
        #pragma unroll
        for (int ks = 0; ks < 9; ++ks) {
            bf16x8 bh = *(const bf16x8*)&Wfh[wbase + ks * 512];
            bf16x8 bl = *(const bf16x8*)&Wfl[wbase + ks * 512];
            acc = __builtin_amdgcn_mfma_f32_16x16x32_bf16(Ah[ks], bh, acc, 0, 0, 0);
            acc = __builtin_amdgcn_mfma_f32_16x16x32_bf16(Ah[ks], bl, acc, 0, 0, 0);
            acc = __builtin_amdgcn_mfma_f32_16x16x32_bf16(Al[ks], bh, acc, 0, 0, 0);
        }
        const int ch = ct * 16 + (l & 15);
        float bias = 0.f;
        if (m == 0) bias = b1a[ch];
        else if (m == 2) bias = b2a[ch];
        const int r0 = (l >> 4) * 4;
        #pragma unroll
        for (int i = 0; i < 4; ++i) {
            const int node = ctn * 16 + r0 + i;
            if (node < ROI)
                outp[((size_t)b * ROI + node) * 32 + ch] = acc[i] + bias;
        }
    }
}

// ---------------- K2a: d2 matrix via MFMA (A-frags in regs, B from global) ----------
__global__ __launch_bounds__(256) void k_dist(
    const unsigned short* __restrict__ Xh, const unsigned short* __restrict__ Xl,
    const float* __restrict__ sqv, float* __restrict__ d2)
{
    __shared__ float sqj[288];
    __shared__ float sqr[32];
    const int tid = threadIdx.x;
    const int b   = blockIdx.y;
    const int r0g = blockIdx.x * 32;
    const size_t bN = (size_t)b * ROI;

    for (int t = tid; t < 288; t += 256)
        sqj[t] = (t < ROI) ? sqv[bN + t] : __builtin_inff();
    if (tid < 32) sqr[tid] = (r0g + tid < ROI) ? sqv[bN + r0g + tid] : 0.f;

    const int l  = tid & 63;
    const int w  = tid >> 6;
    const int ra = w & 1;
    const int rtile = min(blockIdx.x * 2 + ra, 16);

    bf16x8 Ah[9], Al[9];
    {
        const size_t abase = ((size_t)(b * 17 + rtile) * 9) * 512 + l * 8;
        #pragma unroll
        for (int ks = 0; ks < 9; ++ks) {
            Ah[ks] = *(const bf16x8*)&Xh[abase + ks * 512];
            Al[ks] = *(const bf16x8*)&Xl[abase + ks * 512];
        }
    }
    __syncthreads();

    float* drow = &d2[(size_t)b * 288 * 288];
    for (int ct = (w >> 1); ct < 17; ct += 2) {
        const size_t bbase = ((size_t)(b * 17 + ct) * 9) * 512 + l * 8;
        f32x4 acc = {0.f, 0.f, 0.f, 0.f};
        #pragma unroll
        for (int ks = 0; ks < 9; ++ks) {
            bf16x8 bh = *(const bf16x8*)&Xh[bbase + ks * 512];
            bf16x8 bl = *(const bf16x8*)&Xl[bbase + ks * 512];
            acc = __builtin_amdgcn_mfma_f32_16x16x32_bf16(Ah[ks], bh, acc, 0, 0, 0);
            acc = __builtin_amdgcn_mfma_f32_16x16x32_bf16(Ah[ks], bl, acc, 0, 0, 0);
            acc = __builtin_amdgcn_mfma_f32_16x16x32_bf16(Al[ks], bh, acc, 0, 0, 0);
        }
        const int col = ct * 16 + (l & 15);
        const float sj = sqj[col];
        const int rr = ra * 16 + (l >> 4) * 4;
        #pragma unroll
        for (int i = 0; i < 4; ++i)
            drow[(size_t)(r0g + rr + i) * 288 + col] = sqr[rr + i] + sj - 2.f * acc[i];
    }
    for (int t = tid; t < 32 * 16; t += 256) {
        const int r = t >> 4, cc = 272 + (t & 15);
        drow[(size_t)(r0g + r) * 288 + cc] = __builtin_inff();
    }
}

// ---------------- K2b: top-32 via packed-key tournament ----------------
__global__ __launch_bounds__(256) void k_sel(
    const float* __restrict__ d2, int* __restrict__ knn)
{
    const int grp = blockIdx.x * 8 + (threadIdx.x >> 5);
    const int sl  = threadIdx.x & 31;
    const int b   = grp / ROI;
    const int row = grp - b * ROI;
    const float* src = &d2[((size_t)b * 288 + row) * 288];

    unsigned k[9];
    #pragma unroll
    for (int q = 0; q < 9; ++q) {
        const int idx = q * 32 + sl;
        unsigned bits = __float_as_uint(src[idx]);
        unsigned msk  = (unsigned)(((int)bits) >> 31) | 0x80000000u;
        k[q] = ((bits ^ msk) & ~0x1FFu) | (unsigned)idx;
    }
    #pragma unroll
    for (int i = 1; i < 9; ++i) {
        #pragma unroll
        for (int j = i; j > 0; --j) {
            unsigned lo = k[j-1] < k[j] ? k[j-1] : k[j];
            unsigned hi = k[j-1] < k[j] ? k[j]   : k[j-1];
            k[j-1] = lo; k[j] = hi;
        }
    }
    unsigned keep = 0;
    #pragma unroll
    for (int it = 0; it < KSEL; ++it) {
        unsigned m = k[0];
        #pragma unroll
        for (int mm = 16; mm > 0; mm >>= 1) {
            unsigned o = (unsigned)__shfl_xor((int)m, mm, 32);
            m = o < m ? o : m;
        }
        if (sl == it) keep = m;
        const bool win = (k[0] == m);
        #pragma unroll
        for (int q = 0; q < 8; ++q) k[q] = win ? k[q+1] : k[q];
        k[8] = win ? 0xFFFFFFFFu : k[8];
    }
    knn[(size_t)grp * KSEL + sl] = b * ROI + (int)(keep & 0x1FFu);
}

// ---------------- K3/K4: edge MLP second layer via MFMA + segment max ----------------
template<bool G3>
__global__ __launch_bounds__(256) void k_edge_mfma(
    const float* __restrict__ u, const float* __restrict__ v,
    const float* __restrict__ Wb, const float* __restrict__ bb,
    const int* __restrict__ nbr,
    const float* __restrict__ u3, const float* __restrict__ v3,
    float* __restrict__ aout, float* __restrict__ a3out)
{
    const int tid  = threadIdx.x;
    const int l    = tid & 63;
    const int wv   = tid >> 6;
    const int half = l >> 5;
    const int e    = l & 31;

    union { bf16x8 v8; unsigned u4[4]; } B0, B1;
    #pragma unroll
    for (int j = 0; j < 4; ++j) {
        B0.u4[j] = (unsigned)f2bf(Wb[(half * 8 + 2*j    ) * 32 + e])
                 | ((unsigned)f2bf(Wb[(half * 8 + 2*j + 1) * 32 + e]) << 16);
        B1.u4[j] = (unsigned)f2bf(Wb[(16 + half * 8 + 2*j    ) * 32 + e])
                 | ((unsigned)f2bf(Wb[(16 + half * 8 + 2*j + 1) * 32 + e]) << 16);
    }
    const float biasc = bb[e];

    for (int nn = 0; nn < 4; ++nn) {
        const int n  = blockIdx.x * 16 + wv * 4 + nn;
        const int jn = nbr[(size_t)n * DEG + e];

        float hv[16];
        #pragma unroll
        for (int s = 0; s < 2; ++s) {
            const int c0 = s * 16 + half * 8;
            float4 uv0 = *(const float4*)&u[(size_t)n  * 32 + c0];
            float4 uv1 = *(const float4*)&u[(size_t)n  * 32 + c0 + 4];
            float4 vv0 = *(const float4*)&v[(size_t)jn * 32 + c0];
            float4 vv1 = *(const float4*)&v[(size_t)jn * 32 + c0 + 4];
            hv[s*8+0] = lrelu(uv0.x + vv0.x);
            hv[s*8+1] = lrelu(uv0.y + vv0.y);
            hv[s*8+2] = lrelu(uv0.z + vv0.z);
            hv[s*8+3] = lrelu(uv0.w + vv0.w);
            hv[s*8+4] = lrelu(uv1.x + vv1.x);
            hv[s*8+5] = lrelu(uv1.y + vv1.y);
            hv[s*8+6] = lrelu(uv1.z + vv1.z);
            hv[s*8+7] = lrelu(uv1.w + vv1.w);
        }
        union { bf16x8 v8; unsigned u4[4]; } A0, A1;
        #pragma unroll
        for (int j = 0; j < 4; ++j) {
            A0.u4[j] = (unsigned)f2bf(hv[2*j])     | ((unsigned)f2bf(hv[2*j + 1]) << 16);
            A1.u4[j] = (unsigned)f2bf(hv[8 + 2*j]) | ((unsigned)f2bf(hv[8 + 2*j + 1]) << 16);
        }
        f32x16 acc = {0.f,0.f,0.f,0.f,0.f,0.f,0.f,0.f,0.f,0.f,0.f,0.f,0.f,0.f,0.f,0.f};
        acc = __builtin_amdgcn_mfma_f32_32x32x16_bf16(A0.v8, B0.v8, acc, 0, 0, 0);
        acc = __builtin_amdgcn_mfma_f32_32x32x16_bf16(A1.v8, B1.v8, acc, 0, 0, 0);

        float mx = acc[0];
        #pragma unroll
        for (int r = 1; r < 16; ++r) mx = fmaxf(mx, acc[r]);
        mx = fmaxf(mx, __shfl_xor(mx, 32));
        if (l < 32) aout[(size_t)n * 32 + l] = mx + biasc;

        if (G3) {
            float a3v = u3[n] + v3[jn];
            #pragma unroll
            for (int mm = 16; mm > 0; mm >>= 1) a3v = fmaxf(a3v, __shfl_xor(a3v, mm));
            if (l == 0) a3out[n] = a3v;
        }
    }
}

// ---------------- K5a: coalesced per-chunk partial BN stats for a1,a2 ----------------
__global__ __launch_bounds__(256) void k_stats1(
    const float* __restrict__ a1, const float* __restrict__ a2,
    float* __restrict__ part)
{
    const int p = blockIdx.x;
    const int tid = threadIdx.x;
    const int ch = tid & 31, sub = tid >> 5;
    const size_t base = (size_t)p * ROI;
    float s1 = 0.f, q1 = 0.f, s2 = 0.f, q2 = 0.f;
    for (int n = sub; n < ROI; n += 8) {
        float v1 = a1[(base + n) * 32 + ch];
        float v2 = a2[(base + n) * 32 + ch];
        s1 += v1; q1 += v1 * v1; s2 += v2; q2 += v2 * v2;
    }
    __shared__ float L[4][256];
    L[0][tid] = s1; L[1][tid] = q1; L[2][tid] = s2; L[3][tid] = q2;
    __syncthreads();
    if (tid < 128) {
        const int a = tid >> 5, c = tid & 31;
        float s = 0.f;
        #pragma unroll
        for (int k = 0; k < 8; ++k) s += L[a][c + 32 * k];
        part[p * 128 + a * 32 + c] = s;
    }
}

// ---------------- K5b: finalize BN scale/shift ----------------
__global__ __launch_bounds__(256) void k_stats2(
    const float* __restrict__ part, const float* __restrict__ a3,
    const float* __restrict__ g1, const float* __restrict__ be1,
    const float* __restrict__ g2, const float* __restrict__ be2,
    const float* __restrict__ g3, const float* __restrict__ be3,
    float* __restrict__ st)
{
    const int tid = threadIdx.x;
    // a3 scan with 4 independent accumulator streams (ILP)
    float p0 = 0.f, p1 = 0.f, p2 = 0.f, p3 = 0.f;
    float q0 = 0.f, q1 = 0.f, q2 = 0.f, q3 = 0.f;
    int n = tid;
    for (; n + 768 < NN; n += 1024) {
        float a = a3[n], b = a3[n + 256], c = a3[n + 512], d = a3[n + 768];
        p0 += a; q0 += a * a;
        p1 += b; q1 += b * b;
        p2 += c; q2 += c * c;
        p3 += d; q3 += d * d;
    }
    for (; n < NN; n += 256) { float a = a3[n]; p0 += a; q0 += a * a; }
    float s = (p0 + p1) + (p2 + p3);
    float q = (q0 + q1) + (q2 + q3);
    __shared__ float S3[256], Q3[256];
    S3[tid] = s; Q3[tid] = q; __syncthreads();
    for (int off = 128; off > 0; off >>= 1) {
        if (tid < off) { S3[tid] += S3[tid + off]; Q3[tid] += Q3[tid + off]; }
        __syncthreads();
    }
    if (tid < 64) {
        const int a = (tid >> 5) * 2, c = tid & 31;
        float s0 = 0.f, s1 = 0.f, q0b = 0.f, q1b = 0.f;
        for (int p = 0; p < 64; p += 2) {
            s0  += part[p * 128 + a * 32 + c];
            q0b += part[p * 128 + (a + 1) * 32 + c];
            s1  += part[(p + 1) * 128 + a * 32 + c];
            q1b += part[(p + 1) * 128 + (a + 1) * 32 + c];
        }
        float ss = s0 + s1, qq = q0b + q1b;
        float gv = (tid < 32) ? g1[c] : g2[c];
        float bv = (tid < 32) ? be1[c] : be2[c];
        float mu  = ss * (1.f / NN);
        float var = qq * (1.f / NN) - mu * mu;
        float sc  = gv * rsqrtf(var + EPSBN);
        st[tid * 2] = sc; st[tid * 2 + 1] = bv - mu * sc;
    }
    if (tid == 64) {
        float mu  = S3[0] * (1.f / NN);
        float var = Q3[0] * (1.f / NN) - mu * mu;
        float sc  = g3[0] * rsqrtf(var + EPSBN);
        st[128] = sc; st[129] = be3[0] - mu * sc;
    }
}

// ---------------- K6: pooled readout fused with fc1 (ILP-unrolled) ----------------
__global__ __launch_bounds__(256) void k_pool_fc1(
    const float* __restrict__ a1, const float* __restrict__ a2, const float* __restrict__ a3,
    const float* __restrict__ st, const float* __restrict__ Wl1, const float* __restrict__ bl1,
    float* __restrict__ h1)
{
    const int b = blockIdx.x, tid = threadIdx.x;
    __shared__ float zs[332];
    __shared__ float P[4][64];
    const int c = tid & 63, grp = tid >> 6;
    const float* src = (c < 32) ? a1 : a2;
    const int ch = c & 31;
    const float sc = st[c * 2], sh = st[c * 2 + 1];
    // pool: 4 independent accumulator streams
    {
        const size_t rb = (size_t)b * ROI;
        float p0 = 0.f, p1 = 0.f, p2 = 0.f, p3 = 0.f;
        int i = grp;
        for (; i + 12 < ROI; i += 16) {
            p0 += lrelu(src[(rb + i)      * 32 + ch] * sc + sh);
            p1 += lrelu(src[(rb + i + 4)  * 32 + ch] * sc + sh);
            p2 += lrelu(src[(rb + i + 8)  * 32 + ch] * sc + sh);
            p3 += lrelu(src[(rb + i + 12) * 32 + ch] * sc + sh);
        }
        for (; i < ROI; i += 4)
            p0 += lrelu(src[(rb + i) * 32 + ch] * sc + sh);
        P[grp][c] = (p0 + p1) + (p2 + p3);
    }
    const float sc3 = st[128], sh3 = st[129];
    for (int i = tid; i < ROI; i += 256)
        zs[64 + i] = lrelu(a3[b * ROI + i] * sc3 + sh3);
    __syncthreads();
    if (tid < 64)
        zs[tid] = (P[0][tid] + P[1][tid] + P[2][tid] + P[3][tid]) * (1.f / ROI);
    __syncthreads();
    // fc1: 4 independent load/accumulate streams (332 = 83*4)
    {
        float s0 = 0.f, s1 = 0.f, s2 = 0.f, s3 = 0.f;
        #pragma unroll 4
        for (int k = 0; k < 332; k += 4) {
            s0 += zs[k]     * Wl1[(size_t)k       * 256 + tid];
            s1 += zs[k + 1] * Wl1[(size_t)(k + 1) * 256 + tid];
            s2 += zs[k + 2] * Wl1[(size_t)(k + 2) * 256 + tid];
            s3 += zs[k + 3] * Wl1[(size_t)(k + 3) * 256 + tid];
        }
        h1[(size_t)b * 256 + tid] = bl1[tid] + ((s0 + s1) + (s2 + s3));
    }
}

// ---------------- K8/K10: BN stats over B rows (ILP-unrolled) ----------------
__global__ void k_stats_rows(const float* __restrict__ h, int C,
                             const float* __restrict__ g, const float* __restrict__ be,
                             float* __restrict__ st)
{
    const int o = threadIdx.x;
    if (o >= C) return;
    float s0 = 0.f, s1 = 0.f, s2 = 0.f, s3 = 0.f;
    float q0 = 0.f, q1 = 0.f, q2 = 0.f, q3 = 0.f;
    for (int b2 = 0; b2 < NB; b2 += 4) {
        float a = h[(size_t)b2 * C + o];
        float b = h[(size_t)(b2 + 1) * C + o];
        float c = h[(size_t)(b2 + 2) * C + o];
        float d = h[(size_t)(b2 + 3) * C + o];
        s0 += a; q0 += a * a;
        s1 += b; q1 += b * b;
        s2 += c; q2 += c * c;
        s3 += d; q3 += d * d;
    }
    float s = (s0 + s1) + (s2 + s3);
    float ss = (q0 + q1) + (q2 + q3);
    float mu  = s * (1.f / NB);
    float var = ss * (1.f / NB) - mu * mu;
    float sc  = g[o] * rsqrtf(var + EPSBN);
    st[o * 2] = sc; st[o * 2 + 1] = be[o] - mu * sc;
}

// ---------------- K9: h2 = leaky(bn(h1)) @ Wl2 + bl2 (ILP-unrolled) ----------------
__global__ __launch_bounds__(128) void k_fc2(
    const float* __restrict__ h1, const float* __restrict__ st,
    const float* __restrict__ Wl2, const float* __restrict__ bl2,
    float* __restrict__ h2)
{
    const int b = blockIdx.x, tid = threadIdx.x;
    __shared__ float hs[256];
    for (int i = tid; i < 256; i += 128)
        hs[i] = lrelu(h1[(size_t)b * 256 + i] * st[i * 2] + st[i * 2 + 1]);
    __syncthreads();
    float s0 = 0.f, s1 = 0.f, s2 = 0.f, s3 = 0.f;
    #pragma unroll 4
    for (int k = 0; k < 256; k += 4) {
        s0 += hs[k]     * Wl2[(size_t)k       * 128 + tid];
        s1 += hs[k + 1] * Wl2[(size_t)(k + 1) * 128 + tid];
        s2 += hs[k + 2] * Wl2[(size_t)(k + 2) * 128 + tid];
        s3 += hs[k + 3] * Wl2[(size_t)(k + 3) * 128 + tid];
    }
    h2[(size_t)b * 128 + tid] = bl2[tid] + ((s0 + s1) + (s2 + s3));
}

// ---------------- K11: out (ILP-unrolled) ----------------
__global__ void k_fc3(
    const float* __restrict__ h2, const float* __restrict__ st,
    const float* __restrict__ Wl3, const float* __restrict__ bl3,
    float* __restrict__ out)
{
    const int b = threadIdx.x;
    if (b >= NB) return;
    float s0 = 0.f, s1 = 0.f, s2 = 0.f, s3 = 0.f;
    for (int c = 0; c < 128; c += 4) {
        s0 += lrelu(h2[(size_t)b * 128 + c]     * st[c * 2]       + st[c * 2 + 1])       * Wl3[c];
        s1 += lrelu(h2[(size_t)b * 128 + c + 1] * st[(c + 1) * 2] + st[(c + 1) * 2 + 1]) * Wl3[c + 1];
        s2 += lrelu(h2[(size_t)b * 128 + c + 2] * st[(c + 2) * 2] + st[(c + 2) * 2 + 1]) * Wl3[c + 2];
        s3 += lrelu(h2[(size_t)b * 128 + c + 3] * st[(c + 3) * 2] + st[(c + 3) * 2 + 1]) * Wl3[c + 3];
    }
    out[b] = bl3[0] + ((s0 + s1) + (s2 + s3));
}

extern "C" void kernel_launch(void* const* d_in, const int* in_sizes, int n_in,
                              void* d_out, int out_size, void* d_ws, size_t ws_size,
                              hipStream_t stream)
{
    (void)in_sizes; (void)n_in; (void)out_size; (void)ws_size;
    const float* x   = (const float*)d_in[0];
    const int*   ei  = (const int*)d_in[1];
    const float* W1a = (const float*)d_in[3];
    const float* b1a = (const float*)d_in[4];
    const float* W1b = (const float*)d_in[5];
    const float* b1b = (const float*)d_in[6];
    const float* g1  = (const float*)d_in[7];
    const float* be1 = (const float*)d_in[8];
    const float* W2a = (const float*)d_in[9];
    const float* b2a = (const float*)d_in[10];
    const float* W2b = (const float*)d_in[11];
    const float* b2b = (const float*)d_in[12];
    const float* g2  = (const float*)d_in[13];
    const float* be2 = (const float*)d_in[14];
    const float* W3  = (const float*)d_in[15];
    const float* b3  = (const float*)d_in[16];
    const float* g3  = (const float*)d_in[17];
    const float* be3 = (const float*)d_in[18];
    const float* Wl1 = (const float*)d_in[19];
    const float* bl1 = (const float*)d_in[20];
    const float* g4  = (const float*)d_in[21];
    const float* be4 = (const float*)d_in[22];
    const float* Wl2 = (const float*)d_in[23];
    const float* bl2 = (const float*)d_in[24];
    const float* g5  = (const float*)d_in[25];
    const float* be5 = (const float*)d_in[26];
    const float* Wl3 = (const float*)d_in[27];
    const float* bl3 = (const float*)d_in[28];

    float* ws  = (float*)d_ws;
    float* u1  = ws;
    float* v1  = u1 + (size_t)NN * 32;
    float* u2  = v1 + (size_t)NN * 32;
    float* v2  = u2 + (size_t)NN * 32;
    float* u3  = v2 + (size_t)NN * 32;
    float* v3  = u3 + NN;
    float* sqv = v3 + NN;
    float* a1  = sqv + NN;
    float* a2  = a1 + (size_t)NN * 32;
    float* a3  = a2 + (size_t)NN * 32;
    int*   knn = (int*)(a3 + NN);
    float* st  = (float*)(knn + (size_t)NN * 32);
    float* z   = st + 130;
    float* h1  = z + (size_t)NB * 332;
    float* h2  = h1 + (size_t)NB * 256;
    float* s4  = h2 + (size_t)NB * 128;
    float* s5  = s4 + 512;
    float* part = s5 + 512;                         // [64][128]
    unsigned short* Xh = (unsigned short*)(((uintptr_t)(part + 64 * 128) + 255) & ~(uintptr_t)255);
    unsigned short* Xl = Xh + (size_t)64 * 17 * 9 * 512;
    float* d2 = (float*)(((uintptr_t)(Xl + (size_t)64 * 17 * 9 * 512) + 255) & ~(uintptr_t)255);
    unsigned short* Wfh = (unsigned short*)(d2 + (size_t)64 * 288 * 288);
    unsigned short* Wfl = Wfh + (size_t)8 * 9 * 512;

    k_pack<<<(64 * 17 * 9 * 64) / 256, 256, 0, stream>>>(x, Xh, Xl);
    k_packw<<<18, 256, 0, stream>>>(W1a, W2a, Wfh, Wfl);
    k_scalars<<<NN / 4, 256, 0, stream>>>(x, W3, b3, u3, v3, sqv);
    k_proj_mfma<<<1088, 256, 0, stream>>>(Xh, Xl, Wfh, Wfl, b1a, b2a, u1, v1, u2, v2);
    k_dist<<<dim3(9, NB), 256, 0, stream>>>(Xh, Xl, sqv, d2);
    k_sel<<<NN / 8, 256, 0, stream>>>(d2, knn);
    k_edge_mfma<true><<<NN / 16, 256, 0, stream>>>(u1, v1, W1b, b1b, ei, u3, v3, a1, a3);
    k_edge_mfma<false><<<NN / 16, 256, 0, stream>>>(u2, v2, W2b, b2b, knn, nullptr, nullptr, a2, nullptr);
    k_stats1<<<64, 256, 0, stream>>>(a1, a2, part);
    k_stats2<<<1, 256, 0, stream>>>(part, a3, g1, be1, g2, be2, g3, be3, st);
    k_pool_fc1<<<NB, 256, 0, stream>>>(a1, a2, a3, st, Wl1, bl1, h1);
    k_stats_rows<<<1, 256, 0, stream>>>(h1, 256, g4, be4, s4);
    k_fc2<<<NB, 128, 0, stream>>>(h1, s4, Wl2, bl2, h2);
    k_stats_rows<<<1, 128, 0, stream>>>(h2, 128, g5, be5, s5);
    k_fc3<<<1, 64, 0, stream>>>(h2, s5, Wl3, bl3, (float*)d_out);
}

// Round 9
// 161.110 us; speedup vs baseline: 4.3040x; 1.1085x over previous
//
#include <hip/hip_runtime.h>
#include <hip/hip_bf16.h>

#define ROI   268
#define FDIM  268
#define NB    64
#define NN    (NB*ROI)     // 17152
#define CC    32
#define DEG   32
#define KSEL  32
#define SLOPE 0.33f
#define EPSBN 1e-5f

typedef __attribute__((ext_vector_type(8)))  short bf16x8;
typedef __attribute__((ext_vector_type(4)))  float f32x4;
typedef __attribute__((ext_vector_type(16))) float f32x16;

__device__ __forceinline__ float lrelu(float h) { return h >= 0.f ? h : SLOPE * h; }

__device__ __forceinline__ unsigned short f2bf(float f) {
    union { __hip_bfloat16 h; unsigned short s; } u;
    u.h = __float2bfloat16(f);   // RNE, lowers to HW cvt
    return u.s;
}
__device__ __forceinline__ float bf2f(unsigned short h) {
    return __uint_as_float(((unsigned int)h) << 16);
}

// ================= K1: fused prep — pack(x) | packw | scalars =================
// blocks [0,2448): pack x frags; [2448,2466): pack W frags; [2466,3538): u3/v3/sq
#define PREP_PACK_BLOCKS  2448
#define PREP_PACKW_BLOCKS 18
#define PREP_SCAL_BLOCKS  1072

__global__ __launch_bounds__(256) void k_prep(
    const float* __restrict__ x,
    const float* __restrict__ W1a, const float* __restrict__ W2a,
    const float* __restrict__ W3,  const float* __restrict__ b3,
    unsigned short* __restrict__ Xh, unsigned short* __restrict__ Xl,
    unsigned short* __restrict__ Wfh, unsigned short* __restrict__ Wfl,
    float* __restrict__ u3, float* __restrict__ v3, float* __restrict__ sqv)
{
    const int bid = blockIdx.x;
    const int tid = threadIdx.x;
    if (bid < PREP_PACK_BLOCKS) {
        // ---- pack x into MFMA-fragment-ordered split-bf16 ----
        const int gid = bid * 256 + tid;
        const int l   = gid & 63;
        const int f3  = gid >> 6;
        const int ks  = f3 % 9;
        const int bc  = f3 / 9;
        const int ct  = bc % 17;
        const int b   = bc / 17;
        const int node = ct * 16 + (l & 15);
        const int k0   = ks * 32 + (l >> 4) * 8;
        float f[8];
        #pragma unroll
        for (int j = 0; j < 8; ++j) f[j] = 0.f;
        if (node < ROI) {
            const float* row = &x[((size_t)b * ROI + node) * FDIM];
            if (k0 + 3 < FDIM) { float4 v = *(const float4*)&row[k0];     f[0]=v.x; f[1]=v.y; f[2]=v.z; f[3]=v.w; }
            if (k0 + 7 < FDIM) { float4 v = *(const float4*)&row[k0 + 4]; f[4]=v.x; f[5]=v.y; f[6]=v.z; f[7]=v.w; }
        }
        unsigned short hh[8], ll[8];
        #pragma unroll
        for (int j = 0; j < 8; ++j) {
            hh[j] = f2bf(f[j]);
            ll[j] = f2bf(f[j] - bf2f(hh[j]));
        }
        uint4 hp, lp;
        hp.x = (unsigned)hh[0] | ((unsigned)hh[1] << 16); hp.y = (unsigned)hh[2] | ((unsigned)hh[3] << 16);
        hp.z = (unsigned)hh[4] | ((unsigned)hh[5] << 16); hp.w = (unsigned)hh[6] | ((unsigned)hh[7] << 16);
        lp.x = (unsigned)ll[0] | ((unsigned)ll[1] << 16); lp.y = (unsigned)ll[2] | ((unsigned)ll[3] << 16);
        lp.z = (unsigned)ll[4] | ((unsigned)ll[5] << 16); lp.w = (unsigned)ll[6] | ((unsigned)ll[7] << 16);
        const size_t base = (size_t)f3 * 512 + l * 8;
        *(uint4*)&Xh[base] = hp;
        *(uint4*)&Xl[base] = lp;
    } else if (bid < PREP_PACK_BLOCKS + PREP_PACKW_BLOCKS) {
        // ---- pack projection weights into split-bf16 B-fragments ----
        const int gid = (bid - PREP_PACK_BLOCKS) * 256 + tid;   // < 4608
        const int l  = gid & 63;
        const int f3 = gid >> 6;        // 0..71 : mc*9 + ks
        const int ks = f3 % 9;
        const int mc = f3 / 9;          // m*2+ct
        const int ct = mc & 1;
        const int m  = mc >> 1;
        const int k0 = ks * 32 + (l >> 4) * 8;
        const int c  = ct * 16 + (l & 15);
        const float* W = (m < 2) ? W1a : W2a;
        const bool isU = (m & 1) == 0;
        unsigned short hh[8], ll[8];
        #pragma unroll
        for (int j = 0; j < 8; ++j) {
            const int kk = k0 + j;
            float val = 0.f;
            if (kk < FDIM) {
                float wb = W[(size_t)(FDIM + kk) * CC + c];
                val = isU ? (W[(size_t)kk * CC + c] - wb) : wb;
            }
            hh[j] = f2bf(val);
            ll[j] = f2bf(val - bf2f(hh[j]));
        }
        uint4 hp, lp;
        hp.x = (unsigned)hh[0] | ((unsigned)hh[1] << 16); hp.y = (unsigned)hh[2] | ((unsigned)hh[3] << 16);
        hp.z = (unsigned)hh[4] | ((unsigned)hh[5] << 16); hp.w = (unsigned)hh[6] | ((unsigned)hh[7] << 16);
        lp.x = (unsigned)ll[0] | ((unsigned)ll[1] << 16); lp.y = (unsigned)ll[2] | ((unsigned)ll[3] << 16);
        lp.z = (unsigned)ll[4] | ((unsigned)ll[5] << 16); lp.w = (unsigned)ll[6] | ((unsigned)ll[7] << 16);
        const size_t base = (size_t)f3 * 512 + l * 8;
        *(uint4*)&Wfh[base] = hp;
        *(uint4*)&Wfl[base] = lp;
    } else {
        // ---- scalar projections u3, v3 and squared norms (16 nodes/block) ----
        const int s = bid - (PREP_PACK_BLOCKS + PREP_PACKW_BLOCKS);
        const int l = tid & 63;
        #pragma unroll
        for (int i = 0; i < 4; ++i) {
            const int n = s * 16 + i * 4 + (tid >> 6);
            const float* row = &x[(size_t)n * FDIM];
            float su = 0.f, sv = 0.f, sq = 0.f;
            #pragma unroll
            for (int t = 0; t < 4; ++t) {
                const int f = l + 64 * t;
                float xv = row[f];
                float wv = W3[FDIM + f];
                float wu = W3[f] - wv;
                su += xv * wu; sv += xv * wv; sq += xv * xv;
            }
            if (l < 12) {
                const int f = 256 + l;
                float xv = row[f];
                float wv = W3[FDIM + f];
                float wu = W3[f] - wv;
                su += xv * wu; sv += xv * wv; sq += xv * xv;
            }
            #pragma unroll
            for (int mm = 32; mm > 0; mm >>= 1) {
                su += __shfl_xor(su, mm);
                sv += __shfl_xor(sv, mm);
                sq += __shfl_xor(sq, mm);
            }
            if (l == 0) {
                u3[n] = su + b3[0];
                v3[n] = sv;
                sqv[n] = sq;
            }
        }
    }
}

// ---------------- K1d: node projections u1,v1,u2,v2 via MFMA (split-bf16) ---------
__global__ __launch_bounds__(256) void k_proj_mfma(
    const unsigned short* __restrict__ Xh, const unsigned short* __restrict__ Xl,
    const unsigned short* __restrict__ Wfh, const unsigned short* __restrict__ Wfl,
    const float* __restrict__ b1a, const float* __restrict__ b2a,
    float* __restrict__ u1, float* __restrict__ v1,
    float* __restrict__ u2, float* __restrict__ v2)
{
    const int tid = threadIdx.x;
    const int l   = tid & 63;
    const int m   = tid >> 6;         // wave = matrix 0..3
    const int tile = blockIdx.x;      // 0..1087 = b*17+ctn
    const int b    = tile / 17;
    const int ctn  = tile % 17;

    bf16x8 Ah[9], Al[9];
    {
        const size_t abase = (size_t)tile * 9 * 512 + l * 8;
        #pragma unroll
        for (int ks = 0; ks < 9; ++ks) {
            Ah[ks] = *(const bf16x8*)&Xh[abase + ks * 512];
            Al[ks] = *(const bf16x8*)&Xl[abase + ks * 512];
        }
    }
    float* outp = (m == 0) ? u1 : (m == 1) ? v1 : (m == 2) ? u2 : v2;

    #pragma unroll
    for (int ct = 0; ct < 2; ++ct) {
        const size_t wbase = ((size_t)((m * 2 + ct) * 9)) * 512 + l * 8;
        f32x4 acc = {0.f, 0.f, 0.f, 0.f};
        #pragma unroll
        for (int ks = 0; ks < 9; ++ks) {
            bf16x8 bh = *(const bf16x8*)&Wfh[wbase + ks * 512];
            bf16x8 bl = *(const bf16x8*)&Wfl[wbase + ks * 512];
            acc = __builtin_amdgcn_mfma_f32_16x16x32_bf16(Ah[ks], bh, acc, 0, 0, 0);
            acc = __builtin_amdgcn_mfma_f32_16x16x32_bf16(Ah[ks], bl, acc, 0, 0, 0);
            acc = __builtin_amdgcn_mfma_f32_16x16x32_bf16(Al[ks], bh, acc, 0, 0, 0);
        }
        const int ch = ct * 16 + (l & 15);
        float bias = 0.f;
        if (m == 0) bias = b1a[ch];
        else if (m == 2) bias = b2a[ch];
        const int r0 = (l >> 4) * 4;
        #pragma unroll
        for (int i = 0; i < 4; ++i) {
            const int node = ctn * 16 + r0 + i;
            if (node < ROI)
                outp[((size_t)b * ROI + node) * 32 + ch] = acc[i] + bias;
        }
    }
}

// ---------------- K2a: d2 matrix via MFMA (A-frags in regs, B from global) ----------
__global__ __launch_bounds__(256) void k_dist(
    const unsigned short* __restrict__ Xh, const unsigned short* __restrict__ Xl,
    const float* __restrict__ sqv, float* __restrict__ d2)
{
    __shared__ float sqj[288];
    __shared__ float sqr[32];
    const int tid = threadIdx.x;
    const int b   = blockIdx.y;
    const int r0g = blockIdx.x * 32;
    const size_t bN = (size_t)b * ROI;

    for (int t = tid; t < 288; t += 256)
        sqj[t] = (t < ROI) ? sqv[bN + t] : __builtin_inff();
    if (tid < 32) sqr[tid] = (r0g + tid < ROI) ? sqv[bN + r0g + tid] : 0.f;

    const int l  = tid & 63;
    const int w  = tid >> 6;
    const int ra = w & 1;
    const int rtile = min(blockIdx.x * 2 + ra, 16);

    bf16x8 Ah[9], Al[9];
    {
        const size_t abase = ((size_t)(b * 17 + rtile) * 9) * 512 + l * 8;
        #pragma unroll
        for (int ks = 0; ks < 9; ++ks) {
            Ah[ks] = *(const bf16x8*)&Xh[abase + ks * 512];
            Al[ks] = *(const bf16x8*)&Xl[abase + ks * 512];
        }
    }
    __syncthreads();

    float* drow = &d2[(size_t)b * 288 * 288];
    for (int ct = (w >> 1); ct < 17; ct += 2) {
        const size_t bbase = ((size_t)(b * 17 + ct) * 9) * 512 + l * 8;
        f32x4 acc = {0.f, 0.f, 0.f, 0.f};
        #pragma unroll
        for (int ks = 0; ks < 9; ++ks) {
            bf16x8 bh = *(const bf16x8*)&Xh[bbase + ks * 512];
            bf16x8 bl = *(const bf16x8*)&Xl[bbase + ks * 512];
            acc = __builtin_amdgcn_mfma_f32_16x16x32_bf16(Ah[ks], bh, acc, 0, 0, 0);
            acc = __builtin_amdgcn_mfma_f32_16x16x32_bf16(Ah[ks], bl, acc, 0, 0, 0);
            acc = __builtin_amdgcn_mfma_f32_16x16x32_bf16(Al[ks], bh, acc, 0, 0, 0);
        }
        const int col = ct * 16 + (l & 15);
        const float sj = sqj[col];
        const int rr = ra * 16 + (l >> 4) * 4;
        #pragma unroll
        for (int i = 0; i < 4; ++i)
            drow[(size_t)(r0g + rr + i) * 288 + col] = sqr[rr + i] + sj - 2.f * acc[i];
    }
    for (int t = tid; t < 32 * 16; t += 256) {
        const int r = t >> 4, cc = 272 + (t & 15);
        drow[(size_t)(r0g + r) * 288 + cc] = __builtin_inff();
    }
}

// ---------------- K2b: top-32 via packed-key tournament ----------------
__global__ __launch_bounds__(256) void k_sel(
    const float* __restrict__ d2, int* __restrict__ knn)
{
    const int grp = blockIdx.x * 8 + (threadIdx.x >> 5);
    const int sl  = threadIdx.x & 31;
    const int b   = grp / ROI;
    const int row = grp - b * ROI;
    const float* src = &d2[((size_t)b * 288 + row) * 288];

    unsigned k[9];
    #pragma unroll
    for (int q = 0; q < 9; ++q) {
        const int idx = q * 32 + sl;
        unsigned bits = __float_as_uint(src[idx]);
        unsigned msk  = (unsigned)(((int)bits) >> 31) | 0x80000000u;
        k[q] = ((bits ^ msk) & ~0x1FFu) | (unsigned)idx;
    }
    #pragma unroll
    for (int i = 1; i < 9; ++i) {
        #pragma unroll
        for (int j = i; j > 0; --j) {
            unsigned lo = k[j-1] < k[j] ? k[j-1] : k[j];
            unsigned hi = k[j-1] < k[j] ? k[j]   : k[j-1];
            k[j-1] = lo; k[j] = hi;
        }
    }
    unsigned keep = 0;
    #pragma unroll
    for (int it = 0; it < KSEL; ++it) {
        unsigned m = k[0];
        #pragma unroll
        for (int mm = 16; mm > 0; mm >>= 1) {
            unsigned o = (unsigned)__shfl_xor((int)m, mm, 32);
            m = o < m ? o : m;
        }
        if (sl == it) keep = m;
        const bool win = (k[0] == m);
        #pragma unroll
        for (int q = 0; q < 8; ++q) k[q] = win ? k[q+1] : k[q];
        k[8] = win ? 0xFFFFFFFFu : k[8];
    }
    knn[(size_t)grp * KSEL + sl] = b * ROI + (int)(keep & 0x1FFu);
}

// ======== K3: fused edge MLP (gcn1 blocks [0,1072), gcn2 blocks [1072,2144)) ========
__global__ __launch_bounds__(256) void k_edge_both(
    const float* __restrict__ u1, const float* __restrict__ v1,
    const float* __restrict__ W1b, const float* __restrict__ b1b,
    const int* __restrict__ ei,
    const float* __restrict__ u2, const float* __restrict__ v2,
    const float* __restrict__ W2b, const float* __restrict__ b2b,
    const int* __restrict__ knn,
    const float* __restrict__ u3, const float* __restrict__ v3,
    float* __restrict__ a1, float* __restrict__ a2, float* __restrict__ a3)
{
    const int tid  = threadIdx.x;
    const int l    = tid & 63;
    const int wv   = tid >> 6;
    const int half = l >> 5;
    const int e    = l & 31;
    const bool g1 = blockIdx.x < (NN / 16);
    const int  nb = g1 ? blockIdx.x : blockIdx.x - (NN / 16);
    const float* u  = g1 ? u1 : u2;
    const float* v  = g1 ? v1 : v2;
    const float* Wb = g1 ? W1b : W2b;
    const float* bb = g1 ? b1b : b2b;
    const int* nbr  = g1 ? ei : knn;
    float* aout     = g1 ? a1 : a2;

    union { bf16x8 v8; unsigned u4[4]; } B0, B1;
    #pragma unroll
    for (int j = 0; j < 4; ++j) {
        B0.u4[j] = (unsigned)f2bf(Wb[(half * 8 + 2*j    ) * 32 + e])
                 | ((unsigned)f2bf(Wb[(half * 8 + 2*j + 1) * 32 + e]) << 16);
        B1.u4[j] = (unsigned)f2bf(Wb[(16 + half * 8 + 2*j    ) * 32 + e])
                 | ((unsigned)f2bf(Wb[(16 + half * 8 + 2*j + 1) * 32 + e]) << 16);
    }
    const float biasc = bb[e];

    for (int nn = 0; nn < 4; ++nn) {
        const int n  = nb * 16 + wv * 4 + nn;
        const int jn = nbr[(size_t)n * DEG + e];

        float hv[16];
        #pragma unroll
        for (int s = 0; s < 2; ++s) {
            const int c0 = s * 16 + half * 8;
            float4 uv0 = *(const float4*)&u[(size_t)n  * 32 + c0];
            float4 uv1 = *(const float4*)&u[(size_t)n  * 32 + c0 + 4];
            float4 vv0 = *(const float4*)&v[(size_t)jn * 32 + c0];
            float4 vv1 = *(const float4*)&v[(size_t)jn * 32 + c0 + 4];
            hv[s*8+0] = lrelu(uv0.x + vv0.x);
            hv[s*8+1] = lrelu(uv0.y + vv0.y);
            hv[s*8+2] = lrelu(uv0.z + vv0.z);
            hv[s*8+3] = lrelu(uv0.w + vv0.w);
            hv[s*8+4] = lrelu(uv1.x + vv1.x);
            hv[s*8+5] = lrelu(uv1.y + vv1.y);
            hv[s*8+6] = lrelu(uv1.z + vv1.z);
            hv[s*8+7] = lrelu(uv1.w + vv1.w);
        }
        union { bf16x8 v8; unsigned u4[4]; } A0, A1;
        #pragma unroll
        for (int j = 0; j < 4; ++j) {
            A0.u4[j] = (unsigned)f2bf(hv[2*j])     | ((unsigned)f2bf(hv[2*j + 1]) << 16);
            A1.u4[j] = (unsigned)f2bf(hv[8 + 2*j]) | ((unsigned)f2bf(hv[8 + 2*j + 1]) << 16);
        }
        f32x16 acc = {0.f,0.f,0.f,0.f,0.f,0.f,0.f,0.f,0.f,0.f,0.f,0.f,0.f,0.f,0.f,0.f};
        acc = __builtin_amdgcn_mfma_f32_32x32x16_bf16(A0.v8, B0.v8, acc, 0, 0, 0);
        acc = __builtin_amdgcn_mfma_f32_32x32x16_bf16(A1.v8, B1.v8, acc, 0, 0, 0);

        float mx = acc[0];
        #pragma unroll
        for (int r = 1; r < 16; ++r) mx = fmaxf(mx, acc[r]);
        mx = fmaxf(mx, __shfl_xor(mx, 32));
        if (l < 32) aout[(size_t)n * 32 + l] = mx + biasc;

        if (g1) {
            float a3v = u3[n] + v3[jn];
            #pragma unroll
            for (int mm = 16; mm > 0; mm >>= 1) a3v = fmaxf(a3v, __shfl_xor(a3v, mm));
            if (l == 0) a3[n] = a3v;
        }
    }
}

// ---------------- K5a: coalesced per-chunk partial BN stats for a1,a2 ----------------
__global__ __launch_bounds__(256) void k_stats1(
    const float* __restrict__ a1, const float* __restrict__ a2,
    float* __restrict__ part)
{
    const int p = blockIdx.x;
    const int tid = threadIdx.x;
    const int ch = tid & 31, sub = tid >> 5;
    const size_t base = (size_t)p * ROI;
    float s1 = 0.f, q1 = 0.f, s2 = 0.f, q2 = 0.f;
    for (int n = sub; n < ROI; n += 8) {
        float v1 = a1[(base + n) * 32 + ch];
        float v2 = a2[(base + n) * 32 + ch];
        s1 += v1; q1 += v1 * v1; s2 += v2; q2 += v2 * v2;
    }
    __shared__ float L[4][256];
    L[0][tid] = s1; L[1][tid] = q1; L[2][tid] = s2; L[3][tid] = q2;
    __syncthreads();
    if (tid < 128) {
        const int a = tid >> 5, c = tid & 31;
        float s = 0.f;
        #pragma unroll
        for (int k = 0; k < 8; ++k) s += L[a][c + 32 * k];
        part[p * 128 + a * 32 + c] = s;
    }
}

// ---------------- K5b: finalize BN scale/shift ----------------
__global__ __launch_bounds__(256) void k_stats2(
    const float* __restrict__ part, const float* __restrict__ a3,
    const float* __restrict__ g1, const float* __restrict__ be1,
    const float* __restrict__ g2, const float* __restrict__ be2,
    const float* __restrict__ g3, const float* __restrict__ be3,
    float* __restrict__ st)
{
    const int tid = threadIdx.x;
    float p0 = 0.f, p1 = 0.f, p2 = 0.f, p3 = 0.f;
    float q0 = 0.f, q1 = 0.f, q2 = 0.f, q3 = 0.f;
    int n = tid;
    for (; n + 768 < NN; n += 1024) {
        float a = a3[n], b = a3[n + 256], c = a3[n + 512], d = a3[n + 768];
        p0 += a; q0 += a * a;
        p1 += b; q1 += b * b;
        p2 += c; q2 += c * c;
        p3 += d; q3 += d * d;
    }
    for (; n < NN; n += 256) { float a = a3[n]; p0 += a; q0 += a * a; }
    float s = (p0 + p1) + (p2 + p3);
    float q = (q0 + q1) + (q2 + q3);
    __shared__ float S3[256], Q3[256];
    S3[tid] = s; Q3[tid] = q; __syncthreads();
    for (int off = 128; off > 0; off >>= 1) {
        if (tid < off) { S3[tid] += S3[tid + off]; Q3[tid] += Q3[tid + off]; }
        __syncthreads();
    }
    if (tid < 64) {
        const int a = (tid >> 5) * 2, c = tid & 31;
        float s0 = 0.f, s1 = 0.f, q0b = 0.f, q1b = 0.f;
        for (int p = 0; p < 64; p += 2) {
            s0  += part[p * 128 + a * 32 + c];
            q0b += part[p * 128 + (a + 1) * 32 + c];
            s1  += part[(p + 1) * 128 + a * 32 + c];
            q1b += part[(p + 1) * 128 + (a + 1) * 32 + c];
        }
        float ss = s0 + s1, qq = q0b + q1b;
        float gv = (tid < 32) ? g1[c] : g2[c];
        float bv = (tid < 32) ? be1[c] : be2[c];
        float mu  = ss * (1.f / NN);
        float var = qq * (1.f / NN) - mu * mu;
        float sc  = gv * rsqrtf(var + EPSBN);
        st[tid * 2] = sc; st[tid * 2 + 1] = bv - mu * sc;
    }
    if (tid == 64) {
        float mu  = S3[0] * (1.f / NN);
        float var = Q3[0] * (1.f / NN) - mu * mu;
        float sc  = g3[0] * rsqrtf(var + EPSBN);
        st[128] = sc; st[129] = be3[0] - mu * sc;
    }
}

// ---------------- K6: pooled readout fused with fc1 (ILP-unrolled) ----------------
__global__ __launch_bounds__(256) void k_pool_fc1(
    const float* __restrict__ a1, const float* __restrict__ a2, const float* __restrict__ a3,
    const float* __restrict__ st, const float* __restrict__ Wl1, const float* __restrict__ bl1,
    float* __restrict__ h1)
{
    const int b = blockIdx.x, tid = threadIdx.x;
    __shared__ float zs[332];
    __shared__ float P[4][64];
    const int c = tid & 63, grp = tid >> 6;
    const float* src = (c < 32) ? a1 : a2;
    const int ch = c & 31;
    const float sc = st[c * 2], sh = st[c * 2 + 1];
    {
        const size_t rb = (size_t)b * ROI;
        float p0 = 0.f, p1 = 0.f, p2 = 0.f, p3 = 0.f;
        int i = grp;
        for (; i + 12 < ROI; i += 16) {
            p0 += lrelu(src[(rb + i)      * 32 + ch] * sc + sh);
            p1 += lrelu(src[(rb + i + 4)  * 32 + ch] * sc + sh);
            p2 += lrelu(src[(rb + i + 8)  * 32 + ch] * sc + sh);
            p3 += lrelu(src[(rb + i + 12) * 32 + ch] * sc + sh);
        }
        for (; i < ROI; i += 4)
            p0 += lrelu(src[(rb + i) * 32 + ch] * sc + sh);
        P[grp][c] = (p0 + p1) + (p2 + p3);
    }
    const float sc3 = st[128], sh3 = st[129];
    for (int i = tid; i < ROI; i += 256)
        zs[64 + i] = lrelu(a3[b * ROI + i] * sc3 + sh3);
    __syncthreads();
    if (tid < 64)
        zs[tid] = (P[0][tid] + P[1][tid] + P[2][tid] + P[3][tid]) * (1.f / ROI);
    __syncthreads();
    {
        float s0 = 0.f, s1 = 0.f, s2 = 0.f, s3 = 0.f;
        #pragma unroll 4
        for (int k = 0; k < 332; k += 4) {
            s0 += zs[k]     * Wl1[(size_t)k       * 256 + tid];
            s1 += zs[k + 1] * Wl1[(size_t)(k + 1) * 256 + tid];
            s2 += zs[k + 2] * Wl1[(size_t)(k + 2) * 256 + tid];
            s3 += zs[k + 3] * Wl1[(size_t)(k + 3) * 256 + tid];
        }
        h1[(size_t)b * 256 + tid] = bl1[tid] + ((s0 + s1) + (s2 + s3));
    }
}

// ======== K9: fc2 with fused batch stats (each block recomputes stats from L2) ========
__global__ __launch_bounds__(128) void k_fc2s(
    const float* __restrict__ h1,
    const float* __restrict__ g4, const float* __restrict__ be4,
    const float* __restrict__ Wl2, const float* __restrict__ bl2,
    float* __restrict__ h2)
{
    const int b = blockIdx.x, tid = threadIdx.x;
    __shared__ float hs[256];
    // stats for channels tid and tid+128 over the 64 batch rows (ILP: 4 streams)
    float s0 = 0.f, q0 = 0.f, s1 = 0.f, q1 = 0.f;
    float s2 = 0.f, q2 = 0.f, s3 = 0.f, q3 = 0.f;
    for (int r = 0; r < NB; r += 2) {
        float a = h1[(size_t)r * 256 + tid];
        float c = h1[(size_t)r * 256 + tid + 128];
        float d = h1[(size_t)(r + 1) * 256 + tid];
        float e = h1[(size_t)(r + 1) * 256 + tid + 128];
        s0 += a; q0 += a * a;
        s1 += c; q1 += c * c;
        s2 += d; q2 += d * d;
        s3 += e; q3 += e * e;
    }
    {
        float ssA = s0 + s2, qqA = q0 + q2;
        float muA = ssA * (1.f / NB);
        float vaA = qqA * (1.f / NB) - muA * muA;
        float scA = g4[tid] * rsqrtf(vaA + EPSBN);
        float shA = be4[tid] - muA * scA;
        hs[tid] = lrelu(h1[(size_t)b * 256 + tid] * scA + shA);
        float ssB = s1 + s3, qqB = q1 + q3;
        float muB = ssB * (1.f / NB);
        float vaB = qqB * (1.f / NB) - muB * muB;
        float scB = g4[tid + 128] * rsqrtf(vaB + EPSBN);
        float shB = be4[tid + 128] - muB * scB;
        hs[tid + 128] = lrelu(h1[(size_t)b * 256 + tid + 128] * scB + shB);
    }
    __syncthreads();
    float s0b = 0.f, s1b = 0.f, s2b = 0.f, s3b = 0.f;
    #pragma unroll 4
    for (int k = 0; k < 256; k += 4) {
        s0b += hs[k]     * Wl2[(size_t)k       * 128 + tid];
        s1b += hs[k + 1] * Wl2[(size_t)(k + 1) * 128 + tid];
        s2b += hs[k + 2] * Wl2[(size_t)(k + 2) * 128 + tid];
        s3b += hs[k + 3] * Wl2[(size_t)(k + 3) * 128 + tid];
    }
    h2[(size_t)b * 128 + tid] = bl2[tid] + ((s0b + s1b) + (s2b + s3b));
}

// ======== K11: fc3 with fused batch stats (single block) ========
__global__ __launch_bounds__(128) void k_fc3s(
    const float* __restrict__ h2,
    const float* __restrict__ g5, const float* __restrict__ be5,
    const float* __restrict__ Wl3, const float* __restrict__ bl3,
    float* __restrict__ out)
{
    const int tid = threadIdx.x;   // 128 threads, one per channel
    __shared__ float T[64][133];   // padded: stride 133 % 32 = 5 -> conflict-free
    float s0 = 0.f, q0 = 0.f, s1 = 0.f, q1 = 0.f;
    for (int r = 0; r < NB; r += 2) {
        float a = h2[(size_t)r * 128 + tid];
        float b = h2[(size_t)(r + 1) * 128 + tid];
        s0 += a; q0 += a * a;
        s1 += b; q1 += b * b;
    }
    float ss = s0 + s1, qq = q0 + q1;
    float mu  = ss * (1.f / NB);
    float var = qq * (1.f / NB) - mu * mu;
    float sc  = g5[tid] * rsqrtf(var + EPSBN);
    float sh  = be5[tid] - mu * sc;
    const float w3 = Wl3[tid];
    for (int r = 0; r < NB; ++r)
        T[r][tid] = lrelu(h2[(size_t)r * 128 + tid] * sc + sh) * w3;
    __syncthreads();
    if (tid < 64) {
        float a0 = 0.f, a1 = 0.f, a2 = 0.f, a3 = 0.f;
        #pragma unroll 4
        for (int c = 0; c < 128; c += 4) {
            a0 += T[tid][c];
            a1 += T[tid][c + 1];
            a2 += T[tid][c + 2];
            a3 += T[tid][c + 3];
        }
        out[tid] = bl3[0] + ((a0 + a1) + (a2 + a3));
    }
}

extern "C" void kernel_launch(void* const* d_in, const int* in_sizes, int n_in,
                              void* d_out, int out_size, void* d_ws, size_t ws_size,
                              hipStream_t stream)
{
    (void)in_sizes; (void)n_in; (void)out_size; (void)ws_size;
    const float* x   = (const float*)d_in[0];
    const int*   ei  = (const int*)d_in[1];
    const float* W1a = (const float*)d_in[3];
    const float* b1a = (const float*)d_in[4];
    const float* W1b = (const float*)d_in[5];
    const float* b1b = (const float*)d_in[6];
    const float* g1  = (const float*)d_in[7];
    const float* be1 = (const float*)d_in[8];
    const float* W2a = (const float*)d_in[9];
    const float* b2a = (const float*)d_in[10];
    const float* W2b = (const float*)d_in[11];
    const float* b2b = (const float*)d_in[12];
    const float* g2  = (const float*)d_in[13];
    const float* be2 = (const float*)d_in[14];
    const float* W3  = (const float*)d_in[15];
    const float* b3  = (const float*)d_in[16];
    const float* g3  = (const float*)d_in[17];
    const float* be3 = (const float*)d_in[18];
    const float* Wl1 = (const float*)d_in[19];
    const float* bl1 = (const float*)d_in[20];
    const float* g4  = (const float*)d_in[21];
    const float* be4 = (const float*)d_in[22];
    const float* Wl2 = (const float*)d_in[23];
    const float* bl2 = (const float*)d_in[24];
    const float* g5  = (const float*)d_in[25];
    const float* be5 = (const float*)d_in[26];
    const float* Wl3 = (const float*)d_in[27];
    const float* bl3 = (const float*)d_in[28];

    float* ws  = (float*)d_ws;
    float* u1  = ws;
    float* v1  = u1 + (size_t)NN * 32;
    float* u2  = v1 + (size_t)NN * 32;
    float* v2  = u2 + (size_t)NN * 32;
    float* u3  = v2 + (size_t)NN * 32;
    float* v3  = u3 + NN;
    float* sqv = v3 + NN;
    float* a1  = sqv + NN;
    float* a2  = a1 + (size_t)NN * 32;
    float* a3  = a2 + (size_t)NN * 32;
    int*   knn = (int*)(a3 + NN);
    float* st  = (float*)(knn + (size_t)NN * 32);
    float* z   = st + 130;
    float* h1  = z + (size_t)NB * 332;
    float* h2  = h1 + (size_t)NB * 256;
    float* s4  = h2 + (size_t)NB * 128;
    float* s5  = s4 + 512;
    float* part = s5 + 512;                         // [64][128]
    unsigned short* Xh = (unsigned short*)(((uintptr_t)(part + 64 * 128) + 255) & ~(uintptr_t)255);
    unsigned short* Xl = Xh + (size_t)64 * 17 * 9 * 512;
    float* d2 = (float*)(((uintptr_t)(Xl + (size_t)64 * 17 * 9 * 512) + 255) & ~(uintptr_t)255);
    unsigned short* Wfh = (unsigned short*)(d2 + (size_t)64 * 288 * 288);
    unsigned short* Wfl = Wfh + (size_t)8 * 9 * 512;

    k_prep<<<PREP_PACK_BLOCKS + PREP_PACKW_BLOCKS + PREP_SCAL_BLOCKS, 256, 0, stream>>>(
        x, W1a, W2a, W3, b3, Xh, Xl, Wfh, Wfl, u3, v3, sqv);
    k_proj_mfma<<<1088, 256, 0, stream>>>(Xh, Xl, Wfh, Wfl, b1a, b2a, u1, v1, u2, v2);
    k_dist<<<dim3(9, NB), 256, 0, stream>>>(Xh, Xl, sqv, d2);
    k_sel<<<NN / 8, 256, 0, stream>>>(d2, knn);
    k_edge_both<<<2 * (NN / 16), 256, 0, stream>>>(u1, v1, W1b, b1b, ei,
                                                   u2, v2, W2b, b2b, knn,
                                                   u3, v3, a1, a2, a3);
    k_stats1<<<64, 256, 0, stream>>>(a1, a2, part);
    k_stats2<<<1, 256, 0, stream>>>(part, a3, g1, be1, g2, be2, g3, be3, st);
    k_pool_fc1<<<NB, 256, 0, stream>>>(a1, a2, a3, st, Wl1, bl1, h1);
    k_fc2s<<<NB, 128, 0, stream>>>(h1, g4, be4, Wl2, bl2, h2);
    k_fc3s<<<1, 128, 0, stream>>>(h2, g5, be5, Wl3, bl3, (float*)d_out);
}

// Round 10
// 147.545 us; speedup vs baseline: 4.6997x; 1.0919x over previous
//
#include <hip/hip_runtime.h>
#include <hip/hip_bf16.h>

#define ROI   268
#define FDIM  268
#define NB    64
#define NN    (NB*ROI)     // 17152
#define CC    32
#define DEG   32
#define KSEL  32
#define SLOPE 0.33f
#define EPSBN 1e-5f

typedef __attribute__((ext_vector_type(8)))  short bf16x8;
typedef __attribute__((ext_vector_type(4)))  float f32x4;
typedef __attribute__((ext_vector_type(16))) float f32x16;

__device__ __forceinline__ float lrelu(float h) { return h >= 0.f ? h : SLOPE * h; }

__device__ __forceinline__ unsigned short f2bf(float f) {
    union { __hip_bfloat16 h; unsigned short s; } u;
    u.h = __float2bfloat16(f);   // RNE, lowers to HW cvt
    return u.s;
}
__device__ __forceinline__ float bf2f(unsigned short h) {
    return __uint_as_float(((unsigned int)h) << 16);
}

// ================= K1: fused prep — pack(x) | packw | scalars =================
#define PREP_PACK_BLOCKS  2448
#define PREP_PACKW_BLOCKS 18
#define PREP_SCAL_BLOCKS  1072

__global__ __launch_bounds__(256) void k_prep(
    const float* __restrict__ x,
    const float* __restrict__ W1a, const float* __restrict__ W2a,
    const float* __restrict__ W3,  const float* __restrict__ b3,
    unsigned short* __restrict__ Xh, unsigned short* __restrict__ Xl,
    unsigned short* __restrict__ Wfh, unsigned short* __restrict__ Wfl,
    float* __restrict__ u3, float* __restrict__ v3, float* __restrict__ sqv)
{
    const int bid = blockIdx.x;
    const int tid = threadIdx.x;
    if (bid < PREP_PACK_BLOCKS) {
        const int gid = bid * 256 + tid;
        const int l   = gid & 63;
        const int f3  = gid >> 6;
        const int ks  = f3 % 9;
        const int bc  = f3 / 9;
        const int ct  = bc % 17;
        const int b   = bc / 17;
        const int node = ct * 16 + (l & 15);
        const int k0   = ks * 32 + (l >> 4) * 8;
        float f[8];
        #pragma unroll
        for (int j = 0; j < 8; ++j) f[j] = 0.f;
        if (node < ROI) {
            const float* row = &x[((size_t)b * ROI + node) * FDIM];
            if (k0 + 3 < FDIM) { float4 v = *(const float4*)&row[k0];     f[0]=v.x; f[1]=v.y; f[2]=v.z; f[3]=v.w; }
            if (k0 + 7 < FDIM) { float4 v = *(const float4*)&row[k0 + 4]; f[4]=v.x; f[5]=v.y; f[6]=v.z; f[7]=v.w; }
        }
        unsigned short hh[8], ll[8];
        #pragma unroll
        for (int j = 0; j < 8; ++j) {
            hh[j] = f2bf(f[j]);
            ll[j] = f2bf(f[j] - bf2f(hh[j]));
        }
        uint4 hp, lp;
        hp.x = (unsigned)hh[0] | ((unsigned)hh[1] << 16); hp.y = (unsigned)hh[2] | ((unsigned)hh[3] << 16);
        hp.z = (unsigned)hh[4] | ((unsigned)hh[5] << 16); hp.w = (unsigned)hh[6] | ((unsigned)hh[7] << 16);
        lp.x = (unsigned)ll[0] | ((unsigned)ll[1] << 16); lp.y = (unsigned)ll[2] | ((unsigned)ll[3] << 16);
        lp.z = (unsigned)ll[4] | ((unsigned)ll[5] << 16); lp.w = (unsigned)ll[6] | ((unsigned)ll[7] << 16);
        const size_t base = (size_t)f3 * 512 + l * 8;
        *(uint4*)&Xh[base] = hp;
        *(uint4*)&Xl[base] = lp;
    } else if (bid < PREP_PACK_BLOCKS + PREP_PACKW_BLOCKS) {
        const int gid = (bid - PREP_PACK_BLOCKS) * 256 + tid;   // < 4608
        const int l  = gid & 63;
        const int f3 = gid >> 6;
        const int ks = f3 % 9;
        const int mc = f3 / 9;
        const int ct = mc & 1;
        const int m  = mc >> 1;
        const int k0 = ks * 32 + (l >> 4) * 8;
        const int c  = ct * 16 + (l & 15);
        const float* W = (m < 2) ? W1a : W2a;
        const bool isU = (m & 1) == 0;
        unsigned short hh[8], ll[8];
        #pragma unroll
        for (int j = 0; j < 8; ++j) {
            const int kk = k0 + j;
            float val = 0.f;
            if (kk < FDIM) {
                float wb = W[(size_t)(FDIM + kk) * CC + c];
                val = isU ? (W[(size_t)kk * CC + c] - wb) : wb;
            }
            hh[j] = f2bf(val);
            ll[j] = f2bf(val - bf2f(hh[j]));
        }
        uint4 hp, lp;
        hp.x = (unsigned)hh[0] | ((unsigned)hh[1] << 16); hp.y = (unsigned)hh[2] | ((unsigned)hh[3] << 16);
        hp.z = (unsigned)hh[4] | ((unsigned)hh[5] << 16); hp.w = (unsigned)hh[6] | ((unsigned)hh[7] << 16);
        lp.x = (unsigned)ll[0] | ((unsigned)ll[1] << 16); lp.y = (unsigned)ll[2] | ((unsigned)ll[3] << 16);
        lp.z = (unsigned)ll[4] | ((unsigned)ll[5] << 16); lp.w = (unsigned)ll[6] | ((unsigned)ll[7] << 16);
        const size_t base = (size_t)f3 * 512 + l * 8;
        *(uint4*)&Wfh[base] = hp;
        *(uint4*)&Wfl[base] = lp;
    } else {
        const int s = bid - (PREP_PACK_BLOCKS + PREP_PACKW_BLOCKS);
        const int l = tid & 63;
        #pragma unroll
        for (int i = 0; i < 4; ++i) {
            const int n = s * 16 + i * 4 + (tid >> 6);
            const float* row = &x[(size_t)n * FDIM];
            float su = 0.f, sv = 0.f, sq = 0.f;
            #pragma unroll
            for (int t = 0; t < 4; ++t) {
                const int f = l + 64 * t;
                float xv = row[f];
                float wv = W3[FDIM + f];
                float wu = W3[f] - wv;
                su += xv * wu; sv += xv * wv; sq += xv * xv;
            }
            if (l < 12) {
                const int f = 256 + l;
                float xv = row[f];
                float wv = W3[FDIM + f];
                float wu = W3[f] - wv;
                su += xv * wu; sv += xv * wv; sq += xv * xv;
            }
            #pragma unroll
            for (int mm = 32; mm > 0; mm >>= 1) {
                su += __shfl_xor(su, mm);
                sv += __shfl_xor(sv, mm);
                sq += __shfl_xor(sq, mm);
            }
            if (l == 0) {
                u3[n] = su + b3[0];
                v3[n] = sv;
                sqv[n] = sq;
            }
        }
    }
}

// ======= K2: merged dist (blocks [0,320), LDS-staged B) + proj (blocks [320,1408)) =======
#define PD_DIST_BLOCKS 320    // 5 per graph: 4 A-tiles (64 rows) per block
#define PD_PROJ_BLOCKS 1088

__global__ __launch_bounds__(256) void k_projdist(
    const unsigned short* __restrict__ Xh, const unsigned short* __restrict__ Xl,
    const unsigned short* __restrict__ Wfh, const unsigned short* __restrict__ Wfl,
    const float* __restrict__ b1a, const float* __restrict__ b2a,
    const float* __restrict__ sqv,
    float* __restrict__ u1, float* __restrict__ v1,
    float* __restrict__ u2, float* __restrict__ v2,
    float* __restrict__ d2)
{
    __shared__ __align__(16) unsigned short Bh_l[4608], Bl_l[4608];  // one ct-tile, h+l
    __shared__ float sqj[288];
    const int tid = threadIdx.x;
    const int l   = tid & 63;
    const int w   = tid >> 6;

    if (blockIdx.x >= PD_DIST_BLOCKS) {
        // ---------------- proj: u1,v1,u2,v2 via MFMA (split-bf16) ----------------
        const int tile = blockIdx.x - PD_DIST_BLOCKS;   // b*17+ctn
        const int b    = tile / 17;
        const int ctn  = tile % 17;
        bf16x8 Ah[9], Al[9];
        {
            const size_t abase = (size_t)tile * 9 * 512 + l * 8;
            #pragma unroll
            for (int ks = 0; ks < 9; ++ks) {
                Ah[ks] = *(const bf16x8*)&Xh[abase + ks * 512];
                Al[ks] = *(const bf16x8*)&Xl[abase + ks * 512];
            }
        }
        float* outp = (w == 0) ? u1 : (w == 1) ? v1 : (w == 2) ? u2 : v2;
        #pragma unroll
        for (int ct = 0; ct < 2; ++ct) {
            const size_t wbase = ((size_t)((w * 2 + ct) * 9)) * 512 + l * 8;
            f32x4 acc = {0.f, 0.f, 0.f, 0.f};
            #pragma unroll
            for (int ks = 0; ks < 9; ++ks) {
                bf16x8 bh = *(const bf16x8*)&Wfh[wbase + ks * 512];
                bf16x8 bl = *(const bf16x8*)&Wfl[wbase + ks * 512];
                acc = __builtin_amdgcn_mfma_f32_16x16x32_bf16(Ah[ks], bh, acc, 0, 0, 0);
                acc = __builtin_amdgcn_mfma_f32_16x16x32_bf16(Ah[ks], bl, acc, 0, 0, 0);
                acc = __builtin_amdgcn_mfma_f32_16x16x32_bf16(Al[ks], bh, acc, 0, 0, 0);
            }
            const int ch = ct * 16 + (l & 15);
            float bias = 0.f;
            if (w == 0) bias = b1a[ch];
            else if (w == 2) bias = b2a[ch];
            const int r0 = (l >> 4) * 4;
            #pragma unroll
            for (int i = 0; i < 4; ++i) {
                const int node = ctn * 16 + r0 + i;
                if (node < ROI)
                    outp[((size_t)b * ROI + node) * 32 + ch] = acc[i] + bias;
            }
        }
        return;
    }

    // ---------------- dist: d2 rows bx*64..+63 of graph b ----------------
    const int bid = blockIdx.x;
    const int b   = bid / 5;
    const int bx  = bid % 5;
    const int at  = min(bx * 4 + w, 16);     // A-tile per wave (clamped; dup writes identical)
    const size_t bN = (size_t)b * ROI;

    for (int t = tid; t < 288; t += 256)
        sqj[t] = (t < ROI) ? sqv[bN + t] : __builtin_inff();

    bf16x8 Ah[9], Al[9];
    {
        const size_t abase = ((size_t)(b * 17 + at) * 9) * 512 + l * 8;
        #pragma unroll
        for (int ks = 0; ks < 9; ++ks) {
            Ah[ks] = *(const bf16x8*)&Xh[abase + ks * 512];
            Al[ks] = *(const bf16x8*)&Xl[abase + ks * 512];
        }
    }
    const int rbase = at * 16 + (l >> 4) * 4;
    float sqr4[4];
    #pragma unroll
    for (int i = 0; i < 4; ++i) {
        const int row = rbase + i;
        sqr4[i] = (row < ROI) ? sqv[bN + row] : 0.f;
    }

    float* drow = &d2[(size_t)b * 288 * 288];
    for (int ct = 0; ct < 17; ++ct) {
        __syncthreads();   // previous compute's LDS reads done
        {
            const unsigned short* srcH = &Xh[((size_t)(b * 17 + ct) * 9) * 512];
            const unsigned short* srcL = &Xl[((size_t)(b * 17 + ct) * 9) * 512];
            for (int t = tid; t < 576; t += 256) {
                *(uint4*)&Bh_l[t * 8] = *(const uint4*)&srcH[t * 8];
                *(uint4*)&Bl_l[t * 8] = *(const uint4*)&srcL[t * 8];
            }
        }
        __syncthreads();
        f32x4 acc = {0.f, 0.f, 0.f, 0.f};
        #pragma unroll
        for (int ks = 0; ks < 9; ++ks) {
            bf16x8 bh = *(const bf16x8*)&Bh_l[ks * 512 + l * 8];
            bf16x8 bl = *(const bf16x8*)&Bl_l[ks * 512 + l * 8];
            acc = __builtin_amdgcn_mfma_f32_16x16x32_bf16(Ah[ks], bh, acc, 0, 0, 0);
            acc = __builtin_amdgcn_mfma_f32_16x16x32_bf16(Ah[ks], bl, acc, 0, 0, 0);
            acc = __builtin_amdgcn_mfma_f32_16x16x32_bf16(Al[ks], bh, acc, 0, 0, 0);
        }
        const int col = ct * 16 + (l & 15);
        const float sj = sqj[col];
        #pragma unroll
        for (int i = 0; i < 4; ++i)
            drow[(size_t)(rbase + i) * 288 + col] = sqr4[i] + sj - 2.f * acc[i];
    }
    for (int t = tid; t < 64 * 16; t += 256) {
        const int r = bx * 64 + (t >> 4);
        if (r < 288) drow[(size_t)r * 288 + 272 + (t & 15)] = __builtin_inff();
    }
}

// ---------------- K3: top-32 via packed-key tournament ----------------
__global__ __launch_bounds__(256) void k_sel(
    const float* __restrict__ d2, int* __restrict__ knn)
{
    const int grp = blockIdx.x * 8 + (threadIdx.x >> 5);
    const int sl  = threadIdx.x & 31;
    const int b   = grp / ROI;
    const int row = grp - b * ROI;
    const float* src = &d2[((size_t)b * 288 + row) * 288];

    unsigned k[9];
    #pragma unroll
    for (int q = 0; q < 9; ++q) {
        const int idx = q * 32 + sl;
        unsigned bits = __float_as_uint(src[idx]);
        unsigned msk  = (unsigned)(((int)bits) >> 31) | 0x80000000u;
        k[q] = ((bits ^ msk) & ~0x1FFu) | (unsigned)idx;
    }
    #pragma unroll
    for (int i = 1; i < 9; ++i) {
        #pragma unroll
        for (int j = i; j > 0; --j) {
            unsigned lo = k[j-1] < k[j] ? k[j-1] : k[j];
            unsigned hi = k[j-1] < k[j] ? k[j]   : k[j-1];
            k[j-1] = lo; k[j] = hi;
        }
    }
    unsigned keep = 0;
    #pragma unroll
    for (int it = 0; it < KSEL; ++it) {
        unsigned m = k[0];
        #pragma unroll
        for (int mm = 16; mm > 0; mm >>= 1) {
            unsigned o = (unsigned)__shfl_xor((int)m, mm, 32);
            m = o < m ? o : m;
        }
        if (sl == it) keep = m;
        const bool win = (k[0] == m);
        #pragma unroll
        for (int q = 0; q < 8; ++q) k[q] = win ? k[q+1] : k[q];
        k[8] = win ? 0xFFFFFFFFu : k[8];
    }
    knn[(size_t)grp * KSEL + sl] = b * ROI + (int)(keep & 0x1FFu);
}

// ======== K4: fused edge MLP (gcn1 blocks [0,1072), gcn2 blocks [1072,2144)) ========
__global__ __launch_bounds__(256) void k_edge_both(
    const float* __restrict__ u1, const float* __restrict__ v1,
    const float* __restrict__ W1b, const float* __restrict__ b1b,
    const int* __restrict__ ei,
    const float* __restrict__ u2, const float* __restrict__ v2,
    const float* __restrict__ W2b, const float* __restrict__ b2b,
    const int* __restrict__ knn,
    const float* __restrict__ u3, const float* __restrict__ v3,
    float* __restrict__ a1, float* __restrict__ a2, float* __restrict__ a3)
{
    const int tid  = threadIdx.x;
    const int l    = tid & 63;
    const int wv   = tid >> 6;
    const int half = l >> 5;
    const int e    = l & 31;
    const bool g1 = blockIdx.x < (NN / 16);
    const int  nb = g1 ? blockIdx.x : blockIdx.x - (NN / 16);
    const float* u  = g1 ? u1 : u2;
    const float* v  = g1 ? v1 : v2;
    const float* Wb = g1 ? W1b : W2b;
    const float* bb = g1 ? b1b : b2b;
    const int* nbr  = g1 ? ei : knn;
    float* aout     = g1 ? a1 : a2;

    union { bf16x8 v8; unsigned u4[4]; } B0, B1;
    #pragma unroll
    for (int j = 0; j < 4; ++j) {
        B0.u4[j] = (unsigned)f2bf(Wb[(half * 8 + 2*j    ) * 32 + e])
                 | ((unsigned)f2bf(Wb[(half * 8 + 2*j + 1) * 32 + e]) << 16);
        B1.u4[j] = (unsigned)f2bf(Wb[(16 + half * 8 + 2*j    ) * 32 + e])
                 | ((unsigned)f2bf(Wb[(16 + half * 8 + 2*j + 1) * 32 + e]) << 16);
    }
    const float biasc = bb[e];

    int jns[4];
    #pragma unroll
    for (int nn = 0; nn < 4; ++nn)
        jns[nn] = nbr[(size_t)(nb * 16 + wv * 4 + nn) * DEG + e];

    #pragma unroll 2
    for (int nn = 0; nn < 4; ++nn) {
        const int n  = nb * 16 + wv * 4 + nn;
        const int jn = jns[nn];

        float hv[16];
        #pragma unroll
        for (int s = 0; s < 2; ++s) {
            const int c0 = s * 16 + half * 8;
            float4 uv0 = *(const float4*)&u[(size_t)n  * 32 + c0];
            float4 uv1 = *(const float4*)&u[(size_t)n  * 32 + c0 + 4];
            float4 vv0 = *(const float4*)&v[(size_t)jn * 32 + c0];
            float4 vv1 = *(const float4*)&v[(size_t)jn * 32 + c0 + 4];
            hv[s*8+0] = lrelu(uv0.x + vv0.x);
            hv[s*8+1] = lrelu(uv0.y + vv0.y);
            hv[s*8+2] = lrelu(uv0.z + vv0.z);
            hv[s*8+3] = lrelu(uv0.w + vv0.w);
            hv[s*8+4] = lrelu(uv1.x + vv1.x);
            hv[s*8+5] = lrelu(uv1.y + vv1.y);
            hv[s*8+6] = lrelu(uv1.z + vv1.z);
            hv[s*8+7] = lrelu(uv1.w + vv1.w);
        }
        union { bf16x8 v8; unsigned u4[4]; } A0, A1;
        #pragma unroll
        for (int j = 0; j < 4; ++j) {
            A0.u4[j] = (unsigned)f2bf(hv[2*j])     | ((unsigned)f2bf(hv[2*j + 1]) << 16);
            A1.u4[j] = (unsigned)f2bf(hv[8 + 2*j]) | ((unsigned)f2bf(hv[8 + 2*j + 1]) << 16);
        }
        f32x16 acc = {0.f,0.f,0.f,0.f,0.f,0.f,0.f,0.f,0.f,0.f,0.f,0.f,0.f,0.f,0.f,0.f};
        acc = __builtin_amdgcn_mfma_f32_32x32x16_bf16(A0.v8, B0.v8, acc, 0, 0, 0);
        acc = __builtin_amdgcn_mfma_f32_32x32x16_bf16(A1.v8, B1.v8, acc, 0, 0, 0);

        float mx = acc[0];
        #pragma unroll
        for (int r = 1; r < 16; ++r) mx = fmaxf(mx, acc[r]);
        mx = fmaxf(mx, __shfl_xor(mx, 32));
        if (l < 32) aout[(size_t)n * 32 + l] = mx + biasc;

        if (g1) {
            float a3v = u3[n] + v3[jn];
            #pragma unroll
            for (int mm = 16; mm > 0; mm >>= 1) a3v = fmaxf(a3v, __shfl_xor(a3v, mm));
            if (l == 0) a3[n] = a3v;
        }
    }
}

// ---------------- K5: coalesced per-chunk partial BN stats for a1,a2 ----------------
__global__ __launch_bounds__(256) void k_stats1(
    const float* __restrict__ a1, const float* __restrict__ a2,
    float* __restrict__ part)
{
    const int p = blockIdx.x;
    const int tid = threadIdx.x;
    const int ch = tid & 31, sub = tid >> 5;
    const size_t base = (size_t)p * ROI;
    float s1 = 0.f, q1 = 0.f, s2 = 0.f, q2 = 0.f;
    for (int n = sub; n < ROI; n += 8) {
        float v1 = a1[(base + n) * 32 + ch];
        float v2 = a2[(base + n) * 32 + ch];
        s1 += v1; q1 += v1 * v1; s2 += v2; q2 += v2 * v2;
    }
    __shared__ float L[4][256];
    L[0][tid] = s1; L[1][tid] = q1; L[2][tid] = s2; L[3][tid] = q2;
    __syncthreads();
    if (tid < 128) {
        const int a = tid >> 5, c = tid & 31;
        float s = 0.f;
        #pragma unroll
        for (int k = 0; k < 8; ++k) s += L[a][c + 32 * k];
        part[p * 128 + a * 32 + c] = s;
    }
}

// ======== K6: pool + fc1 with fused BN finalize (per-block recompute) ========
__global__ __launch_bounds__(256) void k_pool_fc1(
    const float* __restrict__ a1, const float* __restrict__ a2, const float* __restrict__ a3,
    const float* __restrict__ part,
    const float* __restrict__ g1, const float* __restrict__ be1,
    const float* __restrict__ g2, const float* __restrict__ be2,
    const float* __restrict__ g3, const float* __restrict__ be3,
    const float* __restrict__ Wl1, const float* __restrict__ bl1,
    float* __restrict__ h1)
{
    const int b = blockIdx.x, tid = threadIdx.x;
    __shared__ float stl[130];
    __shared__ float zs[332];
    __shared__ float P[4][64];
    __shared__ float S3[256], Q3[256];

    // ---- a3 stats (redundant per block; L2-resident) ----
    {
        float p0 = 0.f, p1 = 0.f, p2 = 0.f, p3 = 0.f;
        float q0 = 0.f, q1 = 0.f, q2 = 0.f, q3 = 0.f;
        int n = tid;
        for (; n + 768 < NN; n += 1024) {
            float a = a3[n], bb = a3[n + 256], c = a3[n + 512], d = a3[n + 768];
            p0 += a; q0 += a * a;
            p1 += bb; q1 += bb * bb;
            p2 += c; q2 += c * c;
            p3 += d; q3 += d * d;
        }
        for (; n < NN; n += 256) { float a = a3[n]; p0 += a; q0 += a * a; }
        S3[tid] = (p0 + p1) + (p2 + p3);
        Q3[tid] = (q0 + q1) + (q2 + q3);
    }
    __syncthreads();
    for (int off = 128; off > 0; off >>= 1) {
        if (tid < off) { S3[tid] += S3[tid + off]; Q3[tid] += Q3[tid + off]; }
        __syncthreads();
    }
    if (tid < 64) {
        const int a = (tid >> 5) * 2, c = tid & 31;
        float s0 = 0.f, s1 = 0.f, q0b = 0.f, q1b = 0.f;
        for (int p = 0; p < 64; p += 2) {
            s0  += part[p * 128 + a * 32 + c];
            q0b += part[p * 128 + (a + 1) * 32 + c];
            s1  += part[(p + 1) * 128 + a * 32 + c];
            q1b += part[(p + 1) * 128 + (a + 1) * 32 + c];
        }
        float ss = s0 + s1, qq = q0b + q1b;
        float gv = (tid < 32) ? g1[c] : g2[c];
        float bv = (tid < 32) ? be1[c] : be2[c];
        float mu  = ss * (1.f / NN);
        float var = qq * (1.f / NN) - mu * mu;
        float sc  = gv * rsqrtf(var + EPSBN);
        stl[tid * 2] = sc; stl[tid * 2 + 1] = bv - mu * sc;
    }
    if (tid == 64) {
        float mu  = S3[0] * (1.f / NN);
        float var = Q3[0] * (1.f / NN) - mu * mu;
        float sc  = g3[0] * rsqrtf(var + EPSBN);
        stl[128] = sc; stl[129] = be3[0] - mu * sc;
    }
    __syncthreads();

    // ---- pool + z assembly ----
    const int c = tid & 63, grp = tid >> 6;
    const float* src = (c < 32) ? a1 : a2;
    const int ch = c & 31;
    const float sc = stl[c * 2], sh = stl[c * 2 + 1];
    {
        const size_t rb = (size_t)b * ROI;
        float p0 = 0.f, p1 = 0.f, p2 = 0.f, p3 = 0.f;
        int i = grp;
        for (; i + 12 < ROI; i += 16) {
            p0 += lrelu(src[(rb + i)      * 32 + ch] * sc + sh);
            p1 += lrelu(src[(rb + i + 4)  * 32 + ch] * sc + sh);
            p2 += lrelu(src[(rb + i + 8)  * 32 + ch] * sc + sh);
            p3 += lrelu(src[(rb + i + 12) * 32 + ch] * sc + sh);
        }
        for (; i < ROI; i += 4)
            p0 += lrelu(src[(rb + i) * 32 + ch] * sc + sh);
        P[grp][c] = (p0 + p1) + (p2 + p3);
    }
    const float sc3 = stl[128], sh3 = stl[129];
    for (int i = tid; i < ROI; i += 256)
        zs[64 + i] = lrelu(a3[b * ROI + i] * sc3 + sh3);
    __syncthreads();
    if (tid < 64)
        zs[tid] = (P[0][tid] + P[1][tid] + P[2][tid] + P[3][tid]) * (1.f / ROI);
    __syncthreads();

    // ---- fc1 (4 accumulator streams) ----
    {
        float s0 = 0.f, s1 = 0.f, s2 = 0.f, s3 = 0.f;
        #pragma unroll 4
        for (int k = 0; k < 332; k += 4) {
            s0 += zs[k]     * Wl1[(size_t)k       * 256 + tid];
            s1 += zs[k + 1] * Wl1[(size_t)(k + 1) * 256 + tid];
            s2 += zs[k + 2] * Wl1[(size_t)(k + 2) * 256 + tid];
            s3 += zs[k + 3] * Wl1[(size_t)(k + 3) * 256 + tid];
        }
        h1[(size_t)b * 256 + tid] = bl1[tid] + ((s0 + s1) + (s2 + s3));
    }
}

// ======== K7: fc2 with fused batch stats ========
__global__ __launch_bounds__(128) void k_fc2s(
    const float* __restrict__ h1,
    const float* __restrict__ g4, const float* __restrict__ be4,
    const float* __restrict__ Wl2, const float* __restrict__ bl2,
    float* __restrict__ h2)
{
    const int b = blockIdx.x, tid = threadIdx.x;
    __shared__ float hs[256];
    float s0 = 0.f, q0 = 0.f, s1 = 0.f, q1 = 0.f;
    float s2 = 0.f, q2 = 0.f, s3 = 0.f, q3 = 0.f;
    for (int r = 0; r < NB; r += 2) {
        float a = h1[(size_t)r * 256 + tid];
        float c = h1[(size_t)r * 256 + tid + 128];
        float d = h1[(size_t)(r + 1) * 256 + tid];
        float e = h1[(size_t)(r + 1) * 256 + tid + 128];
        s0 += a; q0 += a * a;
        s1 += c; q1 += c * c;
        s2 += d; q2 += d * d;
        s3 += e; q3 += e * e;
    }
    {
        float ssA = s0 + s2, qqA = q0 + q2;
        float muA = ssA * (1.f / NB);
        float vaA = qqA * (1.f / NB) - muA * muA;
        float scA = g4[tid] * rsqrtf(vaA + EPSBN);
        float shA = be4[tid] - muA * scA;
        hs[tid] = lrelu(h1[(size_t)b * 256 + tid] * scA + shA);
        float ssB = s1 + s3, qqB = q1 + q3;
        float muB = ssB * (1.f / NB);
        float vaB = qqB * (1.f / NB) - muB * muB;
        float scB = g4[tid + 128] * rsqrtf(vaB + EPSBN);
        float shB = be4[tid + 128] - muB * scB;
        hs[tid + 128] = lrelu(h1[(size_t)b * 256 + tid + 128] * scB + shB);
    }
    __syncthreads();
    float s0b = 0.f, s1b = 0.f, s2b = 0.f, s3b = 0.f;
    #pragma unroll 4
    for (int k = 0; k < 256; k += 4) {
        s0b += hs[k]     * Wl2[(size_t)k       * 128 + tid];
        s1b += hs[k + 1] * Wl2[(size_t)(k + 1) * 128 + tid];
        s2b += hs[k + 2] * Wl2[(size_t)(k + 2) * 128 + tid];
        s3b += hs[k + 3] * Wl2[(size_t)(k + 3) * 128 + tid];
    }
    h2[(size_t)b * 128 + tid] = bl2[tid] + ((s0b + s1b) + (s2b + s3b));
}

// ======== K8: fc3 with fused batch stats (single block) ========
__global__ __launch_bounds__(128) void k_fc3s(
    const float* __restrict__ h2,
    const float* __restrict__ g5, const float* __restrict__ be5,
    const float* __restrict__ Wl3, const float* __restrict__ bl3,
    float* __restrict__ out)
{
    const int tid = threadIdx.x;
    __shared__ float T[64][133];
    float s0 = 0.f, q0 = 0.f, s1 = 0.f, q1 = 0.f;
    for (int r = 0; r < NB; r += 2) {
        float a = h2[(size_t)r * 128 + tid];
        float b = h2[(size_t)(r + 1) * 128 + tid];
        s0 += a; q0 += a * a;
        s1 += b; q1 += b * b;
    }
    float ss = s0 + s1, qq = q0 + q1;
    float mu  = ss * (1.f / NB);
    float var = qq * (1.f / NB) - mu * mu;
    float sc  = g5[tid] * rsqrtf(var + EPSBN);
    float sh  = be5[tid] - mu * sc;
    const float w3 = Wl3[tid];
    for (int r = 0; r < NB; ++r)
        T[r][tid] = lrelu(h2[(size_t)r * 128 + tid] * sc + sh) * w3;
    __syncthreads();
    if (tid < 64) {
        float a0 = 0.f, a1 = 0.f, a2 = 0.f, a3 = 0.f;
        #pragma unroll 4
        for (int c = 0; c < 128; c += 4) {
            a0 += T[tid][c];
            a1 += T[tid][c + 1];
            a2 += T[tid][c + 2];
            a3 += T[tid][c + 3];
        }
        out[tid] = bl3[0] + ((a0 + a1) + (a2 + a3));
    }
}

extern "C" void kernel_launch(void* const* d_in, const int* in_sizes, int n_in,
                              void* d_out, int out_size, void* d_ws, size_t ws_size,
                              hipStream_t stream)
{
    (void)in_sizes; (void)n_in; (void)out_size; (void)ws_size;
    const float* x   = (const float*)d_in[0];
    const int*   ei  = (const int*)d_in[1];
    const float* W1a = (const float*)d_in[3];
    const float* b1a = (const float*)d_in[4];
    const float* W1b = (const float*)d_in[5];
    const float* b1b = (const float*)d_in[6];
    const float* g1  = (const float*)d_in[7];
    const float* be1 = (const float*)d_in[8];
    const float* W2a = (const float*)d_in[9];
    const float* b2a = (const float*)d_in[10];
    const float* W2b = (const float*)d_in[11];
    const float* b2b = (const float*)d_in[12];
    const float* g2  = (const float*)d_in[13];
    const float* be2 = (const float*)d_in[14];
    const float* W3  = (const float*)d_in[15];
    const float* b3  = (const float*)d_in[16];
    const float* g3  = (const float*)d_in[17];
    const float* be3 = (const float*)d_in[18];
    const float* Wl1 = (const float*)d_in[19];
    const float* bl1 = (const float*)d_in[20];
    const float* g4  = (const float*)d_in[21];
    const float* be4 = (const float*)d_in[22];
    const float* Wl2 = (const float*)d_in[23];
    const float* bl2 = (const float*)d_in[24];
    const float* g5  = (const float*)d_in[25];
    const float* be5 = (const float*)d_in[26];
    const float* Wl3 = (const float*)d_in[27];
    const float* bl3 = (const float*)d_in[28];

    float* ws  = (float*)d_ws;
    float* u1  = ws;
    float* v1  = u1 + (size_t)NN * 32;
    float* u2  = v1 + (size_t)NN * 32;
    float* v2  = u2 + (size_t)NN * 32;
    float* u3  = v2 + (size_t)NN * 32;
    float* v3  = u3 + NN;
    float* sqv = v3 + NN;
    float* a1  = sqv + NN;
    float* a2  = a1 + (size_t)NN * 32;
    float* a3  = a2 + (size_t)NN * 32;
    int*   knn = (int*)(a3 + NN);
    float* h1  = (float*)(knn + (size_t)NN * 32);
    float* h2  = h1 + (size_t)NB * 256;
    float* part = h2 + (size_t)NB * 128;            // [64][128]
    unsigned short* Xh = (unsigned short*)(((uintptr_t)(part + 64 * 128) + 255) & ~(uintptr_t)255);
    unsigned short* Xl = Xh + (size_t)64 * 17 * 9 * 512;
    float* d2 = (float*)(((uintptr_t)(Xl + (size_t)64 * 17 * 9 * 512) + 255) & ~(uintptr_t)255);
    unsigned short* Wfh = (unsigned short*)(d2 + (size_t)64 * 288 * 288);
    unsigned short* Wfl = Wfh + (size_t)8 * 9 * 512;

    k_prep<<<PREP_PACK_BLOCKS + PREP_PACKW_BLOCKS + PREP_SCAL_BLOCKS, 256, 0, stream>>>(
        x, W1a, W2a, W3, b3, Xh, Xl, Wfh, Wfl, u3, v3, sqv);
    k_projdist<<<PD_DIST_BLOCKS + PD_PROJ_BLOCKS, 256, 0, stream>>>(
        Xh, Xl, Wfh, Wfl, b1a, b2a, sqv, u1, v1, u2, v2, d2);
    k_sel<<<NN / 8, 256, 0, stream>>>(d2, knn);
    k_edge_both<<<2 * (NN / 16), 256, 0, stream>>>(u1, v1, W1b, b1b, ei,
                                                   u2, v2, W2b, b2b, knn,
                                                   u3, v3, a1, a2, a3);
    k_stats1<<<64, 256, 0, stream>>>(a1, a2, part);
    k_pool_fc1<<<NB, 256, 0, stream>>>(a1, a2, a3, part, g1, be1, g2, be2, g3, be3,
                                       Wl1, bl1, h1);
    k_fc2s<<<NB, 128, 0, stream>>>(h1, g4, be4, Wl2, bl2, h2);
    k_fc3s<<<1, 128, 0, stream>>>(h2, g5, be5, Wl3, bl3, (float*)d_out);
}